// Round 9
// baseline (168.226 us; speedup 1.0000x reference)
//
#include <hip/hip_runtime.h>
#include <cstdint>

typedef unsigned long long u64;
typedef unsigned int u32;

#define CLS_T    0.05f
#define T0G      0.98f      // collect threshold (pass 1)
#define T1G      0.9965f    // candidate filter threshold (pass 2)
#define TOPK     300
#define NWORDS   5          // ceil(300/64)
#define HBINS    2560
#define KEY_BASE 0x3D000000u
#define CCAP     1024
#define NBLK     2048       // scan blocks
#define SCAP     24         // slots per (class, scan-block)
#define DCAP     8192       // dense per-class capacity

__device__ inline u32 bin_of_bits(u32 bits) {
    u32 b = (bits - KEY_BASE) >> 14;
    if (b > (HBINS - 1)) b = HBINS - 1;
    return b;
}

// compare-exchange for register bitonic: keep max if (lo==up), else min
__device__ inline void cex(u64& v, u64 p, bool lo, bool up) {
    u64 mx = v > p ? v : p;
    u64 mn = v > p ? p : v;
    v = (lo == up) ? mx : mn;
}
__device__ inline void sstep(u64& a0, u64& a1, u32 tid, u32 kk, u32 j) {
    u64 p0 = __shfl_xor((unsigned long long)a0, (int)j, 64);
    u64 p1 = __shfl_xor((unsigned long long)a1, (int)j, 64);
    bool lo = ((tid & j) == 0);
    cex(a0, p0, lo, ((tid & kk) == 0));
    cex(a1, p1, lo, (((tid + 512u) & kk) == 0));
}
__device__ inline void lstep(u64* cand, u64& a0, u64& a1, u32 tid, u32 kk, u32 j) {
    __syncthreads();
    cand[tid] = a0; cand[tid + 512] = a1;
    __syncthreads();
    u64 p0 = cand[tid ^ j], p1 = cand[(tid ^ j) + 512];
    bool lo = ((tid & j) == 0);
    cex(a0, p0, lo, ((tid & kk) == 0));
    cex(a1, p1, lo, (((tid + 512u) & kk) == 0));
}

// ---------------- decode boxes (+clip) + zero akey ----------------
__global__ void decode_kernel(const float* __restrict__ anc,
                              const float* __restrict__ reg,
                              const int* __restrict__ ph,
                              const int* __restrict__ pw,
                              float* __restrict__ boxes,
                              u64* __restrict__ akey, int A)
{
    int a = blockIdx.x * blockDim.x + threadIdx.x;
    if (a >= A) return;
    akey[a] = 0;
    float x1 = anc[a*4+0], y1 = anc[a*4+1], x2 = anc[a*4+2], y2 = anc[a*4+3];
    float w = x2 - x1, h = y2 - y1;
    float cx = x1 + 0.5f*w, cy = y1 + 0.5f*h;
    float r0 = reg[a*4+0]*0.1f, r1 = reg[a*4+1]*0.1f;
    float r2 = reg[a*4+2]*0.2f, r3 = reg[a*4+3]*0.2f;
    float pcx = cx + r0*w, pcy = cy + r1*h;
    float pw_ = expf(r2)*w, ph_ = expf(r3)*h;
    float W = (float)(*pw), H = (float)(*ph);
    boxes[a*4+0] = fmaxf(pcx - 0.5f*pw_, 0.0f);
    boxes[a*4+1] = fmaxf(pcy - 0.5f*ph_, 0.0f);
    boxes[a*4+2] = fminf(pcx + 0.5f*pw_, W);
    boxes[a*4+3] = fminf(pcy + 0.5f*ph_, H);
}

// ---------------- one coalesced pass: collect s > T0G, zero global atomics ----------------
__global__ __launch_bounds__(256) void scan_collect_kernel(
    const float* __restrict__ cls,
    u64* __restrict__ gbuf, u32* __restrict__ segcnt,
    u32* __restrict__ overflow, int A)
{
    __shared__ u32 cnt[80];
    __shared__ u64 buf[80][SCAP];
    __shared__ u32 s_over;
    const int tid = threadIdx.x;
    const int blk = blockIdx.x;

    for (int i = tid; i < 80; i += 256) cnt[i] = 0;
    if (tid == 0) s_over = 0;
    __syncthreads();

    size_t Nf4 = (size_t)A * 20;   // A*80/4
    const float4* p4 = (const float4*)cls;
    for (size_t i = (size_t)blk * 256 + tid; i < Nf4; i += (size_t)NBLK * 256) {
        float4 v = p4[i];
        float ss[4] = {v.x, v.y, v.z, v.w};
        #pragma unroll
        for (int q = 0; q < 4; ++q) {
            if (ss[q] > T0G) {
                u32 flat = (u32)(i * 4 + q);
                u32 a = flat / 80u;            // const-div -> magic mul
                u32 c = flat - a * 80u;
                u32 p = atomicAdd(&cnt[c], 1u);   // LDS atomic only
                if (p < SCAP) buf[c][p] = ((u64)__float_as_uint(ss[q]) << 32) | (u32)(~a);
                else s_over = 1;
            }
        }
    }
    __syncthreads();

    for (int m = tid; m < 80 * SCAP; m += 256) {
        int c = m / SCAP, e = m - c * SCAP;
        u32 cc = cnt[c]; if (cc > SCAP) cc = SCAP;
        if ((u32)e < cc)
            gbuf[((size_t)c * NBLK + blk) * SCAP + e] = buf[c][e];
    }
    for (int c = tid; c < 80; c += 256) {
        u32 cc = cnt[c]; if (cc > SCAP) cc = SCAP;
        segcnt[(size_t)c * NBLK + blk] = cc;
    }
    if (tid == 0 && s_over) *overflow = 1;
}

// ---------------- per-class exclusive prefix over segcnt + totals ----------------
__global__ __launch_bounds__(256) void prefix_kernel(
    const u32* __restrict__ segcnt, u32* __restrict__ pref,
    u32* __restrict__ totals)
{
    const int c = blockIdx.x;
    const int tid = threadIdx.x;
    __shared__ u32 part[256];

    const u32* row = segcnt + (size_t)c * NBLK;
    u32 v[8];
    u32 s = 0;
    #pragma unroll
    for (int q = 0; q < 8; ++q) { v[q] = row[tid * 8 + q]; s += v[q]; }
    part[tid] = s;
    __syncthreads();
    for (int d = 1; d < 256; d <<= 1) {
        u32 t = (tid >= d) ? part[tid - d] : 0;
        __syncthreads();
        part[tid] += t;
        __syncthreads();
    }
    u32 running = part[tid] - s;
    u32* prow = pref + (size_t)c * NBLK;
    #pragma unroll
    for (int q = 0; q < 8; ++q) { prow[tid * 8 + q] = running; running += v[q]; }
    if (tid == 255) totals[c] = part[255];
}

// ---------------- compact: scatter (class,block) slots to dense rows ----------------
__global__ __launch_bounds__(256) void compact_kernel(
    const u32* __restrict__ segcnt, const u32* __restrict__ pref,
    const u64* __restrict__ gbuf, u64* __restrict__ gbuf2)
{
    const int b = blockIdx.x;
    const int tid = threadIdx.x;
    __shared__ u32 scnt[80], sbase[80];
    for (int c = tid; c < 80; c += 256) {
        scnt[c]  = segcnt[(size_t)c * NBLK + b];
        sbase[c] = pref[(size_t)c * NBLK + b];
    }
    __syncthreads();
    for (int m = tid; m < 80 * SCAP; m += 256) {
        int c = m / SCAP, e = m - c * SCAP;
        if ((u32)e < scnt[c]) {
            u32 p = sbase[c] + (u32)e;
            if (p < DCAP)
                gbuf2[(size_t)c * DCAP + p] = gbuf[((size_t)c * NBLK + b) * SCAP + e];
        }
    }
}

// ---------------- per-class: dense gather + sort + NMS + scatter ----------------
__global__ __launch_bounds__(512) void class_nms_fused_kernel(
    const u32* __restrict__ totals, const u64* __restrict__ gbuf2,
    const u32* __restrict__ overflow,
    const float* __restrict__ cls,     // [A][C] for slow path
    const float* __restrict__ boxes, u64* __restrict__ akey, int A, int C)
{
    const int c = blockIdx.x;
    const u32 tid = threadIdx.x;
    const int lane = tid & 63;

    __shared__ u32 sh[HBINS];          // slow path histogram
    __shared__ u64 cand[CCAP];
    __shared__ u32 s_sel, s_cnt, s_rem;
    __shared__ float bx1[TOPK], by1[TOPK], bx2[TOPK], by2[TOPK], bar[TOPK];
    __shared__ u64 iomask[TOPK][NWORDS];
    __shared__ u64 keepm[NWORDS];

    if (tid == 0) { s_sel = 0; s_cnt = 0; }
    __syncthreads();

    const bool over = (*overflow != 0);
    const u32 n = totals[c];
    u32 cnt_f = 0;
    bool fast_ok = false;

    if (!over && n >= TOPK && n <= DCAP) {
        const u64* src = gbuf2 + (size_t)c * DCAP;
        const u32 T1 = __float_as_uint(T1G);
        for (u32 i = tid; i < n; i += 512) {
            u64 e = src[i];
            bool take = ((u32)(e >> 32) > T1);
            u64 m = __ballot(take);
            int nW = __popcll(m);
            if (nW) {
                int ldr = __ffsll((unsigned long long)m) - 1;
                u32 base = 0;
                if (lane == ldr) base = atomicAdd(&s_cnt, (u32)nW);
                base = __shfl(base, ldr);
                if (take) {
                    u32 p = base + (u32)__popcll(m & ((1ull << lane) - 1ull));
                    if (p < CCAP) cand[p] = e;
                }
            }
        }
        __syncthreads();
        cnt_f = s_cnt;
        fast_ok = (cnt_f >= TOPK && cnt_f <= CCAP);
    }

    if (!fast_ok) {
        // ---- slow exact path: 2-level select over the class column ----
        __syncthreads();
        for (int i = tid; i < HBINS; i += 512) sh[i] = 0;
        if (tid == 0) s_cnt = 0;
        __syncthreads();
        for (int a = tid; a < A; a += 512) {
            float s = cls[(size_t)a * C + c];
            if (s > CLS_T) atomicAdd(&sh[bin_of_bits(__float_as_uint(s))], 1u);
        }
        __syncthreads();
        if (tid == 0) {
            u32 cum = 0; int sel = 0;
            for (int d = HBINS - 1; d >= 0; --d) {
                u32 nc = cum + sh[d];
                if (nc >= TOPK) { sel = d; break; }
                cum = nc;
            }
            s_sel = (u32)sel; s_rem = TOPK - cum;
        }
        __syncthreads();
        const u32 sel1 = s_sel;
        __syncthreads();
        for (int i = tid; i < 256; i += 512) sh[i] = 0;
        __syncthreads();
        for (int a = tid; a < A; a += 512) {
            float s = cls[(size_t)a * C + c];
            if (s > CLS_T) {
                u32 k = __float_as_uint(s) - KEY_BASE;
                u32 b = k >> 14; if (b >= HBINS) b = HBINS - 1;
                if (b == sel1) atomicAdd(&sh[(k >> 6) & 0xFF], 1u);
            }
        }
        __syncthreads();
        if (tid == 0) {
            u32 rem = s_rem, cum = 0; int sel = 0;
            for (int d = 255; d >= 0; --d) {
                u32 nc = cum + sh[d];
                if (nc >= rem) { sel = d; break; }
                cum = nc;
            }
            s_sel = (sel1 << 14) | ((u32)sel << 6);
            s_cnt = 0;
        }
        __syncthreads();
        const u32 thresh = s_sel;
        for (int a = tid; a < A; a += 512) {
            float s = cls[(size_t)a * C + c];
            if (s > CLS_T) {
                u32 bits = __float_as_uint(s);
                if (bits - KEY_BASE >= thresh) {
                    u32 p = atomicAdd(&s_cnt, 1u);
                    if (p < CCAP) cand[p] = ((u64)bits << 32) | (u32)(~(u32)a);
                }
            }
        }
        __syncthreads();
        cnt_f = s_cnt < CCAP ? s_cnt : CCAP;
    }

    // ---- pad + register bitonic sort of 1024 (2 elems/thread), descending ----
    for (u32 i = cnt_f + tid; i < CCAP; i += 512) cand[i] = 0;
    __syncthreads();
    u64 a0 = cand[tid], a1 = cand[tid + 512];
    for (u32 kk = 2; kk <= 64; kk <<= 1)
        for (u32 j = kk >> 1; j >= 1; j >>= 1)
            sstep(a0, a1, tid, kk, j);
    lstep(cand, a0, a1, tid, 128u, 64u);
    for (u32 j = 32; j >= 1; j >>= 1) sstep(a0, a1, tid, 128u, j);
    lstep(cand, a0, a1, tid, 256u, 128u);
    lstep(cand, a0, a1, tid, 256u, 64u);
    for (u32 j = 32; j >= 1; j >>= 1) sstep(a0, a1, tid, 256u, j);
    lstep(cand, a0, a1, tid, 512u, 256u);
    lstep(cand, a0, a1, tid, 512u, 128u);
    lstep(cand, a0, a1, tid, 512u, 64u);
    for (u32 j = 32; j >= 1; j >>= 1) sstep(a0, a1, tid, 512u, j);
    {   // kk=1024, j=512: in-thread exchange (up = true for tid<512)
        u64 mx = a0 > a1 ? a0 : a1, mn = a0 > a1 ? a1 : a0;
        a0 = mx; a1 = mn;
    }
    lstep(cand, a0, a1, tid, 1024u, 256u);
    lstep(cand, a0, a1, tid, 1024u, 128u);
    lstep(cand, a0, a1, tid, 1024u, 64u);
    for (u32 j = 32; j >= 1; j >>= 1) sstep(a0, a1, tid, 1024u, j);
    // thread tid holds sorted element tid in a0

    const int T = (int)(cnt_f < TOPK ? cnt_f : TOPK);

    // ---- boxes for my candidate ----
    u64 key = a0; u32 aidx = 0;
    if ((int)tid < T) {
        aidx = ~(u32)(key & 0xFFFFFFFFull);
        float4 b4 = *(const float4*)(boxes + (size_t)aidx * 4);
        bx1[tid] = b4.x; by1[tid] = b4.y; bx2[tid] = b4.z; by2[tid] = b4.w;
        bar[tid] = fmaxf(b4.z - b4.x, 0.0f) * fmaxf(b4.w - b4.y, 0.0f);
    }
    __syncthreads();

    // ---- row masks: thread i -> which j>i it suppresses (IoU>0.5) ----
    if ((int)tid < T) {
        const int i = (int)tid;
        u64 m[NWORDS] = {0,0,0,0,0};
        float x1 = bx1[i], y1 = by1[i], x2 = bx2[i], y2 = by2[i], ai = bar[i];
        for (int j = i + 1; j < T; ++j) {
            float iw = fmaxf(fminf(x2, bx2[j]) - fmaxf(x1, bx1[j]), 0.0f);
            float ih = fmaxf(fminf(y2, by2[j]) - fmaxf(y1, by1[j]), 0.0f);
            float inter = iw * ih;
            float uni = ((ai + bar[j]) - inter) + 1e-8f;
            float q = inter - 0.5f * uni;       // 0.5*uni exact; sign(q) exact
            bool sup;
            if (fabsf(q) > 1e-5f * uni) sup = (q > 0.0f);
            else sup = (inter / uni > 0.5f);    // rare boundary: exact semantics
            if (sup) m[j >> 6] |= 1ull << (j & 63);
        }
        #pragma unroll
        for (int k2 = 0; k2 < NWORDS; ++k2) iomask[i][k2] = m[k2];
    }
    __syncthreads();

    // ---- serial greedy suppression, leader-skip (kept boxes only) ----
    if (tid == 0) {
        u64 sup[NWORDS] = {0,0,0,0,0};
        u64 kp [NWORDS] = {0,0,0,0,0};
        int i = 0;
        while (i < T) {
            kp[i >> 6] |= 1ull << (i & 63);
            #pragma unroll
            for (int k2 = 0; k2 < NWORDS; ++k2) sup[k2] |= iomask[i][k2];
            sup[i >> 6] |= 1ull << (i & 63);
            int ni = T;
            for (int k2 = i >> 6; k2 < NWORDS; ++k2) {
                u64 m = ~sup[k2];
                if (k2 == (i >> 6)) m &= ~((2ull << (i & 63)) - 1ull);
                if (m) { ni = (k2 << 6) + __ffsll((unsigned long long)m) - 1; break; }
            }
            i = ni;
        }
        #pragma unroll
        for (int k2 = 0; k2 < NWORDS; ++k2) keepm[k2] = kp[k2];
    }
    __syncthreads();

    if ((int)tid < T) {
        if ((keepm[tid >> 6] >> (tid & 63)) & 1ull) {
            u32 sbits = (u32)(key >> 32);
            u64 outk = ((u64)sbits << 32) | (u32)(255 - c);
            atomicMax(&akey[aidx], outk);
        }
    }
}

// ---------------- finalize ----------------
__global__ void finalize_kernel(const u64* __restrict__ akey,
                                float* __restrict__ out, int A)
{
    int a = blockIdx.x * blockDim.x + threadIdx.x;
    if (a >= A) return;
    float* scores = out;
    float* labels = out + A;
    float* boxes  = out + (size_t)2 * A;
    u64 k = akey[a];
    if (k) {
        scores[a] = __uint_as_float((u32)(k >> 32));
        labels[a] = (float)(int)(255u - (u32)(k & 0xFFFFFFFFull));
    } else {
        scores[a] = 0.0f;
        labels[a] = -1.0f;
        boxes[(size_t)a*4+0] = 0.0f;
        boxes[(size_t)a*4+1] = 0.0f;
        boxes[(size_t)a*4+2] = 0.0f;
        boxes[(size_t)a*4+3] = 0.0f;
    }
}

// ---------------- fallback (generic C / small ws): round-1 proven kernel ----------------
#define FB_CAP 1024
__global__ __launch_bounds__(256) void fb_topk_nms_kernel(
    const float* __restrict__ cls,
    const float* __restrict__ boxes,
    u64* __restrict__ akey,
    int A, int C)
{
    const int c   = blockIdx.x;
    const int tid = threadIdx.x;

    __shared__ u32 hist[HBINS];
    __shared__ u64 cand[FB_CAP];
    __shared__ float bx1[TOPK], by1[TOPK], bx2[TOPK], by2[TOPK], bar[TOPK];
    __shared__ u64 iomask[TOPK][NWORDS];
    __shared__ u64 keepm[NWORDS];
    __shared__ u32 s_sel1, s_sel2, s_rem, s_cnt;

    for (int i = tid; i < HBINS; i += 256) hist[i] = 0;
    __syncthreads();
    for (int a = tid; a < A; a += 256) {
        float s = cls[(size_t)a * C + c];
        if (s > CLS_T) {
            u32 k = __float_as_uint(s) - KEY_BASE;
            u32 b = k >> 14; if (b >= HBINS) b = HBINS - 1;
            atomicAdd(&hist[b], 1u);
        }
    }
    __syncthreads();
    if (tid == 0) {
        u32 cum = 0; int sel = 0;
        for (int d = HBINS - 1; d >= 0; --d) {
            u32 nc = cum + hist[d];
            if (nc >= TOPK) { sel = d; break; }
            cum = nc;
        }
        s_sel1 = (u32)sel; s_rem = TOPK - cum;
    }
    __syncthreads();
    const u32 sel1 = s_sel1;

    for (int i = tid; i < 256; i += 256) hist[i] = 0;
    __syncthreads();
    for (int a = tid; a < A; a += 256) {
        float s = cls[(size_t)a * C + c];
        if (s > CLS_T) {
            u32 k = __float_as_uint(s) - KEY_BASE;
            u32 b = k >> 14; if (b >= HBINS) b = HBINS - 1;
            if (b == sel1) atomicAdd(&hist[(k >> 6) & 0xFF], 1u);
        }
    }
    __syncthreads();
    if (tid == 0) {
        u32 rem = s_rem, cum = 0; int sel = 0;
        for (int d = 255; d >= 0; --d) {
            u32 nc = cum + hist[d];
            if (nc >= rem) { sel = d; break; }
            cum = nc;
        }
        s_sel2 = (u32)sel; s_cnt = 0;
    }
    __syncthreads();
    const u32 thresh = (sel1 << 14) | (s_sel2 << 6);

    for (int a = tid; a < A; a += 256) {
        float s = cls[(size_t)a * C + c];
        if (s > CLS_T) {
            u32 bits = __float_as_uint(s);
            u32 k = bits - KEY_BASE;
            if (k >= thresh) {
                u32 pos = atomicAdd(&s_cnt, 1u);
                if (pos < FB_CAP) cand[pos] = ((u64)bits << 32) | (u32)(~(u32)a);
            }
        }
    }
    __syncthreads();
    const u32 total = s_cnt < FB_CAP ? s_cnt : FB_CAP;
    for (int i = tid; i < FB_CAP; i += 256)
        if (i >= (int)total) cand[i] = 0;
    __syncthreads();

    for (u32 kk = 2; kk <= FB_CAP; kk <<= 1) {
        for (u32 j = kk >> 1; j > 0; j >>= 1) {
            for (u32 i = tid; i < FB_CAP; i += 256) {
                u32 l = i ^ j;
                if (l > i) {
                    u64 av = cand[i], bv = cand[l];
                    bool up = ((i & kk) == 0);
                    if ((up && av < bv) || (!up && av > bv)) { cand[i] = bv; cand[l] = av; }
                }
            }
            __syncthreads();
        }
    }
    const int T = (int)(total < TOPK ? total : TOPK);

    for (int i = tid; i < T; i += 256) {
        u32 a = ~(u32)(cand[i] & 0xFFFFFFFFull);
        float x1 = boxes[(size_t)a*4+0], y1 = boxes[(size_t)a*4+1];
        float x2 = boxes[(size_t)a*4+2], y2 = boxes[(size_t)a*4+3];
        bx1[i] = x1; by1[i] = y1; bx2[i] = x2; by2[i] = y2;
        bar[i] = fmaxf(x2 - x1, 0.0f) * fmaxf(y2 - y1, 0.0f);
    }
    __syncthreads();

    for (int i = tid; i < T; i += 256) {
        u64 m[NWORDS] = {0,0,0,0,0};
        float x1 = bx1[i], y1 = by1[i], x2 = bx2[i], y2 = by2[i], ai = bar[i];
        for (int j = i + 1; j < T; ++j) {
            float iw = fmaxf(fminf(x2, bx2[j]) - fmaxf(x1, bx1[j]), 0.0f);
            float ih = fmaxf(fminf(y2, by2[j]) - fmaxf(y1, by1[j]), 0.0f);
            float inter = iw * ih;
            float uni = ((ai + bar[j]) - inter) + 1e-8f;
            if (inter / uni > 0.5f) m[j >> 6] |= 1ull << (j & 63);
        }
        for (int k2 = 0; k2 < NWORDS; ++k2) iomask[i][k2] = m[k2];
    }
    __syncthreads();

    if (tid == 0) {
        u64 sup[NWORDS] = {0,0,0,0,0};
        u64 kp [NWORDS] = {0,0,0,0,0};
        for (int i = 0; i < T; ++i) {
            if (!((sup[i >> 6] >> (i & 63)) & 1ull)) {
                kp[i >> 6] |= 1ull << (i & 63);
                for (int k2 = 0; k2 < NWORDS; ++k2) sup[k2] |= iomask[i][k2];
            }
        }
        for (int k2 = 0; k2 < NWORDS; ++k2) keepm[k2] = kp[k2];
    }
    __syncthreads();

    for (int i = tid; i < T; i += 256) {
        if ((keepm[i >> 6] >> (i & 63)) & 1ull) {
            u64 key = cand[i];
            u32 a = ~(u32)(key & 0xFFFFFFFFull);
            u32 sbits = (u32)(key >> 32);
            u64 outk = ((u64)sbits << 32) | (u32)(255 - c);
            atomicMax(&akey[a], outk);
        }
    }
}

extern "C" void kernel_launch(void* const* d_in, const int* in_sizes, int n_in,
                              void* d_out, int out_size, void* d_ws, size_t ws_size,
                              hipStream_t stream) {
    const float* cls = (const float*)d_in[0];
    const float* reg = (const float*)d_in[1];
    const float* anc = (const float*)d_in[2];
    const int*   ph  = (const int*)d_in[3];
    const int*   pw  = (const int*)d_in[4];

    int A = in_sizes[2] / 4;
    int C = in_sizes[0] / A;

    float* out       = (float*)d_out;
    float* out_boxes = out + (size_t)2 * A;

    // workspace: akey | overflow | segcnt | pref | totals | gbuf | gbuf2
    size_t akey_bytes = (size_t)A * sizeof(u64);
    size_t off_of     = (akey_bytes + 255) & ~(size_t)255;
    size_t off_sc     = (off_of + 256 + 255) & ~(size_t)255;
    size_t sc_bytes   = (size_t)80 * NBLK * sizeof(u32);
    size_t off_pf     = (off_sc + sc_bytes + 255) & ~(size_t)255;
    size_t off_tt     = (off_pf + sc_bytes + 255) & ~(size_t)255;
    size_t tt_bytes   = 80 * sizeof(u32);
    size_t off_gb     = (off_tt + tt_bytes + 255) & ~(size_t)255;
    size_t gb_bytes   = (size_t)80 * NBLK * SCAP * sizeof(u64);
    size_t off_g2     = (off_gb + gb_bytes + 255) & ~(size_t)255;
    size_t g2_bytes   = (size_t)80 * DCAP * sizeof(u64);
    size_t need       = off_g2 + g2_bytes;

    u64* akey = (u64*)d_ws;

    decode_kernel<<<(A + 255) / 256, 256, 0, stream>>>(anc, reg, ph, pw, out_boxes, akey, A);

    bool fastpath = (C == 80) && ((A & 3) == 0) && (A < (1 << 20)) && (ws_size >= need);
    if (fastpath) {
        u32* overflow = (u32*)((char*)d_ws + off_of);
        u32* segcnt   = (u32*)((char*)d_ws + off_sc);
        u32* pref     = (u32*)((char*)d_ws + off_pf);
        u32* totals   = (u32*)((char*)d_ws + off_tt);
        u64* gbuf     = (u64*)((char*)d_ws + off_gb);
        u64* gbuf2    = (u64*)((char*)d_ws + off_g2);

        hipMemsetAsync(overflow, 0, sizeof(u32), stream);
        scan_collect_kernel<<<NBLK, 256, 0, stream>>>(cls, gbuf, segcnt, overflow, A);
        prefix_kernel<<<80, 256, 0, stream>>>(segcnt, pref, totals);
        compact_kernel<<<NBLK, 256, 0, stream>>>(segcnt, pref, gbuf, gbuf2);
        class_nms_fused_kernel<<<C, 512, 0, stream>>>(totals, gbuf2, overflow, cls, out_boxes, akey, A, C);
    } else {
        fb_topk_nms_kernel<<<C, 256, 0, stream>>>(cls, out_boxes, akey, A, C);
    }

    finalize_kernel<<<(A + 255) / 256, 256, 0, stream>>>(akey, out, A);
}

// Round 10
// 109.781 us; speedup vs baseline: 1.5324x; 1.5324x over previous
//
#include <hip/hip_runtime.h>
#include <cstdint>

typedef unsigned long long u64;
typedef unsigned int u32;

#define CLS_T    0.05f
#define T0G      0.98f      // collect threshold (pass 1)
#define T1G      0.9965f    // candidate filter threshold (pass 2)
#define TOPK     300
#define NWORDS   5          // ceil(300/64)
#define HBINS    2560
#define KEY_BASE 0x3D000000u
#define CCAP     1024
#define NBLK     2048       // scan blocks
#define SCAP     24         // slots per (class, scan-block)
#define DCAP     8192       // dense per-class capacity

__device__ inline u32 bin_of_bits(u32 bits) {
    u32 b = (bits - KEY_BASE) >> 14;
    if (b > (HBINS - 1)) b = HBINS - 1;
    return b;
}

// compare-exchange for register bitonic: keep max if (lo==up), else min
__device__ inline void cex(u64& v, u64 p, bool lo, bool up) {
    u64 mx = v > p ? v : p;
    u64 mn = v > p ? p : v;
    v = (lo == up) ? mx : mn;
}
__device__ inline void sstep(u64& a0, u64& a1, u32 tid, u32 kk, u32 j) {
    u64 p0 = __shfl_xor((unsigned long long)a0, (int)j, 64);
    u64 p1 = __shfl_xor((unsigned long long)a1, (int)j, 64);
    bool lo = ((tid & j) == 0);
    cex(a0, p0, lo, ((tid & kk) == 0));
    cex(a1, p1, lo, (((tid + 512u) & kk) == 0));
}
__device__ inline void lstep(u64* cand, u64& a0, u64& a1, u32 tid, u32 kk, u32 j) {
    __syncthreads();
    cand[tid] = a0; cand[tid + 512] = a1;
    __syncthreads();
    u64 p0 = cand[tid ^ j], p1 = cand[(tid ^ j) + 512];
    bool lo = ((tid & j) == 0);
    cex(a0, p0, lo, ((tid & kk) == 0));
    cex(a1, p1, lo, (((tid + 512u) & kk) == 0));
}

// ---------------- decode boxes (+clip) + zero akey ----------------
__global__ void decode_kernel(const float* __restrict__ anc,
                              const float* __restrict__ reg,
                              const int* __restrict__ ph,
                              const int* __restrict__ pw,
                              float* __restrict__ boxes,
                              u64* __restrict__ akey, int A)
{
    int a = blockIdx.x * blockDim.x + threadIdx.x;
    if (a >= A) return;
    akey[a] = 0;
    float x1 = anc[a*4+0], y1 = anc[a*4+1], x2 = anc[a*4+2], y2 = anc[a*4+3];
    float w = x2 - x1, h = y2 - y1;
    float cx = x1 + 0.5f*w, cy = y1 + 0.5f*h;
    float r0 = reg[a*4+0]*0.1f, r1 = reg[a*4+1]*0.1f;
    float r2 = reg[a*4+2]*0.2f, r3 = reg[a*4+3]*0.2f;
    float pcx = cx + r0*w, pcy = cy + r1*h;
    float pw_ = expf(r2)*w, ph_ = expf(r3)*h;
    float W = (float)(*pw), H = (float)(*ph);
    boxes[a*4+0] = fmaxf(pcx - 0.5f*pw_, 0.0f);
    boxes[a*4+1] = fmaxf(pcy - 0.5f*ph_, 0.0f);
    boxes[a*4+2] = fminf(pcx + 0.5f*pw_, W);
    boxes[a*4+3] = fminf(pcy + 0.5f*ph_, H);
}

// ---------------- one coalesced pass: collect s > T0G, zero global atomics ----------------
__global__ __launch_bounds__(256) void scan_collect_kernel(
    const float* __restrict__ cls,
    u64* __restrict__ gbuf, u32* __restrict__ segcnt,
    u32* __restrict__ overflow, int A)
{
    __shared__ u32 cnt[80];
    __shared__ u64 buf[80][SCAP];
    __shared__ u32 s_over;
    const int tid = threadIdx.x;
    const int blk = blockIdx.x;

    for (int i = tid; i < 80; i += 256) cnt[i] = 0;
    if (tid == 0) s_over = 0;
    __syncthreads();

    size_t Nf4 = (size_t)A * 20;   // A*80/4
    const float4* p4 = (const float4*)cls;
    for (size_t i = (size_t)blk * 256 + tid; i < Nf4; i += (size_t)NBLK * 256) {
        float4 v = p4[i];
        float ss[4] = {v.x, v.y, v.z, v.w};
        #pragma unroll
        for (int q = 0; q < 4; ++q) {
            if (ss[q] > T0G) {
                u32 flat = (u32)(i * 4 + q);
                u32 a = flat / 80u;            // const-div -> magic mul
                u32 c = flat - a * 80u;
                u32 p = atomicAdd(&cnt[c], 1u);   // LDS atomic only
                if (p < SCAP) buf[c][p] = ((u64)__float_as_uint(ss[q]) << 32) | (u32)(~a);
                else s_over = 1;
            }
        }
    }
    __syncthreads();

    for (int m = tid; m < 80 * SCAP; m += 256) {
        int c = m / SCAP, e = m - c * SCAP;
        u32 cc = cnt[c]; if (cc > SCAP) cc = SCAP;
        if ((u32)e < cc)
            gbuf[((size_t)c * NBLK + blk) * SCAP + e] = buf[c][e];
    }
    for (int c = tid; c < 80; c += 256) {
        u32 cc = cnt[c]; if (cc > SCAP) cc = SCAP;
        segcnt[(size_t)c * NBLK + blk] = cc;
    }
    if (tid == 0 && s_over) *overflow = 1;
}

// ---------------- per-class exclusive prefix over segcnt + totals ----------------
__global__ __launch_bounds__(256) void prefix_kernel(
    const u32* __restrict__ segcnt, u32* __restrict__ pref,
    u32* __restrict__ totals)
{
    const int c = blockIdx.x;
    const int tid = threadIdx.x;
    __shared__ u32 part[256];

    const u32* row = segcnt + (size_t)c * NBLK;
    u32 v[8];
    u32 s = 0;
    #pragma unroll
    for (int q = 0; q < 8; ++q) { v[q] = row[tid * 8 + q]; s += v[q]; }
    part[tid] = s;
    __syncthreads();
    for (int d = 1; d < 256; d <<= 1) {
        u32 t = (tid >= d) ? part[tid - d] : 0;
        __syncthreads();
        part[tid] += t;
        __syncthreads();
    }
    u32 running = part[tid] - s;
    u32* prow = pref + (size_t)c * NBLK;
    #pragma unroll
    for (int q = 0; q < 8; ++q) { prow[tid * 8 + q] = running; running += v[q]; }
    if (tid == 255) totals[c] = part[255];
}

// ---------------- compact: scatter (class,block) slots to dense rows ----------------
__global__ __launch_bounds__(256) void compact_kernel(
    const u32* __restrict__ segcnt, const u32* __restrict__ pref,
    const u64* __restrict__ gbuf, u64* __restrict__ gbuf2)
{
    const int b = blockIdx.x;
    const int tid = threadIdx.x;
    __shared__ u32 scnt[80], sbase[80];
    for (int c = tid; c < 80; c += 256) {
        scnt[c]  = segcnt[(size_t)c * NBLK + b];
        sbase[c] = pref[(size_t)c * NBLK + b];
    }
    __syncthreads();
    for (int m = tid; m < 80 * SCAP; m += 256) {
        int c = m / SCAP, e = m - c * SCAP;
        if ((u32)e < scnt[c]) {
            u32 p = sbase[c] + (u32)e;
            if (p < DCAP)
                gbuf2[(size_t)c * DCAP + p] = gbuf[((size_t)c * NBLK + b) * SCAP + e];
        }
    }
}

// ---------------- per-class: dense gather + sort + ballot-NMS + scatter ----------------
__global__ __launch_bounds__(512) void class_nms_fused_kernel(
    const u32* __restrict__ totals, const u64* __restrict__ gbuf2,
    const u32* __restrict__ overflow,
    const float* __restrict__ cls,     // [A][C] for slow path
    const float* __restrict__ boxes, u64* __restrict__ akey, int A, int C)
{
    const int c = blockIdx.x;
    const u32 tid = threadIdx.x;
    const int lane = tid & 63;

    __shared__ u32 sh[HBINS];          // slow path histogram
    __shared__ u64 cand[CCAP];
    __shared__ u32 s_sel, s_cnt, s_rem;
    __shared__ float bx1[TOPK], by1[TOPK], bx2[TOPK], by2[TOPK], bar[TOPK];
    __shared__ u64 iomaskT[NWORDS][TOPK];   // transposed colmask: [word][box]
    __shared__ u64 s_keep[NWORDS];

    if (tid == 0) { s_sel = 0; s_cnt = 0; }
    __syncthreads();

    const bool over = (*overflow != 0);
    const u32 n = totals[c];
    u32 cnt_f = 0;
    bool fast_ok = false;

    if (!over && n >= TOPK && n <= DCAP) {
        const u64* src = gbuf2 + (size_t)c * DCAP;
        const u32 T1 = __float_as_uint(T1G);
        for (u32 i = tid; i < n; i += 512) {
            u64 e = src[i];
            bool take = ((u32)(e >> 32) > T1);
            u64 m = __ballot(take);
            int nW = __popcll(m);
            if (nW) {
                int ldr = __ffsll((unsigned long long)m) - 1;
                u32 base = 0;
                if (lane == ldr) base = atomicAdd(&s_cnt, (u32)nW);
                base = __shfl(base, ldr);
                if (take) {
                    u32 p = base + (u32)__popcll(m & ((1ull << lane) - 1ull));
                    if (p < CCAP) cand[p] = e;
                }
            }
        }
        __syncthreads();
        cnt_f = s_cnt;
        fast_ok = (cnt_f >= TOPK && cnt_f <= CCAP);
    }

    if (!fast_ok) {
        // ---- slow exact path: 2-level select over the class column ----
        __syncthreads();
        for (int i = tid; i < HBINS; i += 512) sh[i] = 0;
        if (tid == 0) s_cnt = 0;
        __syncthreads();
        for (int a = tid; a < A; a += 512) {
            float s = cls[(size_t)a * C + c];
            if (s > CLS_T) atomicAdd(&sh[bin_of_bits(__float_as_uint(s))], 1u);
        }
        __syncthreads();
        if (tid == 0) {
            u32 cum = 0; int sel = 0;
            for (int d = HBINS - 1; d >= 0; --d) {
                u32 nc = cum + sh[d];
                if (nc >= TOPK) { sel = d; break; }
                cum = nc;
            }
            s_sel = (u32)sel; s_rem = TOPK - cum;
        }
        __syncthreads();
        const u32 sel1 = s_sel;
        __syncthreads();
        for (int i = tid; i < 256; i += 512) sh[i] = 0;
        __syncthreads();
        for (int a = tid; a < A; a += 512) {
            float s = cls[(size_t)a * C + c];
            if (s > CLS_T) {
                u32 k = __float_as_uint(s) - KEY_BASE;
                u32 b = k >> 14; if (b >= HBINS) b = HBINS - 1;
                if (b == sel1) atomicAdd(&sh[(k >> 6) & 0xFF], 1u);
            }
        }
        __syncthreads();
        if (tid == 0) {
            u32 rem = s_rem, cum = 0; int sel = 0;
            for (int d = 255; d >= 0; --d) {
                u32 nc = cum + sh[d];
                if (nc >= rem) { sel = d; break; }
                cum = nc;
            }
            s_sel = (sel1 << 14) | ((u32)sel << 6);
            s_cnt = 0;
        }
        __syncthreads();
        const u32 thresh = s_sel;
        for (int a = tid; a < A; a += 512) {
            float s = cls[(size_t)a * C + c];
            if (s > CLS_T) {
                u32 bits = __float_as_uint(s);
                if (bits - KEY_BASE >= thresh) {
                    u32 p = atomicAdd(&s_cnt, 1u);
                    if (p < CCAP) cand[p] = ((u64)bits << 32) | (u32)(~(u32)a);
                }
            }
        }
        __syncthreads();
        cnt_f = s_cnt < CCAP ? s_cnt : CCAP;
    }

    // ---- pad + register bitonic sort of 1024 (2 elems/thread), descending ----
    for (u32 i = cnt_f + tid; i < CCAP; i += 512) cand[i] = 0;
    __syncthreads();
    u64 a0 = cand[tid], a1 = cand[tid + 512];
    for (u32 kk = 2; kk <= 64; kk <<= 1)
        for (u32 j = kk >> 1; j >= 1; j >>= 1)
            sstep(a0, a1, tid, kk, j);
    lstep(cand, a0, a1, tid, 128u, 64u);
    for (u32 j = 32; j >= 1; j >>= 1) sstep(a0, a1, tid, 128u, j);
    lstep(cand, a0, a1, tid, 256u, 128u);
    lstep(cand, a0, a1, tid, 256u, 64u);
    for (u32 j = 32; j >= 1; j >>= 1) sstep(a0, a1, tid, 256u, j);
    lstep(cand, a0, a1, tid, 512u, 256u);
    lstep(cand, a0, a1, tid, 512u, 128u);
    lstep(cand, a0, a1, tid, 512u, 64u);
    for (u32 j = 32; j >= 1; j >>= 1) sstep(a0, a1, tid, 512u, j);
    {   // kk=1024, j=512: in-thread exchange (up = true for tid<512)
        u64 mx = a0 > a1 ? a0 : a1, mn = a0 > a1 ? a1 : a0;
        a0 = mx; a1 = mn;
    }
    lstep(cand, a0, a1, tid, 1024u, 256u);
    lstep(cand, a0, a1, tid, 1024u, 128u);
    lstep(cand, a0, a1, tid, 1024u, 64u);
    for (u32 j = 32; j >= 1; j >>= 1) sstep(a0, a1, tid, 1024u, j);
    // thread tid holds sorted element tid in a0

    const int T = (int)(cnt_f < TOPK ? cnt_f : TOPK);

    // ---- boxes for my candidate ----
    u64 key = a0; u32 aidx = 0;
    if ((int)tid < T) {
        aidx = ~(u32)(key & 0xFFFFFFFFull);
        float4 b4 = *(const float4*)(boxes + (size_t)aidx * 4);
        bx1[tid] = b4.x; by1[tid] = b4.y; bx2[tid] = b4.z; by2[tid] = b4.w;
        bar[tid] = fmaxf(b4.z - b4.x, 0.0f) * fmaxf(b4.w - b4.y, 0.0f);
    }
    __syncthreads();

    // ---- colmask: which i<tid suppress me (IoU>0.5) -> iomaskT[w][tid] ----
    {
        u64 cm[NWORDS] = {0,0,0,0,0};
        if ((int)tid < T) {
            float x1 = bx1[tid], y1 = by1[tid], x2 = bx2[tid], y2 = by2[tid], ar = bar[tid];
            for (int i = 0; i < (int)tid; ++i) {
                float iw = fmaxf(fminf(x2, bx2[i]) - fmaxf(x1, bx1[i]), 0.0f);
                float ih = fmaxf(fminf(y2, by2[i]) - fmaxf(y1, by1[i]), 0.0f);
                float inter = iw * ih;
                float uni = ((ar + bar[i]) - inter) + 1e-8f;
                float q = inter - 0.5f * uni;       // 0.5*uni exact; sign(q) exact
                bool sup;
                if (fabsf(q) > 1e-5f * uni) sup = (q > 0.0f);
                else sup = (inter / uni > 0.5f);    // rare boundary: exact semantics
                if (sup) cm[i >> 6] |= 1ull << (i & 63);
            }
            #pragma unroll
            for (int w = 0; w < NWORDS; ++w) iomaskT[w][tid] = cm[w];
        }
    }
    __syncthreads();

    // ---- wave 0: word-serial ballot greedy (all register/crossbar ops) ----
    if (tid < 64) {
        #pragma unroll
        for (int w = 0; w < NWORDS; ++w) {
            int b = w * 64 + lane;
            bool valid = (b < T);
            u64 supearly = 0, cmw = 0;
            if (valid) {
                #pragma unroll
                for (int w2 = 0; w2 < NWORDS; ++w2)
                    if (w2 < w) supearly |= s_keep[w2] & iomaskT[w2][b];
                cmw = iomaskT[w][b];
            }
            bool alive0 = valid && (supearly == 0);
            u64 alive = __ballot(alive0);
            u64 kp = 0;
            while (alive) {
                int i = __ffsll((unsigned long long)alive) - 1;
                kp |= 1ull << i;
                u64 supm = __ballot(((cmw >> (u32)i) & 1ull) != 0);
                alive &= ~supm;
                alive &= ~(1ull << i);
            }
            if (lane == 0) s_keep[w] = kp;
        }
    }
    __syncthreads();

    if ((int)tid < T) {
        if ((s_keep[tid >> 6] >> (tid & 63)) & 1ull) {
            u32 sbits = (u32)(key >> 32);
            u64 outk = ((u64)sbits << 32) | (u32)(255 - c);
            atomicMax(&akey[aidx], outk);
        }
    }
}

// ---------------- finalize ----------------
__global__ void finalize_kernel(const u64* __restrict__ akey,
                                float* __restrict__ out, int A)
{
    int a = blockIdx.x * blockDim.x + threadIdx.x;
    if (a >= A) return;
    float* scores = out;
    float* labels = out + A;
    float* boxes  = out + (size_t)2 * A;
    u64 k = akey[a];
    if (k) {
        scores[a] = __uint_as_float((u32)(k >> 32));
        labels[a] = (float)(int)(255u - (u32)(k & 0xFFFFFFFFull));
    } else {
        scores[a] = 0.0f;
        labels[a] = -1.0f;
        boxes[(size_t)a*4+0] = 0.0f;
        boxes[(size_t)a*4+1] = 0.0f;
        boxes[(size_t)a*4+2] = 0.0f;
        boxes[(size_t)a*4+3] = 0.0f;
    }
}

// ---------------- fallback (generic C / small ws): round-1 proven kernel ----------------
#define FB_CAP 1024
__global__ __launch_bounds__(256) void fb_topk_nms_kernel(
    const float* __restrict__ cls,
    const float* __restrict__ boxes,
    u64* __restrict__ akey,
    int A, int C)
{
    const int c   = blockIdx.x;
    const int tid = threadIdx.x;

    __shared__ u32 hist[HBINS];
    __shared__ u64 cand[FB_CAP];
    __shared__ float bx1[TOPK], by1[TOPK], bx2[TOPK], by2[TOPK], bar[TOPK];
    __shared__ u64 iomask[TOPK][NWORDS];
    __shared__ u64 keepm[NWORDS];
    __shared__ u32 s_sel1, s_sel2, s_rem, s_cnt;

    for (int i = tid; i < HBINS; i += 256) hist[i] = 0;
    __syncthreads();
    for (int a = tid; a < A; a += 256) {
        float s = cls[(size_t)a * C + c];
        if (s > CLS_T) {
            u32 k = __float_as_uint(s) - KEY_BASE;
            u32 b = k >> 14; if (b >= HBINS) b = HBINS - 1;
            atomicAdd(&hist[b], 1u);
        }
    }
    __syncthreads();
    if (tid == 0) {
        u32 cum = 0; int sel = 0;
        for (int d = HBINS - 1; d >= 0; --d) {
            u32 nc = cum + hist[d];
            if (nc >= TOPK) { sel = d; break; }
            cum = nc;
        }
        s_sel1 = (u32)sel; s_rem = TOPK - cum;
    }
    __syncthreads();
    const u32 sel1 = s_sel1;

    for (int i = tid; i < 256; i += 256) hist[i] = 0;
    __syncthreads();
    for (int a = tid; a < A; a += 256) {
        float s = cls[(size_t)a * C + c];
        if (s > CLS_T) {
            u32 k = __float_as_uint(s) - KEY_BASE;
            u32 b = k >> 14; if (b >= HBINS) b = HBINS - 1;
            if (b == sel1) atomicAdd(&hist[(k >> 6) & 0xFF], 1u);
        }
    }
    __syncthreads();
    if (tid == 0) {
        u32 rem = s_rem, cum = 0; int sel = 0;
        for (int d = 255; d >= 0; --d) {
            u32 nc = cum + hist[d];
            if (nc >= rem) { sel = d; break; }
            cum = nc;
        }
        s_sel2 = (u32)sel; s_cnt = 0;
    }
    __syncthreads();
    const u32 thresh = (sel1 << 14) | (s_sel2 << 6);

    for (int a = tid; a < A; a += 256) {
        float s = cls[(size_t)a * C + c];
        if (s > CLS_T) {
            u32 bits = __float_as_uint(s);
            u32 k = bits - KEY_BASE;
            if (k >= thresh) {
                u32 pos = atomicAdd(&s_cnt, 1u);
                if (pos < FB_CAP) cand[pos] = ((u64)bits << 32) | (u32)(~(u32)a);
            }
        }
    }
    __syncthreads();
    const u32 total = s_cnt < FB_CAP ? s_cnt : FB_CAP;
    for (int i = tid; i < FB_CAP; i += 256)
        if (i >= (int)total) cand[i] = 0;
    __syncthreads();

    for (u32 kk = 2; kk <= FB_CAP; kk <<= 1) {
        for (u32 j = kk >> 1; j > 0; j >>= 1) {
            for (u32 i = tid; i < FB_CAP; i += 256) {
                u32 l = i ^ j;
                if (l > i) {
                    u64 av = cand[i], bv = cand[l];
                    bool up = ((i & kk) == 0);
                    if ((up && av < bv) || (!up && av > bv)) { cand[i] = bv; cand[l] = av; }
                }
            }
            __syncthreads();
        }
    }
    const int T = (int)(total < TOPK ? total : TOPK);

    for (int i = tid; i < T; i += 256) {
        u32 a = ~(u32)(cand[i] & 0xFFFFFFFFull);
        float x1 = boxes[(size_t)a*4+0], y1 = boxes[(size_t)a*4+1];
        float x2 = boxes[(size_t)a*4+2], y2 = boxes[(size_t)a*4+3];
        bx1[i] = x1; by1[i] = y1; bx2[i] = x2; by2[i] = y2;
        bar[i] = fmaxf(x2 - x1, 0.0f) * fmaxf(y2 - y1, 0.0f);
    }
    __syncthreads();

    for (int i = tid; i < T; i += 256) {
        u64 m[NWORDS] = {0,0,0,0,0};
        float x1 = bx1[i], y1 = by1[i], x2 = bx2[i], y2 = by2[i], ai = bar[i];
        for (int j = i + 1; j < T; ++j) {
            float iw = fmaxf(fminf(x2, bx2[j]) - fmaxf(x1, bx1[j]), 0.0f);
            float ih = fmaxf(fminf(y2, by2[j]) - fmaxf(y1, by1[j]), 0.0f);
            float inter = iw * ih;
            float uni = ((ai + bar[j]) - inter) + 1e-8f;
            if (inter / uni > 0.5f) m[j >> 6] |= 1ull << (j & 63);
        }
        for (int k2 = 0; k2 < NWORDS; ++k2) iomask[i][k2] = m[k2];
    }
    __syncthreads();

    if (tid == 0) {
        u64 sup[NWORDS] = {0,0,0,0,0};
        u64 kp [NWORDS] = {0,0,0,0,0};
        for (int i = 0; i < T; ++i) {
            if (!((sup[i >> 6] >> (i & 63)) & 1ull)) {
                kp[i >> 6] |= 1ull << (i & 63);
                for (int k2 = 0; k2 < NWORDS; ++k2) sup[k2] |= iomask[i][k2];
            }
        }
        for (int k2 = 0; k2 < NWORDS; ++k2) keepm[k2] = kp[k2];
    }
    __syncthreads();

    for (int i = tid; i < T; i += 256) {
        if ((keepm[i >> 6] >> (i & 63)) & 1ull) {
            u64 key = cand[i];
            u32 a = ~(u32)(key & 0xFFFFFFFFull);
            u32 sbits = (u32)(key >> 32);
            u64 outk = ((u64)sbits << 32) | (u32)(255 - c);
            atomicMax(&akey[a], outk);
        }
    }
}

extern "C" void kernel_launch(void* const* d_in, const int* in_sizes, int n_in,
                              void* d_out, int out_size, void* d_ws, size_t ws_size,
                              hipStream_t stream) {
    const float* cls = (const float*)d_in[0];
    const float* reg = (const float*)d_in[1];
    const float* anc = (const float*)d_in[2];
    const int*   ph  = (const int*)d_in[3];
    const int*   pw  = (const int*)d_in[4];

    int A = in_sizes[2] / 4;
    int C = in_sizes[0] / A;

    float* out       = (float*)d_out;
    float* out_boxes = out + (size_t)2 * A;

    // workspace: akey | overflow | segcnt | pref | totals | gbuf | gbuf2
    size_t akey_bytes = (size_t)A * sizeof(u64);
    size_t off_of     = (akey_bytes + 255) & ~(size_t)255;
    size_t off_sc     = (off_of + 256 + 255) & ~(size_t)255;
    size_t sc_bytes   = (size_t)80 * NBLK * sizeof(u32);
    size_t off_pf     = (off_sc + sc_bytes + 255) & ~(size_t)255;
    size_t off_tt     = (off_pf + sc_bytes + 255) & ~(size_t)255;
    size_t tt_bytes   = 80 * sizeof(u32);
    size_t off_gb     = (off_tt + tt_bytes + 255) & ~(size_t)255;
    size_t gb_bytes   = (size_t)80 * NBLK * SCAP * sizeof(u64);
    size_t off_g2     = (off_gb + gb_bytes + 255) & ~(size_t)255;
    size_t g2_bytes   = (size_t)80 * DCAP * sizeof(u64);
    size_t need       = off_g2 + g2_bytes;

    u64* akey = (u64*)d_ws;

    decode_kernel<<<(A + 255) / 256, 256, 0, stream>>>(anc, reg, ph, pw, out_boxes, akey, A);

    bool fastpath = (C == 80) && ((A & 3) == 0) && (A < (1 << 20)) && (ws_size >= need);
    if (fastpath) {
        u32* overflow = (u32*)((char*)d_ws + off_of);
        u32* segcnt   = (u32*)((char*)d_ws + off_sc);
        u32* pref     = (u32*)((char*)d_ws + off_pf);
        u32* totals   = (u32*)((char*)d_ws + off_tt);
        u64* gbuf     = (u64*)((char*)d_ws + off_gb);
        u64* gbuf2    = (u64*)((char*)d_ws + off_g2);

        hipMemsetAsync(overflow, 0, sizeof(u32), stream);
        scan_collect_kernel<<<NBLK, 256, 0, stream>>>(cls, gbuf, segcnt, overflow, A);
        prefix_kernel<<<80, 256, 0, stream>>>(segcnt, pref, totals);
        compact_kernel<<<NBLK, 256, 0, stream>>>(segcnt, pref, gbuf, gbuf2);
        class_nms_fused_kernel<<<C, 512, 0, stream>>>(totals, gbuf2, overflow, cls, out_boxes, akey, A, C);
    } else {
        fb_topk_nms_kernel<<<C, 256, 0, stream>>>(cls, out_boxes, akey, A, C);
    }

    finalize_kernel<<<(A + 255) / 256, 256, 0, stream>>>(akey, out, A);
}

// Round 11
// 99.882 us; speedup vs baseline: 1.6843x; 1.0991x over previous
//
#include <hip/hip_runtime.h>
#include <cstdint>

typedef unsigned long long u64;
typedef unsigned int u32;

#define CLS_T    0.05f
#define T0G      0.98f      // collect threshold (pass 1)
#define T1G      0.9965f    // candidate filter threshold (pass 2)
#define TOPK     300
#define NWORDS   5          // ceil(300/64)
#define HBINS    2560
#define KEY_BASE 0x3D000000u
#define CCAP     1024
#define NBLK     2048       // scan blocks
#define SCAP     24         // slots per (class, scan-block)
#define DCAP     8192       // dense per-class capacity

__device__ inline u32 bin_of_bits(u32 bits) {
    u32 b = (bits - KEY_BASE) >> 14;
    if (b > (HBINS - 1)) b = HBINS - 1;
    return b;
}

// compare-exchange for register bitonic: keep max if (lo==up), else min
__device__ inline void cex(u64& v, u64 p, bool lo, bool up) {
    u64 mx = v > p ? v : p;
    u64 mn = v > p ? p : v;
    v = (lo == up) ? mx : mn;
}
__device__ inline void sstep(u64& a0, u64& a1, u32 tid, u32 kk, u32 j) {
    u64 p0 = __shfl_xor((unsigned long long)a0, (int)j, 64);
    u64 p1 = __shfl_xor((unsigned long long)a1, (int)j, 64);
    bool lo = ((tid & j) == 0);
    cex(a0, p0, lo, ((tid & kk) == 0));
    cex(a1, p1, lo, (((tid + 512u) & kk) == 0));
}
__device__ inline void lstep(u64* cand, u64& a0, u64& a1, u32 tid, u32 kk, u32 j) {
    __syncthreads();
    cand[tid] = a0; cand[tid + 512] = a1;
    __syncthreads();
    u64 p0 = cand[tid ^ j], p1 = cand[(tid ^ j) + 512];
    bool lo = ((tid & j) == 0);
    cex(a0, p0, lo, ((tid & kk) == 0));
    cex(a1, p1, lo, (((tid + 512u) & kk) == 0));
}

// ---------------- decode boxes (+clip) + zero akey ----------------
__global__ void decode_kernel(const float* __restrict__ anc,
                              const float* __restrict__ reg,
                              const int* __restrict__ ph,
                              const int* __restrict__ pw,
                              float* __restrict__ boxes,
                              u64* __restrict__ akey, int A)
{
    int a = blockIdx.x * blockDim.x + threadIdx.x;
    if (a >= A) return;
    akey[a] = 0;
    float x1 = anc[a*4+0], y1 = anc[a*4+1], x2 = anc[a*4+2], y2 = anc[a*4+3];
    float w = x2 - x1, h = y2 - y1;
    float cx = x1 + 0.5f*w, cy = y1 + 0.5f*h;
    float r0 = reg[a*4+0]*0.1f, r1 = reg[a*4+1]*0.1f;
    float r2 = reg[a*4+2]*0.2f, r3 = reg[a*4+3]*0.2f;
    float pcx = cx + r0*w, pcy = cy + r1*h;
    float pw_ = expf(r2)*w, ph_ = expf(r3)*h;
    float W = (float)(*pw), H = (float)(*ph);
    boxes[a*4+0] = fmaxf(pcx - 0.5f*pw_, 0.0f);
    boxes[a*4+1] = fmaxf(pcy - 0.5f*ph_, 0.0f);
    boxes[a*4+2] = fminf(pcx + 0.5f*pw_, W);
    boxes[a*4+3] = fminf(pcy + 0.5f*ph_, H);
}

// ---------------- one coalesced pass: collect s > T0G, zero global atomics ----------------
__global__ __launch_bounds__(256) void scan_collect_kernel(
    const float* __restrict__ cls,
    u64* __restrict__ gbuf, u32* __restrict__ segcnt,
    u32* __restrict__ overflow, int A)
{
    __shared__ u32 cnt[80];
    __shared__ u64 buf[80][SCAP];
    __shared__ u32 s_over;
    const int tid = threadIdx.x;
    const int blk = blockIdx.x;

    for (int i = tid; i < 80; i += 256) cnt[i] = 0;
    if (tid == 0) s_over = 0;
    __syncthreads();

    size_t Nf4 = (size_t)A * 20;   // A*80/4
    const float4* p4 = (const float4*)cls;
    for (size_t i = (size_t)blk * 256 + tid; i < Nf4; i += (size_t)NBLK * 256) {
        float4 v = p4[i];
        float ss[4] = {v.x, v.y, v.z, v.w};
        #pragma unroll
        for (int q = 0; q < 4; ++q) {
            if (ss[q] > T0G) {
                u32 flat = (u32)(i * 4 + q);
                u32 a = flat / 80u;            // const-div -> magic mul
                u32 c = flat - a * 80u;
                u32 p = atomicAdd(&cnt[c], 1u);   // LDS atomic only
                if (p < SCAP) buf[c][p] = ((u64)__float_as_uint(ss[q]) << 32) | (u32)(~a);
                else s_over = 1;
            }
        }
    }
    __syncthreads();

    for (int m = tid; m < 80 * SCAP; m += 256) {
        int c = m / SCAP, e = m - c * SCAP;
        u32 cc = cnt[c]; if (cc > SCAP) cc = SCAP;
        if ((u32)e < cc)
            gbuf[((size_t)c * NBLK + blk) * SCAP + e] = buf[c][e];
    }
    for (int c = tid; c < 80; c += 256) {
        u32 cc = cnt[c]; if (cc > SCAP) cc = SCAP;
        segcnt[(size_t)c * NBLK + blk] = cc;
    }
    if (tid == 0 && s_over) *overflow = 1;
}

// ---------------- per-class exclusive prefix over segcnt + totals ----------------
__global__ __launch_bounds__(256) void prefix_kernel(
    const u32* __restrict__ segcnt, u32* __restrict__ pref,
    u32* __restrict__ totals)
{
    const int c = blockIdx.x;
    const int tid = threadIdx.x;
    __shared__ u32 part[256];

    const u32* row = segcnt + (size_t)c * NBLK;
    u32 v[8];
    u32 s = 0;
    #pragma unroll
    for (int q = 0; q < 8; ++q) { v[q] = row[tid * 8 + q]; s += v[q]; }
    part[tid] = s;
    __syncthreads();
    for (int d = 1; d < 256; d <<= 1) {
        u32 t = (tid >= d) ? part[tid - d] : 0;
        __syncthreads();
        part[tid] += t;
        __syncthreads();
    }
    u32 running = part[tid] - s;
    u32* prow = pref + (size_t)c * NBLK;
    #pragma unroll
    for (int q = 0; q < 8; ++q) { prow[tid * 8 + q] = running; running += v[q]; }
    if (tid == 255) totals[c] = part[255];
}

// ---------------- compact: scatter (class,block) slots to dense rows ----------------
__global__ __launch_bounds__(256) void compact_kernel(
    const u32* __restrict__ segcnt, const u32* __restrict__ pref,
    const u64* __restrict__ gbuf, u64* __restrict__ gbuf2)
{
    const int b = blockIdx.x;
    const int tid = threadIdx.x;
    __shared__ u32 scnt[80], sbase[80];
    for (int c = tid; c < 80; c += 256) {
        scnt[c]  = segcnt[(size_t)c * NBLK + b];
        sbase[c] = pref[(size_t)c * NBLK + b];
    }
    __syncthreads();
    for (int m = tid; m < 80 * SCAP; m += 256) {
        int c = m / SCAP, e = m - c * SCAP;
        if ((u32)e < scnt[c]) {
            u32 p = sbase[c] + (u32)e;
            if (p < DCAP)
                gbuf2[(size_t)c * DCAP + p] = gbuf[((size_t)c * NBLK + b) * SCAP + e];
        }
    }
}

// ---------------- per-class collect: gather + register bitonic sort -> top-300 ----------------
__global__ __launch_bounds__(512) void class_collect_kernel(
    const u32* __restrict__ totals, const u64* __restrict__ gbuf2,
    const u32* __restrict__ overflow,
    const float* __restrict__ cls,     // [A][C] for slow path
    u64* __restrict__ topkeys, u32* __restrict__ topcnt, int A, int C)
{
    const int c = blockIdx.x;
    const u32 tid = threadIdx.x;
    const int lane = tid & 63;

    __shared__ u32 sh[HBINS];          // slow path histogram
    __shared__ u64 cand[CCAP];
    __shared__ u32 s_sel, s_cnt, s_rem;

    if (tid == 0) { s_sel = 0; s_cnt = 0; }
    __syncthreads();

    const bool over = (*overflow != 0);
    const u32 n = totals[c];
    u32 cnt_f = 0;
    bool fast_ok = false;

    if (!over && n >= TOPK && n <= DCAP) {
        const u64* src = gbuf2 + (size_t)c * DCAP;
        const u32 T1 = __float_as_uint(T1G);
        for (u32 i = tid; i < n; i += 512) {
            u64 e = src[i];
            bool take = ((u32)(e >> 32) > T1);
            u64 m = __ballot(take);
            int nW = __popcll(m);
            if (nW) {
                int ldr = __ffsll((unsigned long long)m) - 1;
                u32 base = 0;
                if (lane == ldr) base = atomicAdd(&s_cnt, (u32)nW);
                base = __shfl(base, ldr);
                if (take) {
                    u32 p = base + (u32)__popcll(m & ((1ull << lane) - 1ull));
                    if (p < CCAP) cand[p] = e;
                }
            }
        }
        __syncthreads();
        cnt_f = s_cnt;
        fast_ok = (cnt_f >= TOPK && cnt_f <= CCAP);
    }

    if (!fast_ok) {
        // ---- slow exact path: 2-level select over the class column ----
        __syncthreads();
        for (int i = tid; i < HBINS; i += 512) sh[i] = 0;
        if (tid == 0) s_cnt = 0;
        __syncthreads();
        for (int a = tid; a < A; a += 512) {
            float s = cls[(size_t)a * C + c];
            if (s > CLS_T) atomicAdd(&sh[bin_of_bits(__float_as_uint(s))], 1u);
        }
        __syncthreads();
        if (tid == 0) {
            u32 cum = 0; int sel = 0;
            for (int d = HBINS - 1; d >= 0; --d) {
                u32 nc = cum + sh[d];
                if (nc >= TOPK) { sel = d; break; }
                cum = nc;
            }
            s_sel = (u32)sel; s_rem = TOPK - cum;
        }
        __syncthreads();
        const u32 sel1 = s_sel;
        __syncthreads();
        for (int i = tid; i < 256; i += 512) sh[i] = 0;
        __syncthreads();
        for (int a = tid; a < A; a += 512) {
            float s = cls[(size_t)a * C + c];
            if (s > CLS_T) {
                u32 k = __float_as_uint(s) - KEY_BASE;
                u32 b = k >> 14; if (b >= HBINS) b = HBINS - 1;
                if (b == sel1) atomicAdd(&sh[(k >> 6) & 0xFF], 1u);
            }
        }
        __syncthreads();
        if (tid == 0) {
            u32 rem = s_rem, cum = 0; int sel = 0;
            for (int d = 255; d >= 0; --d) {
                u32 nc = cum + sh[d];
                if (nc >= rem) { sel = d; break; }
                cum = nc;
            }
            s_sel = (sel1 << 14) | ((u32)sel << 6);
            s_cnt = 0;
        }
        __syncthreads();
        const u32 thresh = s_sel;
        for (int a = tid; a < A; a += 512) {
            float s = cls[(size_t)a * C + c];
            if (s > CLS_T) {
                u32 bits = __float_as_uint(s);
                if (bits - KEY_BASE >= thresh) {
                    u32 p = atomicAdd(&s_cnt, 1u);
                    if (p < CCAP) cand[p] = ((u64)bits << 32) | (u32)(~(u32)a);
                }
            }
        }
        __syncthreads();
        cnt_f = s_cnt < CCAP ? s_cnt : CCAP;
    }

    // ---- pad + register bitonic sort of 1024 (2 elems/thread), descending ----
    for (u32 i = cnt_f + tid; i < CCAP; i += 512) cand[i] = 0;
    __syncthreads();
    u64 a0 = cand[tid], a1 = cand[tid + 512];
    for (u32 kk = 2; kk <= 64; kk <<= 1)
        for (u32 j = kk >> 1; j >= 1; j >>= 1)
            sstep(a0, a1, tid, kk, j);
    lstep(cand, a0, a1, tid, 128u, 64u);
    for (u32 j = 32; j >= 1; j >>= 1) sstep(a0, a1, tid, 128u, j);
    lstep(cand, a0, a1, tid, 256u, 128u);
    lstep(cand, a0, a1, tid, 256u, 64u);
    for (u32 j = 32; j >= 1; j >>= 1) sstep(a0, a1, tid, 256u, j);
    lstep(cand, a0, a1, tid, 512u, 256u);
    lstep(cand, a0, a1, tid, 512u, 128u);
    lstep(cand, a0, a1, tid, 512u, 64u);
    for (u32 j = 32; j >= 1; j >>= 1) sstep(a0, a1, tid, 512u, j);
    {   // kk=1024, j=512: in-thread exchange (up = true for tid<512)
        u64 mx = a0 > a1 ? a0 : a1, mn = a0 > a1 ? a1 : a0;
        a0 = mx; a1 = mn;
    }
    lstep(cand, a0, a1, tid, 1024u, 256u);
    lstep(cand, a0, a1, tid, 1024u, 128u);
    lstep(cand, a0, a1, tid, 1024u, 64u);
    for (u32 j = 32; j >= 1; j >>= 1) sstep(a0, a1, tid, 1024u, j);
    // thread tid holds sorted element tid in a0

    const int T = (int)(cnt_f < TOPK ? cnt_f : TOPK);
    if ((int)tid < T) topkeys[(size_t)c * TOPK + tid] = a0;
    if (tid == 0) topcnt[c] = (u32)T;
}

// ---------------- per-class NMS: colmask + round-parallel ballot greedy ----------------
__global__ __launch_bounds__(320) void class_nms2_kernel(
    const u64* __restrict__ topkeys, const u32* __restrict__ topcnt,
    const float* __restrict__ boxes, u64* __restrict__ akey, int C)
{
    const int c = blockIdx.x;
    const u32 tid = threadIdx.x;
    const int lane = tid & 63;

    __shared__ float bx1[TOPK], by1[TOPK], bx2[TOPK], by2[TOPK], bar[TOPK];
    __shared__ u64 iomaskT[NWORDS][TOPK];   // transposed colmask: [word][box]
    __shared__ u64 s_keep[NWORDS];

    const int T = (int)topcnt[c];

    u64 key = 0; u32 aidx = 0;
    if ((int)tid < T) {
        key = topkeys[(size_t)c * TOPK + tid];
        aidx = ~(u32)(key & 0xFFFFFFFFull);
        float4 b4 = *(const float4*)(boxes + (size_t)aidx * 4);
        bx1[tid] = b4.x; by1[tid] = b4.y; bx2[tid] = b4.z; by2[tid] = b4.w;
        bar[tid] = fmaxf(b4.z - b4.x, 0.0f) * fmaxf(b4.w - b4.y, 0.0f);
    }
    __syncthreads();

    // colmask: which i<tid suppress me (IoU>0.5) -> iomaskT[w][tid]
    {
        u64 cm[NWORDS] = {0,0,0,0,0};
        if ((int)tid < T) {
            float x1 = bx1[tid], y1 = by1[tid], x2 = bx2[tid], y2 = by2[tid], ar = bar[tid];
            for (int i = 0; i < (int)tid; ++i) {
                float iw = fmaxf(fminf(x2, bx2[i]) - fmaxf(x1, bx1[i]), 0.0f);
                float ih = fmaxf(fminf(y2, by2[i]) - fmaxf(y1, by1[i]), 0.0f);
                float inter = iw * ih;
                float uni = ((ar + bar[i]) - inter) + 1e-8f;
                float q = inter - 0.5f * uni;       // 0.5*uni exact; sign(q) exact
                bool sup;
                if (fabsf(q) > 1e-5f * uni) sup = (q > 0.0f);
                else sup = (inter / uni > 0.5f);    // rare boundary: exact semantics
                if (sup) cm[i >> 6] |= 1ull << (i & 63);
            }
            #pragma unroll
            for (int w = 0; w < NWORDS; ++w) iomaskT[w][tid] = cm[w];
        }
    }
    __syncthreads();

    // wave 0: word-serial, round-parallel ballot greedy.
    // Per word: U = undecided; each round decides every U-box whose in-word
    // suppressor set is fully decided (newk), then drops boxes suppressed by kept.
    if (tid < 64) {
        u64 K0 = 0, K1 = 0, K2 = 0, K3 = 0, K4 = 0;
        // ---- word 0 ----
        {
            bool valid = (lane < T);
            u64 cmw = valid ? iomaskT[0][lane] : 0;
            u64 U = __ballot(valid);
            u64 Kw = 0;
            int guard = 0;
            while (U && guard++ < 64) {
                u64 newk = __ballot(((U >> lane) & 1ull) && ((cmw & U) == 0));
                Kw |= newk; U &= ~newk;
                u64 supp = __ballot((cmw & Kw) != 0);
                U &= ~supp;
            }
            K0 = Kw;
        }
        // ---- word 1 ----
        {
            int b = 64 + lane; bool valid = (b < T);
            u64 cmw = 0, se = 0;
            if (valid) { se = K0 & iomaskT[0][b]; cmw = iomaskT[1][b]; }
            u64 U = __ballot(valid && se == 0);
            u64 Kw = 0;
            int guard = 0;
            while (U && guard++ < 64) {
                u64 newk = __ballot(((U >> lane) & 1ull) && ((cmw & U) == 0));
                Kw |= newk; U &= ~newk;
                u64 supp = __ballot((cmw & Kw) != 0);
                U &= ~supp;
            }
            K1 = Kw;
        }
        // ---- word 2 ----
        {
            int b = 128 + lane; bool valid = (b < T);
            u64 cmw = 0, se = 0;
            if (valid) {
                se  = K0 & iomaskT[0][b];
                se |= K1 & iomaskT[1][b];
                cmw = iomaskT[2][b];
            }
            u64 U = __ballot(valid && se == 0);
            u64 Kw = 0;
            int guard = 0;
            while (U && guard++ < 64) {
                u64 newk = __ballot(((U >> lane) & 1ull) && ((cmw & U) == 0));
                Kw |= newk; U &= ~newk;
                u64 supp = __ballot((cmw & Kw) != 0);
                U &= ~supp;
            }
            K2 = Kw;
        }
        // ---- word 3 ----
        {
            int b = 192 + lane; bool valid = (b < T);
            u64 cmw = 0, se = 0;
            if (valid) {
                se  = K0 & iomaskT[0][b];
                se |= K1 & iomaskT[1][b];
                se |= K2 & iomaskT[2][b];
                cmw = iomaskT[3][b];
            }
            u64 U = __ballot(valid && se == 0);
            u64 Kw = 0;
            int guard = 0;
            while (U && guard++ < 64) {
                u64 newk = __ballot(((U >> lane) & 1ull) && ((cmw & U) == 0));
                Kw |= newk; U &= ~newk;
                u64 supp = __ballot((cmw & Kw) != 0);
                U &= ~supp;
            }
            K3 = Kw;
        }
        // ---- word 4 ----
        {
            int b = 256 + lane; bool valid = (b < T);
            u64 cmw = 0, se = 0;
            if (valid) {
                se  = K0 & iomaskT[0][b];
                se |= K1 & iomaskT[1][b];
                se |= K2 & iomaskT[2][b];
                se |= K3 & iomaskT[3][b];
                cmw = iomaskT[4][b];
            }
            u64 U = __ballot(valid && se == 0);
            u64 Kw = 0;
            int guard = 0;
            while (U && guard++ < 64) {
                u64 newk = __ballot(((U >> lane) & 1ull) && ((cmw & U) == 0));
                Kw |= newk; U &= ~newk;
                u64 supp = __ballot((cmw & Kw) != 0);
                U &= ~supp;
            }
            K4 = Kw;
        }
        if (lane == 0) {
            s_keep[0] = K0; s_keep[1] = K1; s_keep[2] = K2;
            s_keep[3] = K3; s_keep[4] = K4;
        }
    }
    __syncthreads();

    if ((int)tid < T) {
        if ((s_keep[tid >> 6] >> (tid & 63)) & 1ull) {
            u32 sbits = (u32)(key >> 32);
            u64 outk = ((u64)sbits << 32) | (u32)(255 - c);
            atomicMax(&akey[aidx], outk);
        }
    }
}

// ---------------- finalize ----------------
__global__ void finalize_kernel(const u64* __restrict__ akey,
                                float* __restrict__ out, int A)
{
    int a = blockIdx.x * blockDim.x + threadIdx.x;
    if (a >= A) return;
    float* scores = out;
    float* labels = out + A;
    float* boxes  = out + (size_t)2 * A;
    u64 k = akey[a];
    if (k) {
        scores[a] = __uint_as_float((u32)(k >> 32));
        labels[a] = (float)(int)(255u - (u32)(k & 0xFFFFFFFFull));
    } else {
        scores[a] = 0.0f;
        labels[a] = -1.0f;
        boxes[(size_t)a*4+0] = 0.0f;
        boxes[(size_t)a*4+1] = 0.0f;
        boxes[(size_t)a*4+2] = 0.0f;
        boxes[(size_t)a*4+3] = 0.0f;
    }
}

// ---------------- fallback (generic C / small ws): round-1 proven kernel ----------------
#define FB_CAP 1024
__global__ __launch_bounds__(256) void fb_topk_nms_kernel(
    const float* __restrict__ cls,
    const float* __restrict__ boxes,
    u64* __restrict__ akey,
    int A, int C)
{
    const int c   = blockIdx.x;
    const int tid = threadIdx.x;

    __shared__ u32 hist[HBINS];
    __shared__ u64 cand[FB_CAP];
    __shared__ float bx1[TOPK], by1[TOPK], bx2[TOPK], by2[TOPK], bar[TOPK];
    __shared__ u64 iomask[TOPK][NWORDS];
    __shared__ u64 keepm[NWORDS];
    __shared__ u32 s_sel1, s_sel2, s_rem, s_cnt;

    for (int i = tid; i < HBINS; i += 256) hist[i] = 0;
    __syncthreads();
    for (int a = tid; a < A; a += 256) {
        float s = cls[(size_t)a * C + c];
        if (s > CLS_T) {
            u32 k = __float_as_uint(s) - KEY_BASE;
            u32 b = k >> 14; if (b >= HBINS) b = HBINS - 1;
            atomicAdd(&hist[b], 1u);
        }
    }
    __syncthreads();
    if (tid == 0) {
        u32 cum = 0; int sel = 0;
        for (int d = HBINS - 1; d >= 0; --d) {
            u32 nc = cum + hist[d];
            if (nc >= TOPK) { sel = d; break; }
            cum = nc;
        }
        s_sel1 = (u32)sel; s_rem = TOPK - cum;
    }
    __syncthreads();
    const u32 sel1 = s_sel1;

    for (int i = tid; i < 256; i += 256) hist[i] = 0;
    __syncthreads();
    for (int a = tid; a < A; a += 256) {
        float s = cls[(size_t)a * C + c];
        if (s > CLS_T) {
            u32 k = __float_as_uint(s) - KEY_BASE;
            u32 b = k >> 14; if (b >= HBINS) b = HBINS - 1;
            if (b == sel1) atomicAdd(&hist[(k >> 6) & 0xFF], 1u);
        }
    }
    __syncthreads();
    if (tid == 0) {
        u32 rem = s_rem, cum = 0; int sel = 0;
        for (int d = 255; d >= 0; --d) {
            u32 nc = cum + hist[d];
            if (nc >= rem) { sel = d; break; }
            cum = nc;
        }
        s_sel2 = (u32)sel; s_cnt = 0;
    }
    __syncthreads();
    const u32 thresh = (sel1 << 14) | (s_sel2 << 6);

    for (int a = tid; a < A; a += 256) {
        float s = cls[(size_t)a * C + c];
        if (s > CLS_T) {
            u32 bits = __float_as_uint(s);
            u32 k = bits - KEY_BASE;
            if (k >= thresh) {
                u32 pos = atomicAdd(&s_cnt, 1u);
                if (pos < FB_CAP) cand[pos] = ((u64)bits << 32) | (u32)(~(u32)a);
            }
        }
    }
    __syncthreads();
    const u32 total = s_cnt < FB_CAP ? s_cnt : FB_CAP;
    for (int i = tid; i < FB_CAP; i += 256)
        if (i >= (int)total) cand[i] = 0;
    __syncthreads();

    for (u32 kk = 2; kk <= FB_CAP; kk <<= 1) {
        for (u32 j = kk >> 1; j > 0; j >>= 1) {
            for (u32 i = tid; i < FB_CAP; i += 256) {
                u32 l = i ^ j;
                if (l > i) {
                    u64 av = cand[i], bv = cand[l];
                    bool up = ((i & kk) == 0);
                    if ((up && av < bv) || (!up && av > bv)) { cand[i] = bv; cand[l] = av; }
                }
            }
            __syncthreads();
        }
    }
    const int T = (int)(total < TOPK ? total : TOPK);

    for (int i = tid; i < T; i += 256) {
        u32 a = ~(u32)(cand[i] & 0xFFFFFFFFull);
        float x1 = boxes[(size_t)a*4+0], y1 = boxes[(size_t)a*4+1];
        float x2 = boxes[(size_t)a*4+2], y2 = boxes[(size_t)a*4+3];
        bx1[i] = x1; by1[i] = y1; bx2[i] = x2; by2[i] = y2;
        bar[i] = fmaxf(x2 - x1, 0.0f) * fmaxf(y2 - y1, 0.0f);
    }
    __syncthreads();

    for (int i = tid; i < T; i += 256) {
        u64 m[NWORDS] = {0,0,0,0,0};
        float x1 = bx1[i], y1 = by1[i], x2 = bx2[i], y2 = by2[i], ai = bar[i];
        for (int j = i + 1; j < T; ++j) {
            float iw = fmaxf(fminf(x2, bx2[j]) - fmaxf(x1, bx1[j]), 0.0f);
            float ih = fmaxf(fminf(y2, by2[j]) - fmaxf(y1, by1[j]), 0.0f);
            float inter = iw * ih;
            float uni = ((ai + bar[j]) - inter) + 1e-8f;
            if (inter / uni > 0.5f) m[j >> 6] |= 1ull << (j & 63);
        }
        for (int k2 = 0; k2 < NWORDS; ++k2) iomask[i][k2] = m[k2];
    }
    __syncthreads();

    if (tid == 0) {
        u64 sup[NWORDS] = {0,0,0,0,0};
        u64 kp [NWORDS] = {0,0,0,0,0};
        for (int i = 0; i < T; ++i) {
            if (!((sup[i >> 6] >> (i & 63)) & 1ull)) {
                kp[i >> 6] |= 1ull << (i & 63);
                for (int k2 = 0; k2 < NWORDS; ++k2) sup[k2] |= iomask[i][k2];
            }
        }
        for (int k2 = 0; k2 < NWORDS; ++k2) keepm[k2] = kp[k2];
    }
    __syncthreads();

    for (int i = tid; i < T; i += 256) {
        if ((keepm[i >> 6] >> (i & 63)) & 1ull) {
            u64 key = cand[i];
            u32 a = ~(u32)(key & 0xFFFFFFFFull);
            u32 sbits = (u32)(key >> 32);
            u64 outk = ((u64)sbits << 32) | (u32)(255 - c);
            atomicMax(&akey[a], outk);
        }
    }
}

extern "C" void kernel_launch(void* const* d_in, const int* in_sizes, int n_in,
                              void* d_out, int out_size, void* d_ws, size_t ws_size,
                              hipStream_t stream) {
    const float* cls = (const float*)d_in[0];
    const float* reg = (const float*)d_in[1];
    const float* anc = (const float*)d_in[2];
    const int*   ph  = (const int*)d_in[3];
    const int*   pw  = (const int*)d_in[4];

    int A = in_sizes[2] / 4;
    int C = in_sizes[0] / A;

    float* out       = (float*)d_out;
    float* out_boxes = out + (size_t)2 * A;

    // workspace: akey | overflow | segcnt | pref | totals | topcnt | topkeys | gbuf | gbuf2
    size_t akey_bytes = (size_t)A * sizeof(u64);
    size_t off_of     = (akey_bytes + 255) & ~(size_t)255;
    size_t off_sc     = (off_of + 256 + 255) & ~(size_t)255;
    size_t sc_bytes   = (size_t)80 * NBLK * sizeof(u32);
    size_t off_pf     = (off_sc + sc_bytes + 255) & ~(size_t)255;
    size_t off_tt     = (off_pf + sc_bytes + 255) & ~(size_t)255;
    size_t tt_bytes   = 80 * sizeof(u32);
    size_t off_tc     = (off_tt + tt_bytes + 255) & ~(size_t)255;
    size_t tc_bytes   = 80 * sizeof(u32);
    size_t off_tk     = (off_tc + tc_bytes + 255) & ~(size_t)255;
    size_t tk_bytes   = (size_t)80 * TOPK * sizeof(u64);
    size_t off_gb     = (off_tk + tk_bytes + 255) & ~(size_t)255;
    size_t gb_bytes   = (size_t)80 * NBLK * SCAP * sizeof(u64);
    size_t off_g2     = (off_gb + gb_bytes + 255) & ~(size_t)255;
    size_t g2_bytes   = (size_t)80 * DCAP * sizeof(u64);
    size_t need       = off_g2 + g2_bytes;

    u64* akey = (u64*)d_ws;

    decode_kernel<<<(A + 255) / 256, 256, 0, stream>>>(anc, reg, ph, pw, out_boxes, akey, A);

    bool fastpath = (C == 80) && ((A & 3) == 0) && (A < (1 << 20)) && (ws_size >= need);
    if (fastpath) {
        u32* overflow = (u32*)((char*)d_ws + off_of);
        u32* segcnt   = (u32*)((char*)d_ws + off_sc);
        u32* pref     = (u32*)((char*)d_ws + off_pf);
        u32* totals   = (u32*)((char*)d_ws + off_tt);
        u32* topcnt   = (u32*)((char*)d_ws + off_tc);
        u64* topkeys  = (u64*)((char*)d_ws + off_tk);
        u64* gbuf     = (u64*)((char*)d_ws + off_gb);
        u64* gbuf2    = (u64*)((char*)d_ws + off_g2);

        hipMemsetAsync(overflow, 0, sizeof(u32), stream);
        scan_collect_kernel<<<NBLK, 256, 0, stream>>>(cls, gbuf, segcnt, overflow, A);
        prefix_kernel<<<80, 256, 0, stream>>>(segcnt, pref, totals);
        compact_kernel<<<NBLK, 256, 0, stream>>>(segcnt, pref, gbuf, gbuf2);
        class_collect_kernel<<<C, 512, 0, stream>>>(totals, gbuf2, overflow, cls, topkeys, topcnt, A, C);
        class_nms2_kernel<<<C, 320, 0, stream>>>(topkeys, topcnt, out_boxes, akey, C);
    } else {
        fb_topk_nms_kernel<<<C, 256, 0, stream>>>(cls, out_boxes, akey, A, C);
    }

    finalize_kernel<<<(A + 255) / 256, 256, 0, stream>>>(akey, out, A);
}

// Round 12
// 79.833 us; speedup vs baseline: 2.1072x; 1.2511x over previous
//
#include <hip/hip_runtime.h>
#include <cstdint>

typedef unsigned long long u64;
typedef unsigned int u32;

#define CLS_T    0.05f
#define T0G      0.98f      // collect threshold (pass 1)
#define T1G      0.9965f    // candidate filter threshold (pass 2)
#define TOPK     300
#define NWORDS   5          // ceil(300/64)
#define HBINS    2560
#define KEY_BASE 0x3D000000u
#define CCAP     1024
#define NBLK     2048       // scan blocks
#define SCAP     24         // slots per (class, scan-block)
#define DCAP     8192       // dense per-class capacity

__device__ inline u32 bin_of_bits(u32 bits) {
    u32 b = (bits - KEY_BASE) >> 14;
    if (b > (HBINS - 1)) b = HBINS - 1;
    return b;
}

// compare-exchange for register bitonic: keep max if (lo==up), else min
__device__ inline void cex(u64& v, u64 p, bool lo, bool up) {
    u64 mx = v > p ? v : p;
    u64 mn = v > p ? p : v;
    v = (lo == up) ? mx : mn;
}
__device__ inline void sstep(u64& a0, u64& a1, u32 tid, u32 kk, u32 j) {
    u64 p0 = __shfl_xor((unsigned long long)a0, (int)j, 64);
    u64 p1 = __shfl_xor((unsigned long long)a1, (int)j, 64);
    bool lo = ((tid & j) == 0);
    cex(a0, p0, lo, ((tid & kk) == 0));
    cex(a1, p1, lo, (((tid + 512u) & kk) == 0));
}
__device__ inline void lstep(u64* cand, u64& a0, u64& a1, u32 tid, u32 kk, u32 j) {
    __syncthreads();
    cand[tid] = a0; cand[tid + 512] = a1;
    __syncthreads();
    u64 p0 = cand[tid ^ j], p1 = cand[(tid ^ j) + 512];
    bool lo = ((tid & j) == 0);
    cex(a0, p0, lo, ((tid & kk) == 0));
    cex(a1, p1, lo, (((tid + 512u) & kk) == 0));
}

// ---------------- decode boxes (+clip) + zero akey ----------------
__global__ void decode_kernel(const float* __restrict__ anc,
                              const float* __restrict__ reg,
                              const int* __restrict__ ph,
                              const int* __restrict__ pw,
                              float* __restrict__ boxes,
                              u64* __restrict__ akey, int A)
{
    int a = blockIdx.x * blockDim.x + threadIdx.x;
    if (a >= A) return;
    akey[a] = 0;
    float x1 = anc[a*4+0], y1 = anc[a*4+1], x2 = anc[a*4+2], y2 = anc[a*4+3];
    float w = x2 - x1, h = y2 - y1;
    float cx = x1 + 0.5f*w, cy = y1 + 0.5f*h;
    float r0 = reg[a*4+0]*0.1f, r1 = reg[a*4+1]*0.1f;
    float r2 = reg[a*4+2]*0.2f, r3 = reg[a*4+3]*0.2f;
    float pcx = cx + r0*w, pcy = cy + r1*h;
    float pw_ = expf(r2)*w, ph_ = expf(r3)*h;
    float W = (float)(*pw), H = (float)(*ph);
    boxes[a*4+0] = fmaxf(pcx - 0.5f*pw_, 0.0f);
    boxes[a*4+1] = fmaxf(pcy - 0.5f*ph_, 0.0f);
    boxes[a*4+2] = fminf(pcx + 0.5f*pw_, W);
    boxes[a*4+3] = fminf(pcy + 0.5f*ph_, H);
}

// ---------------- one coalesced pass: collect s > T0G, zero global atomics ----------------
__global__ __launch_bounds__(256) void scan_collect_kernel(
    const float* __restrict__ cls,
    u64* __restrict__ gbuf, u32* __restrict__ segcnt,
    u32* __restrict__ overflow, int A)
{
    __shared__ u32 cnt[80];
    __shared__ u64 buf[80][SCAP];
    __shared__ u32 s_over;
    const int tid = threadIdx.x;
    const int blk = blockIdx.x;

    for (int i = tid; i < 80; i += 256) cnt[i] = 0;
    if (tid == 0) s_over = 0;
    __syncthreads();

    size_t Nf4 = (size_t)A * 20;   // A*80/4
    const float4* p4 = (const float4*)cls;
    for (size_t i = (size_t)blk * 256 + tid; i < Nf4; i += (size_t)NBLK * 256) {
        float4 v = p4[i];
        float ss[4] = {v.x, v.y, v.z, v.w};
        #pragma unroll
        for (int q = 0; q < 4; ++q) {
            if (ss[q] > T0G) {
                u32 flat = (u32)(i * 4 + q);
                u32 a = flat / 80u;            // const-div -> magic mul
                u32 c = flat - a * 80u;
                u32 p = atomicAdd(&cnt[c], 1u);   // LDS atomic only
                if (p < SCAP) buf[c][p] = ((u64)__float_as_uint(ss[q]) << 32) | (u32)(~a);
                else s_over = 1;
            }
        }
    }
    __syncthreads();

    for (int m = tid; m < 80 * SCAP; m += 256) {
        int c = m / SCAP, e = m - c * SCAP;
        u32 cc = cnt[c]; if (cc > SCAP) cc = SCAP;
        if ((u32)e < cc)
            gbuf[((size_t)c * NBLK + blk) * SCAP + e] = buf[c][e];
    }
    for (int c = tid; c < 80; c += 256) {
        u32 cc = cnt[c]; if (cc > SCAP) cc = SCAP;
        segcnt[(size_t)c * NBLK + blk] = cc;
    }
    if (tid == 0 && s_over) *overflow = 1;
}

// ---------------- per-class exclusive prefix over segcnt + totals ----------------
__global__ __launch_bounds__(256) void prefix_kernel(
    const u32* __restrict__ segcnt, u32* __restrict__ pref,
    u32* __restrict__ totals)
{
    const int c = blockIdx.x;
    const int tid = threadIdx.x;
    __shared__ u32 part[256];

    const u32* row = segcnt + (size_t)c * NBLK;
    u32 v[8];
    u32 s = 0;
    #pragma unroll
    for (int q = 0; q < 8; ++q) { v[q] = row[tid * 8 + q]; s += v[q]; }
    part[tid] = s;
    __syncthreads();
    for (int d = 1; d < 256; d <<= 1) {
        u32 t = (tid >= d) ? part[tid - d] : 0;
        __syncthreads();
        part[tid] += t;
        __syncthreads();
    }
    u32 running = part[tid] - s;
    u32* prow = pref + (size_t)c * NBLK;
    #pragma unroll
    for (int q = 0; q < 8; ++q) { prow[tid * 8 + q] = running; running += v[q]; }
    if (tid == 255) totals[c] = part[255];
}

// ---------------- compact: scatter (class,block) slots to dense rows ----------------
__global__ __launch_bounds__(256) void compact_kernel(
    const u32* __restrict__ segcnt, const u32* __restrict__ pref,
    const u64* __restrict__ gbuf, u64* __restrict__ gbuf2)
{
    const int b = blockIdx.x;
    const int tid = threadIdx.x;
    __shared__ u32 scnt[80], sbase[80];
    for (int c = tid; c < 80; c += 256) {
        scnt[c]  = segcnt[(size_t)c * NBLK + b];
        sbase[c] = pref[(size_t)c * NBLK + b];
    }
    __syncthreads();
    for (int m = tid; m < 80 * SCAP; m += 256) {
        int c = m / SCAP, e = m - c * SCAP;
        if ((u32)e < scnt[c]) {
            u32 p = sbase[c] + (u32)e;
            if (p < DCAP)
                gbuf2[(size_t)c * DCAP + p] = gbuf[((size_t)c * NBLK + b) * SCAP + e];
        }
    }
}

// ---------------- per-class collect: gather + register bitonic sort -> top-300 ----------------
__global__ __launch_bounds__(512) void class_collect_kernel(
    const u32* __restrict__ totals, const u64* __restrict__ gbuf2,
    const u32* __restrict__ overflow,
    const float* __restrict__ cls,     // [A][C] for slow path
    u64* __restrict__ topkeys, u32* __restrict__ topcnt, int A, int C)
{
    const int c = blockIdx.x;
    const u32 tid = threadIdx.x;
    const int lane = tid & 63;

    __shared__ u32 sh[HBINS];          // slow path histogram
    __shared__ u64 cand[CCAP];
    __shared__ u32 s_sel, s_cnt, s_rem;

    if (tid == 0) { s_sel = 0; s_cnt = 0; }
    __syncthreads();

    const bool over = (*overflow != 0);
    const u32 n = totals[c];
    u32 cnt_f = 0;
    bool fast_ok = false;

    if (!over && n >= TOPK && n <= DCAP) {
        const u64* src = gbuf2 + (size_t)c * DCAP;
        const u32 T1 = __float_as_uint(T1G);
        for (u32 i = tid; i < n; i += 512) {
            u64 e = src[i];
            bool take = ((u32)(e >> 32) > T1);
            u64 m = __ballot(take);
            int nW = __popcll(m);
            if (nW) {
                int ldr = __ffsll((unsigned long long)m) - 1;
                u32 base = 0;
                if (lane == ldr) base = atomicAdd(&s_cnt, (u32)nW);
                base = __shfl(base, ldr);
                if (take) {
                    u32 p = base + (u32)__popcll(m & ((1ull << lane) - 1ull));
                    if (p < CCAP) cand[p] = e;
                }
            }
        }
        __syncthreads();
        cnt_f = s_cnt;
        fast_ok = (cnt_f >= TOPK && cnt_f <= CCAP);
    }

    if (!fast_ok) {
        // ---- slow exact path: 2-level select over the class column ----
        __syncthreads();
        for (int i = tid; i < HBINS; i += 512) sh[i] = 0;
        if (tid == 0) s_cnt = 0;
        __syncthreads();
        for (int a = tid; a < A; a += 512) {
            float s = cls[(size_t)a * C + c];
            if (s > CLS_T) atomicAdd(&sh[bin_of_bits(__float_as_uint(s))], 1u);
        }
        __syncthreads();
        if (tid == 0) {
            u32 cum = 0; int sel = 0;
            for (int d = HBINS - 1; d >= 0; --d) {
                u32 nc = cum + sh[d];
                if (nc >= TOPK) { sel = d; break; }
                cum = nc;
            }
            s_sel = (u32)sel; s_rem = TOPK - cum;
        }
        __syncthreads();
        const u32 sel1 = s_sel;
        __syncthreads();
        for (int i = tid; i < 256; i += 512) sh[i] = 0;
        __syncthreads();
        for (int a = tid; a < A; a += 512) {
            float s = cls[(size_t)a * C + c];
            if (s > CLS_T) {
                u32 k = __float_as_uint(s) - KEY_BASE;
                u32 b = k >> 14; if (b >= HBINS) b = HBINS - 1;
                if (b == sel1) atomicAdd(&sh[(k >> 6) & 0xFF], 1u);
            }
        }
        __syncthreads();
        if (tid == 0) {
            u32 rem = s_rem, cum = 0; int sel = 0;
            for (int d = 255; d >= 0; --d) {
                u32 nc = cum + sh[d];
                if (nc >= rem) { sel = d; break; }
                cum = nc;
            }
            s_sel = (sel1 << 14) | ((u32)sel << 6);
            s_cnt = 0;
        }
        __syncthreads();
        const u32 thresh = s_sel;
        for (int a = tid; a < A; a += 512) {
            float s = cls[(size_t)a * C + c];
            if (s > CLS_T) {
                u32 bits = __float_as_uint(s);
                if (bits - KEY_BASE >= thresh) {
                    u32 p = atomicAdd(&s_cnt, 1u);
                    if (p < CCAP) cand[p] = ((u64)bits << 32) | (u32)(~(u32)a);
                }
            }
        }
        __syncthreads();
        cnt_f = s_cnt < CCAP ? s_cnt : CCAP;
    }

    // ---- pad + register bitonic sort of 1024 (2 elems/thread), descending ----
    for (u32 i = cnt_f + tid; i < CCAP; i += 512) cand[i] = 0;
    __syncthreads();
    u64 a0 = cand[tid], a1 = cand[tid + 512];
    for (u32 kk = 2; kk <= 64; kk <<= 1)
        for (u32 j = kk >> 1; j >= 1; j >>= 1)
            sstep(a0, a1, tid, kk, j);
    lstep(cand, a0, a1, tid, 128u, 64u);
    for (u32 j = 32; j >= 1; j >>= 1) sstep(a0, a1, tid, 128u, j);
    lstep(cand, a0, a1, tid, 256u, 128u);
    lstep(cand, a0, a1, tid, 256u, 64u);
    for (u32 j = 32; j >= 1; j >>= 1) sstep(a0, a1, tid, 256u, j);
    lstep(cand, a0, a1, tid, 512u, 256u);
    lstep(cand, a0, a1, tid, 512u, 128u);
    lstep(cand, a0, a1, tid, 512u, 64u);
    for (u32 j = 32; j >= 1; j >>= 1) sstep(a0, a1, tid, 512u, j);
    {   // kk=1024, j=512: in-thread exchange (up = true for tid<512)
        u64 mx = a0 > a1 ? a0 : a1, mn = a0 > a1 ? a1 : a0;
        a0 = mx; a1 = mn;
    }
    lstep(cand, a0, a1, tid, 1024u, 256u);
    lstep(cand, a0, a1, tid, 1024u, 128u);
    lstep(cand, a0, a1, tid, 1024u, 64u);
    for (u32 j = 32; j >= 1; j >>= 1) sstep(a0, a1, tid, 1024u, j);
    // thread tid holds sorted element tid in a0

    const int T = (int)(cnt_f < TOPK ? cnt_f : TOPK);
    if ((int)tid < T) topkeys[(size_t)c * TOPK + tid] = a0;
    if (tid == 0) topcnt[c] = (u32)T;
}

// ---------------- per-class NMS: split branchless colmask + ballot greedy ----------------
__global__ __launch_bounds__(640) void class_nms2_kernel(
    const u64* __restrict__ topkeys, const u32* __restrict__ topcnt,
    const float* __restrict__ boxes, u64* __restrict__ akey, int C)
{
    const int c = blockIdx.x;
    const u32 tid = threadIdx.x;
    const int lane = tid & 63;

    __shared__ float4 sbox[TOPK];
    __shared__ float  sbar[TOPK];
    __shared__ u64 iomaskT[NWORDS][TOPK];   // transposed colmask: [word][box]
    __shared__ u64 s_keep[NWORDS];

    const int T = (int)topcnt[c];

    u64 key = 0; u32 aidx = 0;
    if ((int)tid < T) {
        key = topkeys[(size_t)c * TOPK + tid];
        aidx = ~(u32)(key & 0xFFFFFFFFull);
        float4 b4 = *(const float4*)(boxes + (size_t)aidx * 4);
        sbox[tid] = b4;
        sbar[tid] = fmaxf(b4.z - b4.x, 0.0f) * fmaxf(b4.w - b4.y, 0.0f);
    }
    for (int m = tid; m < NWORDS * TOPK; m += 640) ((u64*)iomaskT)[m] = 0;
    __syncthreads();

    // colmask: row jj, parity p -> which i<jj suppress jj (IoU>0.5), branchless
    {
        const int jj = (int)(tid < 320 ? tid : tid - 320);
        const int p  = (int)(tid < 320 ? 0 : 1);
        if (jj < T) {
            float4 b = sbox[jj];
            float ar = sbar[jj];
            u64 cm[NWORDS] = {0,0,0,0,0};
            for (int i = p; i < jj; i += 2) {
                float4 bi = sbox[i];
                float iw = fmaxf(fminf(b.z, bi.z) - fmaxf(b.x, bi.x), 0.0f);
                float ih = fmaxf(fminf(b.w, bi.w) - fmaxf(b.y, bi.y), 0.0f);
                float inter = iw * ih;
                float uni = ((ar + sbar[i]) - inter) + 1e-8f;
                if (inter / uni > 0.5f) cm[i >> 6] |= 1ull << (i & 63);
            }
            #pragma unroll
            for (int w = 0; w < NWORDS; ++w)
                if (cm[w]) atomicOr(&iomaskT[w][jj], cm[w]);
        }
    }
    __syncthreads();

    // wave 0: word-serial, round-parallel ballot greedy
    if (tid < 64) {
        u64 K[NWORDS];
        #pragma unroll
        for (int w = 0; w < NWORDS; ++w) {
            int b = w * 64 + lane;
            bool valid = (b < T);
            u64 cmw = 0, se = 0;
            if (valid) {
                #pragma unroll
                for (int w2 = 0; w2 < NWORDS; ++w2)
                    if (w2 < w) se |= K[w2] & iomaskT[w2][b];
                cmw = iomaskT[w][b];
            }
            u64 U = __ballot(valid && se == 0);
            u64 Kw = 0;
            int guard = 0;
            while (U && guard++ < 64) {
                u64 newk = __ballot(((U >> lane) & 1ull) && ((cmw & U) == 0));
                Kw |= newk; U &= ~newk;
                u64 supp = __ballot((cmw & Kw) != 0);
                U &= ~supp;
            }
            K[w] = Kw;
        }
        if (lane == 0) {
            #pragma unroll
            for (int w = 0; w < NWORDS; ++w) s_keep[w] = K[w];
        }
    }
    __syncthreads();

    if ((int)tid < T) {
        if ((s_keep[tid >> 6] >> (tid & 63)) & 1ull) {
            u32 sbits = (u32)(key >> 32);
            u64 outk = ((u64)sbits << 32) | (u32)(255 - c);
            atomicMax(&akey[aidx], outk);
        }
    }
}

// ---------------- finalize ----------------
__global__ void finalize_kernel(const u64* __restrict__ akey,
                                float* __restrict__ out, int A)
{
    int a = blockIdx.x * blockDim.x + threadIdx.x;
    if (a >= A) return;
    float* scores = out;
    float* labels = out + A;
    float* boxes  = out + (size_t)2 * A;
    u64 k = akey[a];
    if (k) {
        scores[a] = __uint_as_float((u32)(k >> 32));
        labels[a] = (float)(int)(255u - (u32)(k & 0xFFFFFFFFull));
    } else {
        scores[a] = 0.0f;
        labels[a] = -1.0f;
        boxes[(size_t)a*4+0] = 0.0f;
        boxes[(size_t)a*4+1] = 0.0f;
        boxes[(size_t)a*4+2] = 0.0f;
        boxes[(size_t)a*4+3] = 0.0f;
    }
}

// ---------------- fallback (generic C / small ws): round-1 proven kernel ----------------
#define FB_CAP 1024
__global__ __launch_bounds__(256) void fb_topk_nms_kernel(
    const float* __restrict__ cls,
    const float* __restrict__ boxes,
    u64* __restrict__ akey,
    int A, int C)
{
    const int c   = blockIdx.x;
    const int tid = threadIdx.x;

    __shared__ u32 hist[HBINS];
    __shared__ u64 cand[FB_CAP];
    __shared__ float bx1[TOPK], by1[TOPK], bx2[TOPK], by2[TOPK], bar[TOPK];
    __shared__ u64 iomask[TOPK][NWORDS];
    __shared__ u64 keepm[NWORDS];
    __shared__ u32 s_sel1, s_sel2, s_rem, s_cnt;

    for (int i = tid; i < HBINS; i += 256) hist[i] = 0;
    __syncthreads();
    for (int a = tid; a < A; a += 256) {
        float s = cls[(size_t)a * C + c];
        if (s > CLS_T) {
            u32 k = __float_as_uint(s) - KEY_BASE;
            u32 b = k >> 14; if (b >= HBINS) b = HBINS - 1;
            atomicAdd(&hist[b], 1u);
        }
    }
    __syncthreads();
    if (tid == 0) {
        u32 cum = 0; int sel = 0;
        for (int d = HBINS - 1; d >= 0; --d) {
            u32 nc = cum + hist[d];
            if (nc >= TOPK) { sel = d; break; }
            cum = nc;
        }
        s_sel1 = (u32)sel; s_rem = TOPK - cum;
    }
    __syncthreads();
    const u32 sel1 = s_sel1;

    for (int i = tid; i < 256; i += 256) hist[i] = 0;
    __syncthreads();
    for (int a = tid; a < A; a += 256) {
        float s = cls[(size_t)a * C + c];
        if (s > CLS_T) {
            u32 k = __float_as_uint(s) - KEY_BASE;
            u32 b = k >> 14; if (b >= HBINS) b = HBINS - 1;
            if (b == sel1) atomicAdd(&hist[(k >> 6) & 0xFF], 1u);
        }
    }
    __syncthreads();
    if (tid == 0) {
        u32 rem = s_rem, cum = 0; int sel = 0;
        for (int d = 255; d >= 0; --d) {
            u32 nc = cum + hist[d];
            if (nc >= rem) { sel = d; break; }
            cum = nc;
        }
        s_sel2 = (u32)sel; s_cnt = 0;
    }
    __syncthreads();
    const u32 thresh = (sel1 << 14) | (s_sel2 << 6);

    for (int a = tid; a < A; a += 256) {
        float s = cls[(size_t)a * C + c];
        if (s > CLS_T) {
            u32 bits = __float_as_uint(s);
            u32 k = bits - KEY_BASE;
            if (k >= thresh) {
                u32 pos = atomicAdd(&s_cnt, 1u);
                if (pos < FB_CAP) cand[pos] = ((u64)bits << 32) | (u32)(~(u32)a);
            }
        }
    }
    __syncthreads();
    const u32 total = s_cnt < FB_CAP ? s_cnt : FB_CAP;
    for (int i = tid; i < FB_CAP; i += 256)
        if (i >= (int)total) cand[i] = 0;
    __syncthreads();

    for (u32 kk = 2; kk <= FB_CAP; kk <<= 1) {
        for (u32 j = kk >> 1; j > 0; j >>= 1) {
            for (u32 i = tid; i < FB_CAP; i += 256) {
                u32 l = i ^ j;
                if (l > i) {
                    u64 av = cand[i], bv = cand[l];
                    bool up = ((i & kk) == 0);
                    if ((up && av < bv) || (!up && av > bv)) { cand[i] = bv; cand[l] = av; }
                }
            }
            __syncthreads();
        }
    }
    const int T = (int)(total < TOPK ? total : TOPK);

    for (int i = tid; i < T; i += 256) {
        u32 a = ~(u32)(cand[i] & 0xFFFFFFFFull);
        float x1 = boxes[(size_t)a*4+0], y1 = boxes[(size_t)a*4+1];
        float x2 = boxes[(size_t)a*4+2], y2 = boxes[(size_t)a*4+3];
        bx1[i] = x1; by1[i] = y1; bx2[i] = x2; by2[i] = y2;
        bar[i] = fmaxf(x2 - x1, 0.0f) * fmaxf(y2 - y1, 0.0f);
    }
    __syncthreads();

    for (int i = tid; i < T; i += 256) {
        u64 m[NWORDS] = {0,0,0,0,0};
        float x1 = bx1[i], y1 = by1[i], x2 = bx2[i], y2 = by2[i], ai = bar[i];
        for (int j = i + 1; j < T; ++j) {
            float iw = fmaxf(fminf(x2, bx2[j]) - fmaxf(x1, bx1[j]), 0.0f);
            float ih = fmaxf(fminf(y2, by2[j]) - fmaxf(y1, by1[j]), 0.0f);
            float inter = iw * ih;
            float uni = ((ai + bar[j]) - inter) + 1e-8f;
            if (inter / uni > 0.5f) m[j >> 6] |= 1ull << (j & 63);
        }
        for (int k2 = 0; k2 < NWORDS; ++k2) iomask[i][k2] = m[k2];
    }
    __syncthreads();

    if (tid == 0) {
        u64 sup[NWORDS] = {0,0,0,0,0};
        u64 kp [NWORDS] = {0,0,0,0,0};
        for (int i = 0; i < T; ++i) {
            if (!((sup[i >> 6] >> (i & 63)) & 1ull)) {
                kp[i >> 6] |= 1ull << (i & 63);
                for (int k2 = 0; k2 < NWORDS; ++k2) sup[k2] |= iomask[i][k2];
            }
        }
        for (int k2 = 0; k2 < NWORDS; ++k2) keepm[k2] = kp[k2];
    }
    __syncthreads();

    for (int i = tid; i < T; i += 256) {
        if ((keepm[i >> 6] >> (i & 63)) & 1ull) {
            u64 key = cand[i];
            u32 a = ~(u32)(key & 0xFFFFFFFFull);
            u32 sbits = (u32)(key >> 32);
            u64 outk = ((u64)sbits << 32) | (u32)(255 - c);
            atomicMax(&akey[a], outk);
        }
    }
}

extern "C" void kernel_launch(void* const* d_in, const int* in_sizes, int n_in,
                              void* d_out, int out_size, void* d_ws, size_t ws_size,
                              hipStream_t stream) {
    const float* cls = (const float*)d_in[0];
    const float* reg = (const float*)d_in[1];
    const float* anc = (const float*)d_in[2];
    const int*   ph  = (const int*)d_in[3];
    const int*   pw  = (const int*)d_in[4];

    int A = in_sizes[2] / 4;
    int C = in_sizes[0] / A;

    float* out       = (float*)d_out;
    float* out_boxes = out + (size_t)2 * A;

    // workspace: akey | overflow | segcnt | pref | totals | topcnt | topkeys | gbuf | gbuf2
    size_t akey_bytes = (size_t)A * sizeof(u64);
    size_t off_of     = (akey_bytes + 255) & ~(size_t)255;
    size_t off_sc     = (off_of + 256 + 255) & ~(size_t)255;
    size_t sc_bytes   = (size_t)80 * NBLK * sizeof(u32);
    size_t off_pf     = (off_sc + sc_bytes + 255) & ~(size_t)255;
    size_t off_tt     = (off_pf + sc_bytes + 255) & ~(size_t)255;
    size_t tt_bytes   = 80 * sizeof(u32);
    size_t off_tc     = (off_tt + tt_bytes + 255) & ~(size_t)255;
    size_t tc_bytes   = 80 * sizeof(u32);
    size_t off_tk     = (off_tc + tc_bytes + 255) & ~(size_t)255;
    size_t tk_bytes   = (size_t)80 * TOPK * sizeof(u64);
    size_t off_gb     = (off_tk + tk_bytes + 255) & ~(size_t)255;
    size_t gb_bytes   = (size_t)80 * NBLK * SCAP * sizeof(u64);
    size_t off_g2     = (off_gb + gb_bytes + 255) & ~(size_t)255;
    size_t g2_bytes   = (size_t)80 * DCAP * sizeof(u64);
    size_t need       = off_g2 + g2_bytes;

    u64* akey = (u64*)d_ws;

    decode_kernel<<<(A + 255) / 256, 256, 0, stream>>>(anc, reg, ph, pw, out_boxes, akey, A);

    bool fastpath = (C == 80) && ((A & 3) == 0) && (A < (1 << 20)) && (ws_size >= need);
    if (fastpath) {
        u32* overflow = (u32*)((char*)d_ws + off_of);
        u32* segcnt   = (u32*)((char*)d_ws + off_sc);
        u32* pref     = (u32*)((char*)d_ws + off_pf);
        u32* totals   = (u32*)((char*)d_ws + off_tt);
        u32* topcnt   = (u32*)((char*)d_ws + off_tc);
        u64* topkeys  = (u64*)((char*)d_ws + off_tk);
        u64* gbuf     = (u64*)((char*)d_ws + off_gb);
        u64* gbuf2    = (u64*)((char*)d_ws + off_g2);

        hipMemsetAsync(overflow, 0, sizeof(u32), stream);
        scan_collect_kernel<<<NBLK, 256, 0, stream>>>(cls, gbuf, segcnt, overflow, A);
        prefix_kernel<<<80, 256, 0, stream>>>(segcnt, pref, totals);
        compact_kernel<<<NBLK, 256, 0, stream>>>(segcnt, pref, gbuf, gbuf2);
        class_collect_kernel<<<C, 512, 0, stream>>>(totals, gbuf2, overflow, cls, topkeys, topcnt, A, C);
        class_nms2_kernel<<<C, 640, 0, stream>>>(topkeys, topcnt, out_boxes, akey, C);
    } else {
        fb_topk_nms_kernel<<<C, 256, 0, stream>>>(cls, out_boxes, akey, A, C);
    }

    finalize_kernel<<<(A + 255) / 256, 256, 0, stream>>>(akey, out, A);
}

// Round 13
// 78.568 us; speedup vs baseline: 2.1412x; 1.0161x over previous
//
#include <hip/hip_runtime.h>
#include <cstdint>

typedef unsigned long long u64;
typedef unsigned int u32;

#define CLS_T    0.05f
#define T0G      0.98f      // collect threshold (pass 1)
#define T1G      0.9965f    // candidate filter threshold (pass 2)
#define TOPK     300
#define NWORDS   5          // ceil(300/64)
#define HBINS    2560
#define KEY_BASE 0x3D000000u
#define CCAP     1024
#define NBLK     2048       // scan blocks
#define SCAP     24         // slots per (class, scan-block)
#define DCAP     8192       // dense per-class capacity

__device__ inline u32 bin_of_bits(u32 bits) {
    u32 b = (bits - KEY_BASE) >> 14;
    if (b > (HBINS - 1)) b = HBINS - 1;
    return b;
}

// compare-exchange for register bitonic: keep max if (lo==up), else min
__device__ inline void cex(u64& v, u64 p, bool lo, bool up) {
    u64 mx = v > p ? v : p;
    u64 mn = v > p ? p : v;
    v = (lo == up) ? mx : mn;
}
__device__ inline void sstep(u64& a0, u64& a1, u32 tid, u32 kk, u32 j) {
    u64 p0 = __shfl_xor((unsigned long long)a0, (int)j, 64);
    u64 p1 = __shfl_xor((unsigned long long)a1, (int)j, 64);
    bool lo = ((tid & j) == 0);
    cex(a0, p0, lo, ((tid & kk) == 0));
    cex(a1, p1, lo, (((tid + 512u) & kk) == 0));
}
__device__ inline void lstep(u64* cand, u64& a0, u64& a1, u32 tid, u32 kk, u32 j) {
    __syncthreads();
    cand[tid] = a0; cand[tid + 512] = a1;
    __syncthreads();
    u64 p0 = cand[tid ^ j], p1 = cand[(tid ^ j) + 512];
    bool lo = ((tid & j) == 0);
    cex(a0, p0, lo, ((tid & kk) == 0));
    cex(a1, p1, lo, (((tid + 512u) & kk) == 0));
}

// ---------------- decode boxes (+clip) + zero akey + zero overflow ----------------
__global__ void decode_kernel(const float* __restrict__ anc,
                              const float* __restrict__ reg,
                              const int* __restrict__ ph,
                              const int* __restrict__ pw,
                              float* __restrict__ boxes,
                              u64* __restrict__ akey,
                              u32* __restrict__ overflow, int A)
{
    int a = blockIdx.x * blockDim.x + threadIdx.x;
    if (a == 0) *overflow = 0;
    if (a >= A) return;
    akey[a] = 0;
    float x1 = anc[a*4+0], y1 = anc[a*4+1], x2 = anc[a*4+2], y2 = anc[a*4+3];
    float w = x2 - x1, h = y2 - y1;
    float cx = x1 + 0.5f*w, cy = y1 + 0.5f*h;
    float r0 = reg[a*4+0]*0.1f, r1 = reg[a*4+1]*0.1f;
    float r2 = reg[a*4+2]*0.2f, r3 = reg[a*4+3]*0.2f;
    float pcx = cx + r0*w, pcy = cy + r1*h;
    float pw_ = expf(r2)*w, ph_ = expf(r3)*h;
    float W = (float)(*pw), H = (float)(*ph);
    boxes[a*4+0] = fmaxf(pcx - 0.5f*pw_, 0.0f);
    boxes[a*4+1] = fmaxf(pcy - 0.5f*ph_, 0.0f);
    boxes[a*4+2] = fminf(pcx + 0.5f*pw_, W);
    boxes[a*4+3] = fminf(pcy + 0.5f*ph_, H);
}

// ---------------- one coalesced pass: collect s > T0G, zero global atomics ----------------
__global__ __launch_bounds__(256) void scan_collect_kernel(
    const float* __restrict__ cls,
    u64* __restrict__ gbuf, u32* __restrict__ segcnt,
    u32* __restrict__ overflow, int A)
{
    __shared__ u32 cnt[80];
    __shared__ u64 buf[80][SCAP];
    __shared__ u32 s_over;
    const int tid = threadIdx.x;
    const int blk = blockIdx.x;

    for (int i = tid; i < 80; i += 256) cnt[i] = 0;
    if (tid == 0) s_over = 0;
    __syncthreads();

    size_t Nf4 = (size_t)A * 20;   // A*80/4
    const float4* p4 = (const float4*)cls;
    for (size_t i = (size_t)blk * 256 + tid; i < Nf4; i += (size_t)NBLK * 256) {
        float4 v = p4[i];
        float ss[4] = {v.x, v.y, v.z, v.w};
        #pragma unroll
        for (int q = 0; q < 4; ++q) {
            if (ss[q] > T0G) {
                u32 flat = (u32)(i * 4 + q);
                u32 a = flat / 80u;            // const-div -> magic mul
                u32 c = flat - a * 80u;
                u32 p = atomicAdd(&cnt[c], 1u);   // LDS atomic only
                if (p < SCAP) buf[c][p] = ((u64)__float_as_uint(ss[q]) << 32) | (u32)(~a);
                else s_over = 1;
            }
        }
    }
    __syncthreads();

    for (int m = tid; m < 80 * SCAP; m += 256) {
        int c = m / SCAP, e = m - c * SCAP;
        u32 cc = cnt[c]; if (cc > SCAP) cc = SCAP;
        if ((u32)e < cc)
            gbuf[((size_t)c * NBLK + blk) * SCAP + e] = buf[c][e];
    }
    for (int c = tid; c < 80; c += 256) {
        u32 cc = cnt[c]; if (cc > SCAP) cc = SCAP;
        segcnt[(size_t)c * NBLK + blk] = cc;
    }
    if (tid == 0 && s_over) atomicOr(overflow, 1u);
}

// ---------------- per-class exclusive prefix over segcnt + totals ----------------
__global__ __launch_bounds__(256) void prefix_kernel(
    const u32* __restrict__ segcnt, u32* __restrict__ pref,
    u32* __restrict__ totals)
{
    const int c = blockIdx.x;
    const int tid = threadIdx.x;
    __shared__ u32 part[256];

    const u32* row = segcnt + (size_t)c * NBLK;
    u32 v[8];
    u32 s = 0;
    #pragma unroll
    for (int q = 0; q < 8; ++q) { v[q] = row[tid * 8 + q]; s += v[q]; }
    part[tid] = s;
    __syncthreads();
    for (int d = 1; d < 256; d <<= 1) {
        u32 t = (tid >= d) ? part[tid - d] : 0;
        __syncthreads();
        part[tid] += t;
        __syncthreads();
    }
    u32 running = part[tid] - s;
    u32* prow = pref + (size_t)c * NBLK;
    #pragma unroll
    for (int q = 0; q < 8; ++q) { prow[tid * 8 + q] = running; running += v[q]; }
    if (tid == 255) totals[c] = part[255];
}

// ---------------- compact: scatter (class,block) slots to dense rows ----------------
__global__ __launch_bounds__(256) void compact_kernel(
    const u32* __restrict__ segcnt, const u32* __restrict__ pref,
    const u64* __restrict__ gbuf, u64* __restrict__ gbuf2)
{
    const int b = blockIdx.x;
    const int tid = threadIdx.x;
    __shared__ u32 scnt[80], sbase[80];
    for (int c = tid; c < 80; c += 256) {
        scnt[c]  = segcnt[(size_t)c * NBLK + b];
        sbase[c] = pref[(size_t)c * NBLK + b];
    }
    __syncthreads();
    for (int m = tid; m < 80 * SCAP; m += 256) {
        int c = m / SCAP, e = m - c * SCAP;
        if ((u32)e < scnt[c]) {
            u32 p = sbase[c] + (u32)e;
            if (p < DCAP)
                gbuf2[(size_t)c * DCAP + p] = gbuf[((size_t)c * NBLK + b) * SCAP + e];
        }
    }
}

// ---------------- per-class collect: gather + register bitonic sort -> top-300 ----------------
__global__ __launch_bounds__(512) void class_collect_kernel(
    const u32* __restrict__ totals, const u64* __restrict__ gbuf2,
    const u32* __restrict__ overflow,
    const float* __restrict__ cls,     // [A][C] for slow path
    u64* __restrict__ topkeys, u32* __restrict__ topcnt, int A, int C)
{
    const int c = blockIdx.x;
    const u32 tid = threadIdx.x;
    const int lane = tid & 63;

    __shared__ u32 sh[HBINS];          // slow path histogram
    __shared__ u64 cand[CCAP];
    __shared__ u32 s_sel, s_cnt, s_rem;

    if (tid == 0) { s_sel = 0; s_cnt = 0; }
    __syncthreads();

    const bool over = (*overflow != 0);
    const u32 n = totals[c];
    u32 cnt_f = 0;
    bool fast_ok = false;

    if (!over && n >= TOPK && n <= DCAP) {
        const u64* src = gbuf2 + (size_t)c * DCAP;
        const u32 T1 = __float_as_uint(T1G);
        for (u32 i = tid; i < n; i += 512) {
            u64 e = src[i];
            bool take = ((u32)(e >> 32) > T1);
            u64 m = __ballot(take);
            int nW = __popcll(m);
            if (nW) {
                int ldr = __ffsll((unsigned long long)m) - 1;
                u32 base = 0;
                if (lane == ldr) base = atomicAdd(&s_cnt, (u32)nW);
                base = __shfl(base, ldr);
                if (take) {
                    u32 p = base + (u32)__popcll(m & ((1ull << lane) - 1ull));
                    if (p < CCAP) cand[p] = e;
                }
            }
        }
        __syncthreads();
        cnt_f = s_cnt;
        fast_ok = (cnt_f >= TOPK && cnt_f <= CCAP);
    }

    if (!fast_ok) {
        // ---- slow exact path: 2-level select over the class column ----
        __syncthreads();
        for (int i = tid; i < HBINS; i += 512) sh[i] = 0;
        if (tid == 0) s_cnt = 0;
        __syncthreads();
        for (int a = tid; a < A; a += 512) {
            float s = cls[(size_t)a * C + c];
            if (s > CLS_T) atomicAdd(&sh[bin_of_bits(__float_as_uint(s))], 1u);
        }
        __syncthreads();
        if (tid == 0) {
            u32 cum = 0; int sel = 0;
            for (int d = HBINS - 1; d >= 0; --d) {
                u32 nc = cum + sh[d];
                if (nc >= TOPK) { sel = d; break; }
                cum = nc;
            }
            s_sel = (u32)sel; s_rem = TOPK - cum;
        }
        __syncthreads();
        const u32 sel1 = s_sel;
        __syncthreads();
        for (int i = tid; i < 256; i += 512) sh[i] = 0;
        __syncthreads();
        for (int a = tid; a < A; a += 512) {
            float s = cls[(size_t)a * C + c];
            if (s > CLS_T) {
                u32 k = __float_as_uint(s) - KEY_BASE;
                u32 b = k >> 14; if (b >= HBINS) b = HBINS - 1;
                if (b == sel1) atomicAdd(&sh[(k >> 6) & 0xFF], 1u);
            }
        }
        __syncthreads();
        if (tid == 0) {
            u32 rem = s_rem, cum = 0; int sel = 0;
            for (int d = 255; d >= 0; --d) {
                u32 nc = cum + sh[d];
                if (nc >= rem) { sel = d; break; }
                cum = nc;
            }
            s_sel = (sel1 << 14) | ((u32)sel << 6);
            s_cnt = 0;
        }
        __syncthreads();
        const u32 thresh = s_sel;
        for (int a = tid; a < A; a += 512) {
            float s = cls[(size_t)a * C + c];
            if (s > CLS_T) {
                u32 bits = __float_as_uint(s);
                if (bits - KEY_BASE >= thresh) {
                    u32 p = atomicAdd(&s_cnt, 1u);
                    if (p < CCAP) cand[p] = ((u64)bits << 32) | (u32)(~(u32)a);
                }
            }
        }
        __syncthreads();
        cnt_f = s_cnt < CCAP ? s_cnt : CCAP;
    }

    // ---- pad + register bitonic sort of 1024 (2 elems/thread), descending ----
    for (u32 i = cnt_f + tid; i < CCAP; i += 512) cand[i] = 0;
    __syncthreads();
    u64 a0 = cand[tid], a1 = cand[tid + 512];
    for (u32 kk = 2; kk <= 64; kk <<= 1)
        for (u32 j = kk >> 1; j >= 1; j >>= 1)
            sstep(a0, a1, tid, kk, j);
    lstep(cand, a0, a1, tid, 128u, 64u);
    for (u32 j = 32; j >= 1; j >>= 1) sstep(a0, a1, tid, 128u, j);
    lstep(cand, a0, a1, tid, 256u, 128u);
    lstep(cand, a0, a1, tid, 256u, 64u);
    for (u32 j = 32; j >= 1; j >>= 1) sstep(a0, a1, tid, 256u, j);
    lstep(cand, a0, a1, tid, 512u, 256u);
    lstep(cand, a0, a1, tid, 512u, 128u);
    lstep(cand, a0, a1, tid, 512u, 64u);
    for (u32 j = 32; j >= 1; j >>= 1) sstep(a0, a1, tid, 512u, j);
    {   // kk=1024, j=512: in-thread exchange (up = true for tid<512)
        u64 mx = a0 > a1 ? a0 : a1, mn = a0 > a1 ? a1 : a0;
        a0 = mx; a1 = mn;
    }
    lstep(cand, a0, a1, tid, 1024u, 256u);
    lstep(cand, a0, a1, tid, 1024u, 128u);
    lstep(cand, a0, a1, tid, 1024u, 64u);
    for (u32 j = 32; j >= 1; j >>= 1) sstep(a0, a1, tid, 1024u, j);
    // thread tid holds sorted element tid in a0

    const int T = (int)(cnt_f < TOPK ? cnt_f : TOPK);
    if ((int)tid < T) topkeys[(size_t)c * TOPK + tid] = a0;
    if (tid == 0) topcnt[c] = (u32)T;
}

// ---------------- per-class NMS: split branchless colmask + ballot greedy ----------------
__global__ __launch_bounds__(640) void class_nms2_kernel(
    const u64* __restrict__ topkeys, const u32* __restrict__ topcnt,
    const float* __restrict__ boxes, u64* __restrict__ akey, int C)
{
    const int c = blockIdx.x;
    const u32 tid = threadIdx.x;
    const int lane = tid & 63;

    __shared__ float4 sbox[TOPK];
    __shared__ float  sbar[TOPK];
    __shared__ u64 iomaskT[NWORDS][TOPK];   // transposed colmask: [word][box]
    __shared__ u64 s_keep[NWORDS];

    const int T = (int)topcnt[c];

    u64 key = 0; u32 aidx = 0;
    if ((int)tid < T) {
        key = topkeys[(size_t)c * TOPK + tid];
        aidx = ~(u32)(key & 0xFFFFFFFFull);
        float4 b4 = *(const float4*)(boxes + (size_t)aidx * 4);
        sbox[tid] = b4;
        sbar[tid] = fmaxf(b4.z - b4.x, 0.0f) * fmaxf(b4.w - b4.y, 0.0f);
    }
    for (int m = tid; m < NWORDS * TOPK; m += 640) ((u64*)iomaskT)[m] = 0;
    __syncthreads();

    // colmask: row jj, parity p -> which i<jj suppress jj (IoU>0.5), branchless
    {
        const int jj = (int)(tid < 320 ? tid : tid - 320);
        const int p  = (int)(tid < 320 ? 0 : 1);
        if (jj < T) {
            float4 b = sbox[jj];
            float ar = sbar[jj];
            u64 cm[NWORDS] = {0,0,0,0,0};
            for (int i = p; i < jj; i += 2) {
                float4 bi = sbox[i];
                float iw = fmaxf(fminf(b.z, bi.z) - fmaxf(b.x, bi.x), 0.0f);
                float ih = fmaxf(fminf(b.w, bi.w) - fmaxf(b.y, bi.y), 0.0f);
                float inter = iw * ih;
                float uni = ((ar + sbar[i]) - inter) + 1e-8f;
                if (inter / uni > 0.5f) cm[i >> 6] |= 1ull << (i & 63);
            }
            #pragma unroll
            for (int w = 0; w < NWORDS; ++w)
                if (cm[w]) atomicOr(&iomaskT[w][jj], cm[w]);
        }
    }
    __syncthreads();

    // wave 0: word-serial, round-parallel ballot greedy
    if (tid < 64) {
        u64 K[NWORDS];
        #pragma unroll
        for (int w = 0; w < NWORDS; ++w) {
            int b = w * 64 + lane;
            bool valid = (b < T);
            u64 cmw = 0, se = 0;
            if (valid) {
                #pragma unroll
                for (int w2 = 0; w2 < NWORDS; ++w2)
                    if (w2 < w) se |= K[w2] & iomaskT[w2][b];
                cmw = iomaskT[w][b];
            }
            u64 U = __ballot(valid && se == 0);
            u64 Kw = 0;
            int guard = 0;
            while (U && guard++ < 64) {
                u64 newk = __ballot(((U >> lane) & 1ull) && ((cmw & U) == 0));
                Kw |= newk; U &= ~newk;
                u64 supp = __ballot((cmw & Kw) != 0);
                U &= ~supp;
            }
            K[w] = Kw;
        }
        if (lane == 0) {
            #pragma unroll
            for (int w = 0; w < NWORDS; ++w) s_keep[w] = K[w];
        }
    }
    __syncthreads();

    if ((int)tid < T) {
        if ((s_keep[tid >> 6] >> (tid & 63)) & 1ull) {
            u32 sbits = (u32)(key >> 32);
            u64 outk = ((u64)sbits << 32) | (u32)(255 - c);
            atomicMax(&akey[aidx], outk);
        }
    }
}

// ---------------- finalize ----------------
__global__ void finalize_kernel(const u64* __restrict__ akey,
                                float* __restrict__ out, int A)
{
    int a = blockIdx.x * blockDim.x + threadIdx.x;
    if (a >= A) return;
    float* scores = out;
    float* labels = out + A;
    float* boxes  = out + (size_t)2 * A;
    u64 k = akey[a];
    if (k) {
        scores[a] = __uint_as_float((u32)(k >> 32));
        labels[a] = (float)(int)(255u - (u32)(k & 0xFFFFFFFFull));
    } else {
        scores[a] = 0.0f;
        labels[a] = -1.0f;
        boxes[(size_t)a*4+0] = 0.0f;
        boxes[(size_t)a*4+1] = 0.0f;
        boxes[(size_t)a*4+2] = 0.0f;
        boxes[(size_t)a*4+3] = 0.0f;
    }
}

// ---------------- fallback (generic C / small ws): round-1 proven kernel ----------------
#define FB_CAP 1024
__global__ __launch_bounds__(256) void fb_topk_nms_kernel(
    const float* __restrict__ cls,
    const float* __restrict__ boxes,
    u64* __restrict__ akey,
    int A, int C)
{
    const int c   = blockIdx.x;
    const int tid = threadIdx.x;

    __shared__ u32 hist[HBINS];
    __shared__ u64 cand[FB_CAP];
    __shared__ float bx1[TOPK], by1[TOPK], bx2[TOPK], by2[TOPK], bar[TOPK];
    __shared__ u64 iomask[TOPK][NWORDS];
    __shared__ u64 keepm[NWORDS];
    __shared__ u32 s_sel1, s_sel2, s_rem, s_cnt;

    for (int i = tid; i < HBINS; i += 256) hist[i] = 0;
    __syncthreads();
    for (int a = tid; a < A; a += 256) {
        float s = cls[(size_t)a * C + c];
        if (s > CLS_T) {
            u32 k = __float_as_uint(s) - KEY_BASE;
            u32 b = k >> 14; if (b >= HBINS) b = HBINS - 1;
            atomicAdd(&hist[b], 1u);
        }
    }
    __syncthreads();
    if (tid == 0) {
        u32 cum = 0; int sel = 0;
        for (int d = HBINS - 1; d >= 0; --d) {
            u32 nc = cum + hist[d];
            if (nc >= TOPK) { sel = d; break; }
            cum = nc;
        }
        s_sel1 = (u32)sel; s_rem = TOPK - cum;
    }
    __syncthreads();
    const u32 sel1 = s_sel1;

    for (int i = tid; i < 256; i += 256) hist[i] = 0;
    __syncthreads();
    for (int a = tid; a < A; a += 256) {
        float s = cls[(size_t)a * C + c];
        if (s > CLS_T) {
            u32 k = __float_as_uint(s) - KEY_BASE;
            u32 b = k >> 14; if (b >= HBINS) b = HBINS - 1;
            if (b == sel1) atomicAdd(&hist[(k >> 6) & 0xFF], 1u);
        }
    }
    __syncthreads();
    if (tid == 0) {
        u32 rem = s_rem, cum = 0; int sel = 0;
        for (int d = 255; d >= 0; --d) {
            u32 nc = cum + hist[d];
            if (nc >= rem) { sel = d; break; }
            cum = nc;
        }
        s_sel2 = (u32)sel; s_cnt = 0;
    }
    __syncthreads();
    const u32 thresh = (sel1 << 14) | (s_sel2 << 6);

    for (int a = tid; a < A; a += 256) {
        float s = cls[(size_t)a * C + c];
        if (s > CLS_T) {
            u32 bits = __float_as_uint(s);
            u32 k = bits - KEY_BASE;
            if (k >= thresh) {
                u32 pos = atomicAdd(&s_cnt, 1u);
                if (pos < FB_CAP) cand[pos] = ((u64)bits << 32) | (u32)(~(u32)a);
            }
        }
    }
    __syncthreads();
    const u32 total = s_cnt < FB_CAP ? s_cnt : FB_CAP;
    for (int i = tid; i < FB_CAP; i += 256)
        if (i >= (int)total) cand[i] = 0;
    __syncthreads();

    for (u32 kk = 2; kk <= FB_CAP; kk <<= 1) {
        for (u32 j = kk >> 1; j > 0; j >>= 1) {
            for (u32 i = tid; i < FB_CAP; i += 256) {
                u32 l = i ^ j;
                if (l > i) {
                    u64 av = cand[i], bv = cand[l];
                    bool up = ((i & kk) == 0);
                    if ((up && av < bv) || (!up && av > bv)) { cand[i] = bv; cand[l] = av; }
                }
            }
            __syncthreads();
        }
    }
    const int T = (int)(total < TOPK ? total : TOPK);

    for (int i = tid; i < T; i += 256) {
        u32 a = ~(u32)(cand[i] & 0xFFFFFFFFull);
        float x1 = boxes[(size_t)a*4+0], y1 = boxes[(size_t)a*4+1];
        float x2 = boxes[(size_t)a*4+2], y2 = boxes[(size_t)a*4+3];
        bx1[i] = x1; by1[i] = y1; bx2[i] = x2; by2[i] = y2;
        bar[i] = fmaxf(x2 - x1, 0.0f) * fmaxf(y2 - y1, 0.0f);
    }
    __syncthreads();

    for (int i = tid; i < T; i += 256) {
        u64 m[NWORDS] = {0,0,0,0,0};
        float x1 = bx1[i], y1 = by1[i], x2 = bx2[i], y2 = by2[i], ai = bar[i];
        for (int j = i + 1; j < T; ++j) {
            float iw = fmaxf(fminf(x2, bx2[j]) - fmaxf(x1, bx1[j]), 0.0f);
            float ih = fmaxf(fminf(y2, by2[j]) - fmaxf(y1, by1[j]), 0.0f);
            float inter = iw * ih;
            float uni = ((ai + bar[j]) - inter) + 1e-8f;
            if (inter / uni > 0.5f) m[j >> 6] |= 1ull << (j & 63);
        }
        for (int k2 = 0; k2 < NWORDS; ++k2) iomask[i][k2] = m[k2];
    }
    __syncthreads();

    if (tid == 0) {
        u64 sup[NWORDS] = {0,0,0,0,0};
        u64 kp [NWORDS] = {0,0,0,0,0};
        for (int i = 0; i < T; ++i) {
            if (!((sup[i >> 6] >> (i & 63)) & 1ull)) {
                kp[i >> 6] |= 1ull << (i & 63);
                for (int k2 = 0; k2 < NWORDS; ++k2) sup[k2] |= iomask[i][k2];
            }
        }
        for (int k2 = 0; k2 < NWORDS; ++k2) keepm[k2] = kp[k2];
    }
    __syncthreads();

    for (int i = tid; i < T; i += 256) {
        if ((keepm[i >> 6] >> (i & 63)) & 1ull) {
            u64 key = cand[i];
            u32 a = ~(u32)(key & 0xFFFFFFFFull);
            u32 sbits = (u32)(key >> 32);
            u64 outk = ((u64)sbits << 32) | (u32)(255 - c);
            atomicMax(&akey[a], outk);
        }
    }
}

extern "C" void kernel_launch(void* const* d_in, const int* in_sizes, int n_in,
                              void* d_out, int out_size, void* d_ws, size_t ws_size,
                              hipStream_t stream) {
    const float* cls = (const float*)d_in[0];
    const float* reg = (const float*)d_in[1];
    const float* anc = (const float*)d_in[2];
    const int*   ph  = (const int*)d_in[3];
    const int*   pw  = (const int*)d_in[4];

    int A = in_sizes[2] / 4;
    int C = in_sizes[0] / A;

    float* out       = (float*)d_out;
    float* out_boxes = out + (size_t)2 * A;

    // workspace: akey | overflow | segcnt | pref | totals | topcnt | topkeys | gbuf | gbuf2
    size_t akey_bytes = (size_t)A * sizeof(u64);
    size_t off_of     = (akey_bytes + 255) & ~(size_t)255;
    size_t off_sc     = (off_of + 256 + 255) & ~(size_t)255;
    size_t sc_bytes   = (size_t)80 * NBLK * sizeof(u32);
    size_t off_pf     = (off_sc + sc_bytes + 255) & ~(size_t)255;
    size_t off_tt     = (off_pf + sc_bytes + 255) & ~(size_t)255;
    size_t tt_bytes   = 80 * sizeof(u32);
    size_t off_tc     = (off_tt + tt_bytes + 255) & ~(size_t)255;
    size_t tc_bytes   = 80 * sizeof(u32);
    size_t off_tk     = (off_tc + tc_bytes + 255) & ~(size_t)255;
    size_t tk_bytes   = (size_t)80 * TOPK * sizeof(u64);
    size_t off_gb     = (off_tk + tk_bytes + 255) & ~(size_t)255;
    size_t gb_bytes   = (size_t)80 * NBLK * SCAP * sizeof(u64);
    size_t off_g2     = (off_gb + gb_bytes + 255) & ~(size_t)255;
    size_t g2_bytes   = (size_t)80 * DCAP * sizeof(u64);
    size_t need       = off_g2 + g2_bytes;

    u64* akey = (u64*)d_ws;
    u32* overflow = (u32*)((char*)d_ws + off_of);

    bool fastpath = (C == 80) && ((A & 3) == 0) && (A < (1 << 20)) && (ws_size >= need);

    decode_kernel<<<(A + 255) / 256, 256, 0, stream>>>(anc, reg, ph, pw, out_boxes, akey, overflow, A);

    if (fastpath) {
        u32* segcnt   = (u32*)((char*)d_ws + off_sc);
        u32* pref     = (u32*)((char*)d_ws + off_pf);
        u32* totals   = (u32*)((char*)d_ws + off_tt);
        u32* topcnt   = (u32*)((char*)d_ws + off_tc);
        u64* topkeys  = (u64*)((char*)d_ws + off_tk);
        u64* gbuf     = (u64*)((char*)d_ws + off_gb);
        u64* gbuf2    = (u64*)((char*)d_ws + off_g2);

        scan_collect_kernel<<<NBLK, 256, 0, stream>>>(cls, gbuf, segcnt, overflow, A);
        prefix_kernel<<<80, 256, 0, stream>>>(segcnt, pref, totals);
        compact_kernel<<<NBLK, 256, 0, stream>>>(segcnt, pref, gbuf, gbuf2);
        class_collect_kernel<<<C, 512, 0, stream>>>(totals, gbuf2, overflow, cls, topkeys, topcnt, A, C);
        class_nms2_kernel<<<C, 640, 0, stream>>>(topkeys, topcnt, out_boxes, akey, C);
    } else {
        fb_topk_nms_kernel<<<C, 256, 0, stream>>>(cls, out_boxes, akey, A, C);
    }

    finalize_kernel<<<(A + 255) / 256, 256, 0, stream>>>(akey, out, A);
}

// Round 14
// 70.026 us; speedup vs baseline: 2.4023x; 1.1220x over previous
//
#include <hip/hip_runtime.h>
#include <cstdint>

typedef unsigned long long u64;
typedef unsigned int u32;

#define CLS_T    0.05f
#define T0G      0.98f      // collect threshold (pass 1)
#define T1G      0.9965f    // candidate filter threshold (pass 2)
#define TOPK     300
#define NWORDS   5          // ceil(300/64)
#define HBINS    2560
#define KEY_BASE 0x3D000000u
#define CCAP     1024
#define NBLK     2048       // scan blocks
#define SCAP     24         // slots per (class, scan-block)
#define DCAP     8192       // dense per-class capacity
#define OVBIT    0x80000000u

__device__ inline u32 bin_of_bits(u32 bits) {
    u32 b = (bits - KEY_BASE) >> 14;
    if (b > (HBINS - 1)) b = HBINS - 1;
    return b;
}

// compare-exchange for register bitonic: keep max if (lo==up), else min
__device__ inline void cex(u64& v, u64 p, bool lo, bool up) {
    u64 mx = v > p ? v : p;
    u64 mn = v > p ? p : v;
    v = (lo == up) ? mx : mn;
}
__device__ inline void sstep(u64& a0, u64& a1, u32 tid, u32 kk, u32 j) {
    u64 p0 = __shfl_xor((unsigned long long)a0, (int)j, 64);
    u64 p1 = __shfl_xor((unsigned long long)a1, (int)j, 64);
    bool lo = ((tid & j) == 0);
    cex(a0, p0, lo, ((tid & kk) == 0));
    cex(a1, p1, lo, (((tid + 512u) & kk) == 0));
}
// 640-thread-safe LDS exchange step: all threads hit barriers, tid<512 work
__device__ inline void lstep640(u64* cand, u64& a0, u64& a1, u32 tid, u32 kk, u32 j) {
    __syncthreads();
    if (tid < 512) { cand[tid] = a0; cand[tid + 512] = a1; }
    __syncthreads();
    if (tid < 512) {
        u64 p0 = cand[tid ^ j], p1 = cand[(tid ^ j) + 512];
        bool lo = ((tid & j) == 0);
        cex(a0, p0, lo, ((tid & kk) == 0));
        cex(a1, p1, lo, (((tid + 512u) & kk) == 0));
    }
}

// ---------------- standalone decode (fallback path only) ----------------
__global__ void decode_kernel(const float* __restrict__ anc,
                              const float* __restrict__ reg,
                              const int* __restrict__ ph,
                              const int* __restrict__ pw,
                              float* __restrict__ boxes,
                              u64* __restrict__ akey, int A)
{
    int a = blockIdx.x * blockDim.x + threadIdx.x;
    if (a >= A) return;
    akey[a] = 0;
    float x1 = anc[a*4+0], y1 = anc[a*4+1], x2 = anc[a*4+2], y2 = anc[a*4+3];
    float w = x2 - x1, h = y2 - y1;
    float cx = x1 + 0.5f*w, cy = y1 + 0.5f*h;
    float r0 = reg[a*4+0]*0.1f, r1 = reg[a*4+1]*0.1f;
    float r2 = reg[a*4+2]*0.2f, r3 = reg[a*4+3]*0.2f;
    float pcx = cx + r0*w, pcy = cy + r1*h;
    float pw_ = expf(r2)*w, ph_ = expf(r3)*h;
    float W = (float)(*pw), H = (float)(*ph);
    boxes[a*4+0] = fmaxf(pcx - 0.5f*pw_, 0.0f);
    boxes[a*4+1] = fmaxf(pcy - 0.5f*ph_, 0.0f);
    boxes[a*4+2] = fminf(pcx + 0.5f*pw_, W);
    boxes[a*4+3] = fminf(pcy + 0.5f*ph_, H);
}

// ---------------- fused decode + one-pass collect (zero global atomics) ----------------
// Overflow is signaled via bit31 of segcnt entries (no pre-zeroed flag needed).
__global__ __launch_bounds__(256) void fused_scan_kernel(
    const float* __restrict__ anc, const float* __restrict__ reg,
    const int* __restrict__ ph, const int* __restrict__ pw,
    const float* __restrict__ cls,
    float* __restrict__ boxes, u64* __restrict__ akey,
    u64* __restrict__ gbuf, u32* __restrict__ segcnt, int A)
{
    const int tid = threadIdx.x;
    const int blk = blockIdx.x;

    // ---- decode part (grid-stride over anchors; independent of scan data) ----
    float W = (float)(*pw), H = (float)(*ph);
    for (int a = blk * 256 + tid; a < A; a += NBLK * 256) {
        akey[a] = 0;
        float x1 = anc[a*4+0], y1 = anc[a*4+1], x2 = anc[a*4+2], y2 = anc[a*4+3];
        float w = x2 - x1, h = y2 - y1;
        float cx = x1 + 0.5f*w, cy = y1 + 0.5f*h;
        float r0 = reg[a*4+0]*0.1f, r1 = reg[a*4+1]*0.1f;
        float r2 = reg[a*4+2]*0.2f, r3 = reg[a*4+3]*0.2f;
        float pcx = cx + r0*w, pcy = cy + r1*h;
        float pw_ = expf(r2)*w, ph_ = expf(r3)*h;
        boxes[a*4+0] = fmaxf(pcx - 0.5f*pw_, 0.0f);
        boxes[a*4+1] = fmaxf(pcy - 0.5f*ph_, 0.0f);
        boxes[a*4+2] = fminf(pcx + 0.5f*pw_, W);
        boxes[a*4+3] = fminf(pcy + 0.5f*ph_, H);
    }

    // ---- scan-collect part ----
    __shared__ u32 cnt[80];
    __shared__ u64 buf[80][SCAP];
    __shared__ u32 s_over;
    for (int i = tid; i < 80; i += 256) cnt[i] = 0;
    if (tid == 0) s_over = 0;
    __syncthreads();

    size_t Nf4 = (size_t)A * 20;   // A*80/4
    const float4* p4 = (const float4*)cls;
    for (size_t i = (size_t)blk * 256 + tid; i < Nf4; i += (size_t)NBLK * 256) {
        float4 v = p4[i];
        float ss[4] = {v.x, v.y, v.z, v.w};
        #pragma unroll
        for (int q = 0; q < 4; ++q) {
            if (ss[q] > T0G) {
                u32 flat = (u32)(i * 4 + q);
                u32 a = flat / 80u;            // const-div -> magic mul
                u32 c = flat - a * 80u;
                u32 p = atomicAdd(&cnt[c], 1u);   // LDS atomic only
                if (p < SCAP) buf[c][p] = ((u64)__float_as_uint(ss[q]) << 32) | (u32)(~a);
                else s_over = 1;
            }
        }
    }
    __syncthreads();

    const u32 ob = s_over ? OVBIT : 0u;
    for (int m = tid; m < 80 * SCAP; m += 256) {
        int c = m / SCAP, e = m - c * SCAP;
        u32 cc = cnt[c]; if (cc > SCAP) cc = SCAP;
        if ((u32)e < cc)
            gbuf[((size_t)c * NBLK + blk) * SCAP + e] = buf[c][e];
    }
    for (int c = tid; c < 80; c += 256) {
        u32 cc = cnt[c]; if (cc > SCAP) cc = SCAP;
        segcnt[(size_t)c * NBLK + blk] = cc | ob;
    }
}

// ---------------- per-class exclusive prefix + totals (propagates bit31) ----------------
__global__ __launch_bounds__(256) void prefix_kernel(
    const u32* __restrict__ segcnt, u32* __restrict__ pref,
    u32* __restrict__ totals)
{
    const int c = blockIdx.x;
    const int tid = threadIdx.x;
    __shared__ u32 part[256];
    __shared__ u32 s_ob;
    if (tid == 0) s_ob = 0;
    __syncthreads();

    const u32* row = segcnt + (size_t)c * NBLK;
    u32 v[8];
    u32 s = 0, ob = 0;
    #pragma unroll
    for (int q = 0; q < 8; ++q) {
        u32 r = row[tid * 8 + q];
        ob |= r & OVBIT;
        v[q] = r & ~OVBIT;
        s += v[q];
    }
    if (ob) atomicOr(&s_ob, 1u);
    part[tid] = s;
    __syncthreads();
    for (int d = 1; d < 256; d <<= 1) {
        u32 t = (tid >= d) ? part[tid - d] : 0;
        __syncthreads();
        part[tid] += t;
        __syncthreads();
    }
    u32 running = part[tid] - s;
    u32* prow = pref + (size_t)c * NBLK;
    #pragma unroll
    for (int q = 0; q < 8; ++q) { prow[tid * 8 + q] = running; running += v[q]; }
    if (tid == 255) totals[c] = part[255] | (s_ob ? OVBIT : 0u);
}

// ---------------- compact: scatter (class,block) slots to dense rows ----------------
__global__ __launch_bounds__(256) void compact_kernel(
    const u32* __restrict__ segcnt, const u32* __restrict__ pref,
    const u64* __restrict__ gbuf, u64* __restrict__ gbuf2)
{
    const int b = blockIdx.x;
    const int tid = threadIdx.x;
    __shared__ u32 scnt[80], sbase[80];
    for (int c = tid; c < 80; c += 256) {
        scnt[c]  = segcnt[(size_t)c * NBLK + b] & ~OVBIT;
        sbase[c] = pref[(size_t)c * NBLK + b];
    }
    __syncthreads();
    for (int m = tid; m < 80 * SCAP; m += 256) {
        int c = m / SCAP, e = m - c * SCAP;
        if ((u32)e < scnt[c]) {
            u32 p = sbase[c] + (u32)e;
            if (p < DCAP)
                gbuf2[(size_t)c * DCAP + p] = gbuf[((size_t)c * NBLK + b) * SCAP + e];
        }
    }
}

// ---------------- fused per-class: gather + sort + colmask + ballot NMS + scatter ----------------
__global__ __launch_bounds__(640) void class_fused_kernel(
    const u32* __restrict__ totals, const u64* __restrict__ gbuf2,
    const float* __restrict__ cls,     // [A][C] for slow path
    const float* __restrict__ boxes, u64* __restrict__ akey, int A, int C)
{
    const int c = blockIdx.x;
    const u32 tid = threadIdx.x;
    const int lane = tid & 63;

    __shared__ u32 sh[HBINS];          // slow path histogram
    __shared__ u64 cand[CCAP];
    __shared__ u32 s_sel, s_cnt, s_rem;
    __shared__ float4 sbox[TOPK];
    __shared__ float  sbar[TOPK];
    __shared__ u64 iomaskT[NWORDS][TOPK];
    __shared__ u64 s_keep[NWORDS];

    if (tid == 0) { s_sel = 0; s_cnt = 0; }
    __syncthreads();

    const u32 traw = totals[c];
    const bool over = (traw & OVBIT) != 0;
    const u32 n = traw & ~OVBIT;
    u32 cnt_f = 0;
    bool fast_ok = false;

    if (!over && n >= TOPK && n <= DCAP) {
        const u64* src = gbuf2 + (size_t)c * DCAP;
        const u32 T1 = __float_as_uint(T1G);
        for (u32 i = tid; i < n; i += 640) {
            u64 e = src[i];
            bool take = ((u32)(e >> 32) > T1);
            u64 m = __ballot(take);
            int nW = __popcll(m);
            if (nW) {
                int ldr = __ffsll((unsigned long long)m) - 1;
                u32 base = 0;
                if (lane == ldr) base = atomicAdd(&s_cnt, (u32)nW);
                base = __shfl(base, ldr);
                if (take) {
                    u32 p = base + (u32)__popcll(m & ((1ull << lane) - 1ull));
                    if (p < CCAP) cand[p] = e;
                }
            }
        }
        __syncthreads();
        cnt_f = s_cnt;
        fast_ok = (cnt_f >= TOPK && cnt_f <= CCAP);
    }

    if (!fast_ok) {
        // ---- slow exact path: 2-level select over the class column ----
        __syncthreads();
        for (int i = tid; i < HBINS; i += 640) sh[i] = 0;
        if (tid == 0) s_cnt = 0;
        __syncthreads();
        for (int a = tid; a < A; a += 640) {
            float s = cls[(size_t)a * C + c];
            if (s > CLS_T) atomicAdd(&sh[bin_of_bits(__float_as_uint(s))], 1u);
        }
        __syncthreads();
        if (tid == 0) {
            u32 cum = 0; int sel = 0;
            for (int d = HBINS - 1; d >= 0; --d) {
                u32 nc = cum + sh[d];
                if (nc >= TOPK) { sel = d; break; }
                cum = nc;
            }
            s_sel = (u32)sel; s_rem = TOPK - cum;
        }
        __syncthreads();
        const u32 sel1 = s_sel;
        __syncthreads();
        for (int i = tid; i < 256; i += 640) sh[i] = 0;
        __syncthreads();
        for (int a = tid; a < A; a += 640) {
            float s = cls[(size_t)a * C + c];
            if (s > CLS_T) {
                u32 k = __float_as_uint(s) - KEY_BASE;
                u32 b = k >> 14; if (b >= HBINS) b = HBINS - 1;
                if (b == sel1) atomicAdd(&sh[(k >> 6) & 0xFF], 1u);
            }
        }
        __syncthreads();
        if (tid == 0) {
            u32 rem = s_rem, cum = 0; int sel = 0;
            for (int d = 255; d >= 0; --d) {
                u32 nc = cum + sh[d];
                if (nc >= rem) { sel = d; break; }
                cum = nc;
            }
            s_sel = (sel1 << 14) | ((u32)sel << 6);
            s_cnt = 0;
        }
        __syncthreads();
        const u32 thresh = s_sel;
        for (int a = tid; a < A; a += 640) {
            float s = cls[(size_t)a * C + c];
            if (s > CLS_T) {
                u32 bits = __float_as_uint(s);
                if (bits - KEY_BASE >= thresh) {
                    u32 p = atomicAdd(&s_cnt, 1u);
                    if (p < CCAP) cand[p] = ((u64)bits << 32) | (u32)(~(u32)a);
                }
            }
        }
        __syncthreads();
        cnt_f = s_cnt < CCAP ? s_cnt : CCAP;
    }

    // pad + zero iomaskT
    for (u32 i = cnt_f + tid; i < CCAP; i += 640) cand[i] = 0;
    for (int m = tid; m < NWORDS * TOPK; m += 640) ((u64*)iomaskT)[m] = 0;
    __syncthreads();

    // ---- register bitonic sort of 1024 (tid<512 active, barrier-safe) ----
    u64 a0 = 0, a1 = 0;
    if (tid < 512) { a0 = cand[tid]; a1 = cand[tid + 512]; }
    if (tid < 512)
        for (u32 kk = 2; kk <= 64; kk <<= 1)
            for (u32 j = kk >> 1; j >= 1; j >>= 1)
                sstep(a0, a1, tid, kk, j);
    lstep640(cand, a0, a1, tid, 128u, 64u);
    if (tid < 512) for (u32 j = 32; j >= 1; j >>= 1) sstep(a0, a1, tid, 128u, j);
    lstep640(cand, a0, a1, tid, 256u, 128u);
    lstep640(cand, a0, a1, tid, 256u, 64u);
    if (tid < 512) for (u32 j = 32; j >= 1; j >>= 1) sstep(a0, a1, tid, 256u, j);
    lstep640(cand, a0, a1, tid, 512u, 256u);
    lstep640(cand, a0, a1, tid, 512u, 128u);
    lstep640(cand, a0, a1, tid, 512u, 64u);
    if (tid < 512) for (u32 j = 32; j >= 1; j >>= 1) sstep(a0, a1, tid, 512u, j);
    if (tid < 512) {   // kk=1024, j=512: in-thread exchange
        u64 mx = a0 > a1 ? a0 : a1, mn = a0 > a1 ? a1 : a0;
        a0 = mx; a1 = mn;
    }
    lstep640(cand, a0, a1, tid, 1024u, 256u);
    lstep640(cand, a0, a1, tid, 1024u, 128u);
    lstep640(cand, a0, a1, tid, 1024u, 64u);
    if (tid < 512) for (u32 j = 32; j >= 1; j >>= 1) sstep(a0, a1, tid, 1024u, j);
    // thread tid<512 holds sorted element tid in a0

    const int T = (int)(cnt_f < TOPK ? cnt_f : TOPK);

    // ---- boxes for my candidate ----
    u64 key = a0; u32 aidx = 0;
    if ((int)tid < T) {
        aidx = ~(u32)(key & 0xFFFFFFFFull);
        float4 b4 = *(const float4*)(boxes + (size_t)aidx * 4);
        sbox[tid] = b4;
        sbar[tid] = fmaxf(b4.z - b4.x, 0.0f) * fmaxf(b4.w - b4.y, 0.0f);
    }
    __syncthreads();

    // ---- colmask: row jj, parity p, branchless IoU ----
    {
        const int jj = (int)(tid < 320 ? tid : tid - 320);
        const int p  = (int)(tid < 320 ? 0 : 1);
        if (jj < T) {
            float4 b = sbox[jj];
            float ar = sbar[jj];
            u64 cm[NWORDS] = {0,0,0,0,0};
            for (int i = p; i < jj; i += 2) {
                float4 bi = sbox[i];
                float iw = fmaxf(fminf(b.z, bi.z) - fmaxf(b.x, bi.x), 0.0f);
                float ih = fmaxf(fminf(b.w, bi.w) - fmaxf(b.y, bi.y), 0.0f);
                float inter = iw * ih;
                float uni = ((ar + sbar[i]) - inter) + 1e-8f;
                if (inter / uni > 0.5f) cm[i >> 6] |= 1ull << (i & 63);
            }
            #pragma unroll
            for (int w = 0; w < NWORDS; ++w)
                if (cm[w]) atomicOr(&iomaskT[w][jj], cm[w]);
        }
    }
    __syncthreads();

    // ---- wave 0: word-serial, round-parallel ballot greedy ----
    if (tid < 64) {
        u64 K[NWORDS];
        #pragma unroll
        for (int w = 0; w < NWORDS; ++w) {
            int b = w * 64 + lane;
            bool valid = (b < T);
            u64 cmw = 0, se = 0;
            if (valid) {
                #pragma unroll
                for (int w2 = 0; w2 < NWORDS; ++w2)
                    if (w2 < w) se |= K[w2] & iomaskT[w2][b];
                cmw = iomaskT[w][b];
            }
            u64 U = __ballot(valid && se == 0);
            u64 Kw = 0;
            int guard = 0;
            while (U && guard++ < 64) {
                u64 newk = __ballot(((U >> lane) & 1ull) && ((cmw & U) == 0));
                Kw |= newk; U &= ~newk;
                u64 supp = __ballot((cmw & Kw) != 0);
                U &= ~supp;
            }
            K[w] = Kw;
        }
        if (lane == 0) {
            #pragma unroll
            for (int w = 0; w < NWORDS; ++w) s_keep[w] = K[w];
        }
    }
    __syncthreads();

    if ((int)tid < T) {
        if ((s_keep[tid >> 6] >> (tid & 63)) & 1ull) {
            u32 sbits = (u32)(key >> 32);
            u64 outk = ((u64)sbits << 32) | (u32)(255 - c);
            atomicMax(&akey[aidx], outk);
        }
    }
}

// ---------------- finalize ----------------
__global__ void finalize_kernel(const u64* __restrict__ akey,
                                float* __restrict__ out, int A)
{
    int a = blockIdx.x * blockDim.x + threadIdx.x;
    if (a >= A) return;
    float* scores = out;
    float* labels = out + A;
    float* boxes  = out + (size_t)2 * A;
    u64 k = akey[a];
    if (k) {
        scores[a] = __uint_as_float((u32)(k >> 32));
        labels[a] = (float)(int)(255u - (u32)(k & 0xFFFFFFFFull));
    } else {
        scores[a] = 0.0f;
        labels[a] = -1.0f;
        boxes[(size_t)a*4+0] = 0.0f;
        boxes[(size_t)a*4+1] = 0.0f;
        boxes[(size_t)a*4+2] = 0.0f;
        boxes[(size_t)a*4+3] = 0.0f;
    }
}

// ---------------- fallback (generic C / small ws): round-1 proven kernel ----------------
#define FB_CAP 1024
__global__ __launch_bounds__(256) void fb_topk_nms_kernel(
    const float* __restrict__ cls,
    const float* __restrict__ boxes,
    u64* __restrict__ akey,
    int A, int C)
{
    const int c   = blockIdx.x;
    const int tid = threadIdx.x;

    __shared__ u32 hist[HBINS];
    __shared__ u64 cand[FB_CAP];
    __shared__ float bx1[TOPK], by1[TOPK], bx2[TOPK], by2[TOPK], bar[TOPK];
    __shared__ u64 iomask[TOPK][NWORDS];
    __shared__ u64 keepm[NWORDS];
    __shared__ u32 s_sel1, s_sel2, s_rem, s_cnt;

    for (int i = tid; i < HBINS; i += 256) hist[i] = 0;
    __syncthreads();
    for (int a = tid; a < A; a += 256) {
        float s = cls[(size_t)a * C + c];
        if (s > CLS_T) {
            u32 k = __float_as_uint(s) - KEY_BASE;
            u32 b = k >> 14; if (b >= HBINS) b = HBINS - 1;
            atomicAdd(&hist[b], 1u);
        }
    }
    __syncthreads();
    if (tid == 0) {
        u32 cum = 0; int sel = 0;
        for (int d = HBINS - 1; d >= 0; --d) {
            u32 nc = cum + hist[d];
            if (nc >= TOPK) { sel = d; break; }
            cum = nc;
        }
        s_sel1 = (u32)sel; s_rem = TOPK - cum;
    }
    __syncthreads();
    const u32 sel1 = s_sel1;

    for (int i = tid; i < 256; i += 256) hist[i] = 0;
    __syncthreads();
    for (int a = tid; a < A; a += 256) {
        float s = cls[(size_t)a * C + c];
        if (s > CLS_T) {
            u32 k = __float_as_uint(s) - KEY_BASE;
            u32 b = k >> 14; if (b >= HBINS) b = HBINS - 1;
            if (b == sel1) atomicAdd(&hist[(k >> 6) & 0xFF], 1u);
        }
    }
    __syncthreads();
    if (tid == 0) {
        u32 rem = s_rem, cum = 0; int sel = 0;
        for (int d = 255; d >= 0; --d) {
            u32 nc = cum + hist[d];
            if (nc >= rem) { sel = d; break; }
            cum = nc;
        }
        s_sel2 = (u32)sel; s_cnt = 0;
    }
    __syncthreads();
    const u32 thresh = (sel1 << 14) | (s_sel2 << 6);

    for (int a = tid; a < A; a += 256) {
        float s = cls[(size_t)a * C + c];
        if (s > CLS_T) {
            u32 bits = __float_as_uint(s);
            u32 k = bits - KEY_BASE;
            if (k >= thresh) {
                u32 pos = atomicAdd(&s_cnt, 1u);
                if (pos < FB_CAP) cand[pos] = ((u64)bits << 32) | (u32)(~(u32)a);
            }
        }
    }
    __syncthreads();
    const u32 total = s_cnt < FB_CAP ? s_cnt : FB_CAP;
    for (int i = tid; i < FB_CAP; i += 256)
        if (i >= (int)total) cand[i] = 0;
    __syncthreads();

    for (u32 kk = 2; kk <= FB_CAP; kk <<= 1) {
        for (u32 j = kk >> 1; j > 0; j >>= 1) {
            for (u32 i = tid; i < FB_CAP; i += 256) {
                u32 l = i ^ j;
                if (l > i) {
                    u64 av = cand[i], bv = cand[l];
                    bool up = ((i & kk) == 0);
                    if ((up && av < bv) || (!up && av > bv)) { cand[i] = bv; cand[l] = av; }
                }
            }
            __syncthreads();
        }
    }
    const int T = (int)(total < TOPK ? total : TOPK);

    for (int i = tid; i < T; i += 256) {
        u32 a = ~(u32)(cand[i] & 0xFFFFFFFFull);
        float x1 = boxes[(size_t)a*4+0], y1 = boxes[(size_t)a*4+1];
        float x2 = boxes[(size_t)a*4+2], y2 = boxes[(size_t)a*4+3];
        bx1[i] = x1; by1[i] = y1; bx2[i] = x2; by2[i] = y2;
        bar[i] = fmaxf(x2 - x1, 0.0f) * fmaxf(y2 - y1, 0.0f);
    }
    __syncthreads();

    for (int i = tid; i < T; i += 256) {
        u64 m[NWORDS] = {0,0,0,0,0};
        float x1 = bx1[i], y1 = by1[i], x2 = bx2[i], y2 = by2[i], ai = bar[i];
        for (int j = i + 1; j < T; ++j) {
            float iw = fmaxf(fminf(x2, bx2[j]) - fmaxf(x1, bx1[j]), 0.0f);
            float ih = fmaxf(fminf(y2, by2[j]) - fmaxf(y1, by1[j]), 0.0f);
            float inter = iw * ih;
            float uni = ((ai + bar[j]) - inter) + 1e-8f;
            if (inter / uni > 0.5f) m[j >> 6] |= 1ull << (j & 63);
        }
        for (int k2 = 0; k2 < NWORDS; ++k2) iomask[i][k2] = m[k2];
    }
    __syncthreads();

    if (tid == 0) {
        u64 sup[NWORDS] = {0,0,0,0,0};
        u64 kp [NWORDS] = {0,0,0,0,0};
        for (int i = 0; i < T; ++i) {
            if (!((sup[i >> 6] >> (i & 63)) & 1ull)) {
                kp[i >> 6] |= 1ull << (i & 63);
                for (int k2 = 0; k2 < NWORDS; ++k2) sup[k2] |= iomask[i][k2];
            }
        }
        for (int k2 = 0; k2 < NWORDS; ++k2) keepm[k2] = kp[k2];
    }
    __syncthreads();

    for (int i = tid; i < T; i += 256) {
        if ((keepm[i >> 6] >> (i & 63)) & 1ull) {
            u64 key = cand[i];
            u32 a = ~(u32)(key & 0xFFFFFFFFull);
            u32 sbits = (u32)(key >> 32);
            u64 outk = ((u64)sbits << 32) | (u32)(255 - c);
            atomicMax(&akey[a], outk);
        }
    }
}

extern "C" void kernel_launch(void* const* d_in, const int* in_sizes, int n_in,
                              void* d_out, int out_size, void* d_ws, size_t ws_size,
                              hipStream_t stream) {
    const float* cls = (const float*)d_in[0];
    const float* reg = (const float*)d_in[1];
    const float* anc = (const float*)d_in[2];
    const int*   ph  = (const int*)d_in[3];
    const int*   pw  = (const int*)d_in[4];

    int A = in_sizes[2] / 4;
    int C = in_sizes[0] / A;

    float* out       = (float*)d_out;
    float* out_boxes = out + (size_t)2 * A;

    // workspace: akey | segcnt | pref | totals | gbuf | gbuf2
    size_t akey_bytes = (size_t)A * sizeof(u64);
    size_t off_sc     = (akey_bytes + 255) & ~(size_t)255;
    size_t sc_bytes   = (size_t)80 * NBLK * sizeof(u32);
    size_t off_pf     = (off_sc + sc_bytes + 255) & ~(size_t)255;
    size_t off_tt     = (off_pf + sc_bytes + 255) & ~(size_t)255;
    size_t tt_bytes   = 80 * sizeof(u32);
    size_t off_gb     = (off_tt + tt_bytes + 255) & ~(size_t)255;
    size_t gb_bytes   = (size_t)80 * NBLK * SCAP * sizeof(u64);
    size_t off_g2     = (off_gb + gb_bytes + 255) & ~(size_t)255;
    size_t g2_bytes   = (size_t)80 * DCAP * sizeof(u64);
    size_t need       = off_g2 + g2_bytes;

    u64* akey = (u64*)d_ws;

    bool fastpath = (C == 80) && ((A & 3) == 0) && (A < (1 << 20)) && (ws_size >= need);

    if (fastpath) {
        u32* segcnt = (u32*)((char*)d_ws + off_sc);
        u32* pref   = (u32*)((char*)d_ws + off_pf);
        u32* totals = (u32*)((char*)d_ws + off_tt);
        u64* gbuf   = (u64*)((char*)d_ws + off_gb);
        u64* gbuf2  = (u64*)((char*)d_ws + off_g2);

        fused_scan_kernel<<<NBLK, 256, 0, stream>>>(anc, reg, ph, pw, cls,
                                                    out_boxes, akey, gbuf, segcnt, A);
        prefix_kernel<<<80, 256, 0, stream>>>(segcnt, pref, totals);
        compact_kernel<<<NBLK, 256, 0, stream>>>(segcnt, pref, gbuf, gbuf2);
        class_fused_kernel<<<C, 640, 0, stream>>>(totals, gbuf2, cls, out_boxes, akey, A, C);
    } else {
        decode_kernel<<<(A + 255) / 256, 256, 0, stream>>>(anc, reg, ph, pw, out_boxes, akey, A);
        fb_topk_nms_kernel<<<C, 256, 0, stream>>>(cls, out_boxes, akey, A, C);
    }

    finalize_kernel<<<(A + 255) / 256, 256, 0, stream>>>(akey, out, A);
}

// Round 15
// 59.523 us; speedup vs baseline: 2.8262x; 1.1765x over previous
//
#include <hip/hip_runtime.h>
#include <cstdint>

typedef unsigned long long u64;
typedef unsigned int u32;

#define CLS_T    0.05f
#define T1G      0.9965f    // single collect threshold (fast path)
#define TOPK     300
#define NWORDS   5          // ceil(300/64)
#define HBINS    2560
#define KEY_BASE 0x3D000000u
#define CCAP     1024
#define NBLK     2048       // scan blocks
#define SCAP     16         // slots per (class, scan-block): 128B segment
#define OVBIT    0x80000000u

__device__ inline u32 bin_of_bits(u32 bits) {
    u32 b = (bits - KEY_BASE) >> 14;
    if (b > (HBINS - 1)) b = HBINS - 1;
    return b;
}

// compare-exchange for register bitonic: keep max if (lo==up), else min
__device__ inline void cex(u64& v, u64 p, bool lo, bool up) {
    u64 mx = v > p ? v : p;
    u64 mn = v > p ? p : v;
    v = (lo == up) ? mx : mn;
}
__device__ inline void sstep(u64& a0, u64& a1, u32 tid, u32 kk, u32 j) {
    u64 p0 = __shfl_xor((unsigned long long)a0, (int)j, 64);
    u64 p1 = __shfl_xor((unsigned long long)a1, (int)j, 64);
    bool lo = ((tid & j) == 0);
    cex(a0, p0, lo, ((tid & kk) == 0));
    cex(a1, p1, lo, (((tid + 512u) & kk) == 0));
}
// 640-thread-safe LDS exchange step: all threads hit barriers, tid<512 work
__device__ inline void lstep640(u64* cand, u64& a0, u64& a1, u32 tid, u32 kk, u32 j) {
    __syncthreads();
    if (tid < 512) { cand[tid] = a0; cand[tid + 512] = a1; }
    __syncthreads();
    if (tid < 512) {
        u64 p0 = cand[tid ^ j], p1 = cand[(tid ^ j) + 512];
        bool lo = ((tid & j) == 0);
        cex(a0, p0, lo, ((tid & kk) == 0));
        cex(a1, p1, lo, (((tid + 512u) & kk) == 0));
    }
}

// ---------------- standalone decode (fallback path only) ----------------
__global__ void decode_kernel(const float* __restrict__ anc,
                              const float* __restrict__ reg,
                              const int* __restrict__ ph,
                              const int* __restrict__ pw,
                              float* __restrict__ boxes,
                              u64* __restrict__ akey, int A)
{
    int a = blockIdx.x * blockDim.x + threadIdx.x;
    if (a >= A) return;
    akey[a] = 0;
    float x1 = anc[a*4+0], y1 = anc[a*4+1], x2 = anc[a*4+2], y2 = anc[a*4+3];
    float w = x2 - x1, h = y2 - y1;
    float cx = x1 + 0.5f*w, cy = y1 + 0.5f*h;
    float r0 = reg[a*4+0]*0.1f, r1 = reg[a*4+1]*0.1f;
    float r2 = reg[a*4+2]*0.2f, r3 = reg[a*4+3]*0.2f;
    float pcx = cx + r0*w, pcy = cy + r1*h;
    float pw_ = expf(r2)*w, ph_ = expf(r3)*h;
    float W = (float)(*pw), H = (float)(*ph);
    boxes[a*4+0] = fmaxf(pcx - 0.5f*pw_, 0.0f);
    boxes[a*4+1] = fmaxf(pcy - 0.5f*ph_, 0.0f);
    boxes[a*4+2] = fminf(pcx + 0.5f*pw_, W);
    boxes[a*4+3] = fminf(pcy + 0.5f*ph_, H);
}

// ---------------- fused decode + one-pass collect at T1 (zero global atomics) ----------------
// Overflow signaled via bit31 of segcnt entries.
__global__ __launch_bounds__(256) void fused_scan_kernel(
    const float* __restrict__ anc, const float* __restrict__ reg,
    const int* __restrict__ ph, const int* __restrict__ pw,
    const float* __restrict__ cls,
    float* __restrict__ boxes, u64* __restrict__ akey,
    u64* __restrict__ gbuf, u32* __restrict__ segcnt, int A)
{
    const int tid = threadIdx.x;
    const int blk = blockIdx.x;

    // ---- decode part (grid-stride; independent of scan data) ----
    float W = (float)(*pw), H = (float)(*ph);
    for (int a = blk * 256 + tid; a < A; a += NBLK * 256) {
        akey[a] = 0;
        float x1 = anc[a*4+0], y1 = anc[a*4+1], x2 = anc[a*4+2], y2 = anc[a*4+3];
        float w = x2 - x1, h = y2 - y1;
        float cx = x1 + 0.5f*w, cy = y1 + 0.5f*h;
        float r0 = reg[a*4+0]*0.1f, r1 = reg[a*4+1]*0.1f;
        float r2 = reg[a*4+2]*0.2f, r3 = reg[a*4+3]*0.2f;
        float pcx = cx + r0*w, pcy = cy + r1*h;
        float pw_ = expf(r2)*w, ph_ = expf(r3)*h;
        boxes[a*4+0] = fmaxf(pcx - 0.5f*pw_, 0.0f);
        boxes[a*4+1] = fmaxf(pcy - 0.5f*ph_, 0.0f);
        boxes[a*4+2] = fminf(pcx + 0.5f*pw_, W);
        boxes[a*4+3] = fminf(pcy + 0.5f*ph_, H);
    }

    // ---- scan-collect part (threshold T1 directly) ----
    __shared__ u32 cnt[80];
    __shared__ u64 buf[80][SCAP];
    __shared__ u32 s_over;
    for (int i = tid; i < 80; i += 256) cnt[i] = 0;
    if (tid == 0) s_over = 0;
    __syncthreads();

    size_t Nf4 = (size_t)A * 20;   // A*80/4
    const float4* p4 = (const float4*)cls;
    for (size_t i = (size_t)blk * 256 + tid; i < Nf4; i += (size_t)NBLK * 256) {
        float4 v = p4[i];
        float ss[4] = {v.x, v.y, v.z, v.w};
        #pragma unroll
        for (int q = 0; q < 4; ++q) {
            if (ss[q] > T1G) {
                u32 flat = (u32)(i * 4 + q);
                u32 a = flat / 80u;            // const-div -> magic mul
                u32 c = flat - a * 80u;
                u32 p = atomicAdd(&cnt[c], 1u);   // LDS atomic only
                if (p < SCAP) buf[c][p] = ((u64)__float_as_uint(ss[q]) << 32) | (u32)(~a);
                else s_over = 1;
            }
        }
    }
    __syncthreads();

    const u32 ob = s_over ? OVBIT : 0u;
    for (int m = tid; m < 80 * SCAP; m += 256) {
        int c = m / SCAP, e = m - c * SCAP;
        u32 cc = cnt[c]; if (cc > SCAP) cc = SCAP;
        if ((u32)e < cc)
            gbuf[((size_t)c * NBLK + blk) * SCAP + e] = buf[c][e];
    }
    for (int c = tid; c < 80; c += 256) {
        u32 cc = cnt[c]; if (cc > SCAP) cc = SCAP;
        segcnt[(size_t)c * NBLK + blk] = cc | ob;
    }
}

// ---------------- per-class exclusive prefix + totals (propagates bit31) ----------------
__global__ __launch_bounds__(256) void prefix_kernel(
    const u32* __restrict__ segcnt, u32* __restrict__ pref,
    u32* __restrict__ totals)
{
    const int c = blockIdx.x;
    const int tid = threadIdx.x;
    __shared__ u32 part[256];
    __shared__ u32 s_ob;
    if (tid == 0) s_ob = 0;
    __syncthreads();

    const u32* row = segcnt + (size_t)c * NBLK;
    u32 v[8];
    u32 s = 0, ob = 0;
    #pragma unroll
    for (int q = 0; q < 8; ++q) {
        u32 r = row[tid * 8 + q];
        ob |= r & OVBIT;
        v[q] = r & ~OVBIT;
        s += v[q];
    }
    if (ob) atomicOr(&s_ob, 1u);
    part[tid] = s;
    __syncthreads();
    for (int d = 1; d < 256; d <<= 1) {
        u32 t = (tid >= d) ? part[tid - d] : 0;
        __syncthreads();
        part[tid] += t;
        __syncthreads();
    }
    u32 running = part[tid] - s;
    u32* prow = pref + (size_t)c * NBLK;
    #pragma unroll
    for (int q = 0; q < 8; ++q) { prow[tid * 8 + q] = running; running += v[q]; }
    if (tid == 255) totals[c] = part[255] | (s_ob ? OVBIT : 0u);
}

// ---------------- fused per-class: direct gather (binary search) + sort + NMS ----------------
__global__ __launch_bounds__(640) void class_fused_kernel(
    const u32* __restrict__ totals, const u32* __restrict__ pref,
    const u64* __restrict__ gbuf,
    const float* __restrict__ cls,     // [A][C] for slow path
    const float* __restrict__ boxes, u64* __restrict__ akey, int A, int C)
{
    const int c = blockIdx.x;
    const u32 tid = threadIdx.x;
    const int lane = tid & 63;

    __shared__ u32 sh[HBINS];          // slow path histogram
    __shared__ u32 sp[NBLK];           // fast path: staged pref row
    __shared__ u64 cand[CCAP];
    __shared__ u32 s_sel, s_cnt, s_rem;
    __shared__ float4 sbox[TOPK];
    __shared__ float  sbar[TOPK];
    __shared__ u64 iomaskT[NWORDS][TOPK];
    __shared__ u64 s_keep[NWORDS];

    if (tid == 0) { s_sel = 0; s_cnt = 0; }
    __syncthreads();

    const u32 traw = totals[c];
    const bool over = (traw & OVBIT) != 0;
    const u32 n = traw & ~OVBIT;
    u32 cnt_f = 0;
    bool fast_ok = false;

    if (!over && n >= TOPK && n <= CCAP) {
        // stage pref row
        for (int i = tid; i < NBLK; i += 640) sp[i] = pref[(size_t)c * NBLK + i];
        __syncthreads();
        // direct gather: dense index i -> (segment b, slot e) via binary search
        for (u32 i = tid; i < n; i += 640) {
            int lo = 0, hi = NBLK;
            while (hi - lo > 1) {
                int mid = (lo + hi) >> 1;
                if (sp[mid] <= i) lo = mid; else hi = mid;
            }
            u32 e = i - sp[lo];
            cand[i] = gbuf[((size_t)c * NBLK + lo) * SCAP + e];
        }
        __syncthreads();
        cnt_f = n;
        fast_ok = true;
    }

    if (!fast_ok) {
        // ---- slow exact path: 2-level select over the class column ----
        __syncthreads();
        for (int i = tid; i < HBINS; i += 640) sh[i] = 0;
        if (tid == 0) s_cnt = 0;
        __syncthreads();
        for (int a = tid; a < A; a += 640) {
            float s = cls[(size_t)a * C + c];
            if (s > CLS_T) atomicAdd(&sh[bin_of_bits(__float_as_uint(s))], 1u);
        }
        __syncthreads();
        if (tid == 0) {
            u32 cum = 0; int sel = 0;
            for (int d = HBINS - 1; d >= 0; --d) {
                u32 nc = cum + sh[d];
                if (nc >= TOPK) { sel = d; break; }
                cum = nc;
            }
            s_sel = (u32)sel; s_rem = TOPK - cum;
        }
        __syncthreads();
        const u32 sel1 = s_sel;
        __syncthreads();
        for (int i = tid; i < 256; i += 640) sh[i] = 0;
        __syncthreads();
        for (int a = tid; a < A; a += 640) {
            float s = cls[(size_t)a * C + c];
            if (s > CLS_T) {
                u32 k = __float_as_uint(s) - KEY_BASE;
                u32 b = k >> 14; if (b >= HBINS) b = HBINS - 1;
                if (b == sel1) atomicAdd(&sh[(k >> 6) & 0xFF], 1u);
            }
        }
        __syncthreads();
        if (tid == 0) {
            u32 rem = s_rem, cum = 0; int sel = 0;
            for (int d = 255; d >= 0; --d) {
                u32 nc = cum + sh[d];
                if (nc >= rem) { sel = d; break; }
                cum = nc;
            }
            s_sel = (sel1 << 14) | ((u32)sel << 6);
            s_cnt = 0;
        }
        __syncthreads();
        const u32 thresh = s_sel;
        for (int a = tid; a < A; a += 640) {
            float s = cls[(size_t)a * C + c];
            if (s > CLS_T) {
                u32 bits = __float_as_uint(s);
                if (bits - KEY_BASE >= thresh) {
                    u32 p = atomicAdd(&s_cnt, 1u);
                    if (p < CCAP) cand[p] = ((u64)bits << 32) | (u32)(~(u32)a);
                }
            }
        }
        __syncthreads();
        cnt_f = s_cnt < CCAP ? s_cnt : CCAP;
    }

    // pad + zero iomaskT
    for (u32 i = cnt_f + tid; i < CCAP; i += 640) cand[i] = 0;
    for (int m = tid; m < NWORDS * TOPK; m += 640) ((u64*)iomaskT)[m] = 0;
    __syncthreads();

    // ---- register bitonic sort of 1024 (tid<512 active, barrier-safe) ----
    u64 a0 = 0, a1 = 0;
    if (tid < 512) { a0 = cand[tid]; a1 = cand[tid + 512]; }
    if (tid < 512)
        for (u32 kk = 2; kk <= 64; kk <<= 1)
            for (u32 j = kk >> 1; j >= 1; j >>= 1)
                sstep(a0, a1, tid, kk, j);
    lstep640(cand, a0, a1, tid, 128u, 64u);
    if (tid < 512) for (u32 j = 32; j >= 1; j >>= 1) sstep(a0, a1, tid, 128u, j);
    lstep640(cand, a0, a1, tid, 256u, 128u);
    lstep640(cand, a0, a1, tid, 256u, 64u);
    if (tid < 512) for (u32 j = 32; j >= 1; j >>= 1) sstep(a0, a1, tid, 256u, j);
    lstep640(cand, a0, a1, tid, 512u, 256u);
    lstep640(cand, a0, a1, tid, 512u, 128u);
    lstep640(cand, a0, a1, tid, 512u, 64u);
    if (tid < 512) for (u32 j = 32; j >= 1; j >>= 1) sstep(a0, a1, tid, 512u, j);
    if (tid < 512) {   // kk=1024, j=512: in-thread exchange
        u64 mx = a0 > a1 ? a0 : a1, mn = a0 > a1 ? a1 : a0;
        a0 = mx; a1 = mn;
    }
    lstep640(cand, a0, a1, tid, 1024u, 256u);
    lstep640(cand, a0, a1, tid, 1024u, 128u);
    lstep640(cand, a0, a1, tid, 1024u, 64u);
    if (tid < 512) for (u32 j = 32; j >= 1; j >>= 1) sstep(a0, a1, tid, 1024u, j);
    // thread tid<512 holds sorted element tid in a0

    const int T = (int)(cnt_f < TOPK ? cnt_f : TOPK);

    // ---- boxes for my candidate ----
    u64 key = a0; u32 aidx = 0;
    if ((int)tid < T) {
        aidx = ~(u32)(key & 0xFFFFFFFFull);
        float4 b4 = *(const float4*)(boxes + (size_t)aidx * 4);
        sbox[tid] = b4;
        sbar[tid] = fmaxf(b4.z - b4.x, 0.0f) * fmaxf(b4.w - b4.y, 0.0f);
    }
    __syncthreads();

    // ---- colmask: row jj, parity p, branchless IoU ----
    {
        const int jj = (int)(tid < 320 ? tid : tid - 320);
        const int p  = (int)(tid < 320 ? 0 : 1);
        if (jj < T) {
            float4 b = sbox[jj];
            float ar = sbar[jj];
            u64 cm[NWORDS] = {0,0,0,0,0};
            for (int i = p; i < jj; i += 2) {
                float4 bi = sbox[i];
                float iw = fmaxf(fminf(b.z, bi.z) - fmaxf(b.x, bi.x), 0.0f);
                float ih = fmaxf(fminf(b.w, bi.w) - fmaxf(b.y, bi.y), 0.0f);
                float inter = iw * ih;
                float uni = ((ar + sbar[i]) - inter) + 1e-8f;
                if (inter / uni > 0.5f) cm[i >> 6] |= 1ull << (i & 63);
            }
            #pragma unroll
            for (int w = 0; w < NWORDS; ++w)
                if (cm[w]) atomicOr(&iomaskT[w][jj], cm[w]);
        }
    }
    __syncthreads();

    // ---- wave 0: word-serial, round-parallel ballot greedy ----
    if (tid < 64) {
        u64 K[NWORDS];
        #pragma unroll
        for (int w = 0; w < NWORDS; ++w) {
            int b = w * 64 + lane;
            bool valid = (b < T);
            u64 cmw = 0, se = 0;
            if (valid) {
                #pragma unroll
                for (int w2 = 0; w2 < NWORDS; ++w2)
                    if (w2 < w) se |= K[w2] & iomaskT[w2][b];
                cmw = iomaskT[w][b];
            }
            u64 U = __ballot(valid && se == 0);
            u64 Kw = 0;
            int guard = 0;
            while (U && guard++ < 64) {
                u64 newk = __ballot(((U >> lane) & 1ull) && ((cmw & U) == 0));
                Kw |= newk; U &= ~newk;
                u64 supp = __ballot((cmw & Kw) != 0);
                U &= ~supp;
            }
            K[w] = Kw;
        }
        if (lane == 0) {
            #pragma unroll
            for (int w = 0; w < NWORDS; ++w) s_keep[w] = K[w];
        }
    }
    __syncthreads();

    if ((int)tid < T) {
        if ((s_keep[tid >> 6] >> (tid & 63)) & 1ull) {
            u32 sbits = (u32)(key >> 32);
            u64 outk = ((u64)sbits << 32) | (u32)(255 - c);
            atomicMax(&akey[aidx], outk);
        }
    }
}

// ---------------- finalize ----------------
__global__ void finalize_kernel(const u64* __restrict__ akey,
                                float* __restrict__ out, int A)
{
    int a = blockIdx.x * blockDim.x + threadIdx.x;
    if (a >= A) return;
    float* scores = out;
    float* labels = out + A;
    float* boxes  = out + (size_t)2 * A;
    u64 k = akey[a];
    if (k) {
        scores[a] = __uint_as_float((u32)(k >> 32));
        labels[a] = (float)(int)(255u - (u32)(k & 0xFFFFFFFFull));
    } else {
        scores[a] = 0.0f;
        labels[a] = -1.0f;
        boxes[(size_t)a*4+0] = 0.0f;
        boxes[(size_t)a*4+1] = 0.0f;
        boxes[(size_t)a*4+2] = 0.0f;
        boxes[(size_t)a*4+3] = 0.0f;
    }
}

// ---------------- fallback (generic C / small ws): round-1 proven kernel ----------------
#define FB_CAP 1024
__global__ __launch_bounds__(256) void fb_topk_nms_kernel(
    const float* __restrict__ cls,
    const float* __restrict__ boxes,
    u64* __restrict__ akey,
    int A, int C)
{
    const int c   = blockIdx.x;
    const int tid = threadIdx.x;

    __shared__ u32 hist[HBINS];
    __shared__ u64 cand[FB_CAP];
    __shared__ float bx1[TOPK], by1[TOPK], bx2[TOPK], by2[TOPK], bar[TOPK];
    __shared__ u64 iomask[TOPK][NWORDS];
    __shared__ u64 keepm[NWORDS];
    __shared__ u32 s_sel1, s_sel2, s_rem, s_cnt;

    for (int i = tid; i < HBINS; i += 256) hist[i] = 0;
    __syncthreads();
    for (int a = tid; a < A; a += 256) {
        float s = cls[(size_t)a * C + c];
        if (s > CLS_T) {
            u32 k = __float_as_uint(s) - KEY_BASE;
            u32 b = k >> 14; if (b >= HBINS) b = HBINS - 1;
            atomicAdd(&hist[b], 1u);
        }
    }
    __syncthreads();
    if (tid == 0) {
        u32 cum = 0; int sel = 0;
        for (int d = HBINS - 1; d >= 0; --d) {
            u32 nc = cum + hist[d];
            if (nc >= TOPK) { sel = d; break; }
            cum = nc;
        }
        s_sel1 = (u32)sel; s_rem = TOPK - cum;
    }
    __syncthreads();
    const u32 sel1 = s_sel1;

    for (int i = tid; i < 256; i += 256) hist[i] = 0;
    __syncthreads();
    for (int a = tid; a < A; a += 256) {
        float s = cls[(size_t)a * C + c];
        if (s > CLS_T) {
            u32 k = __float_as_uint(s) - KEY_BASE;
            u32 b = k >> 14; if (b >= HBINS) b = HBINS - 1;
            if (b == sel1) atomicAdd(&hist[(k >> 6) & 0xFF], 1u);
        }
    }
    __syncthreads();
    if (tid == 0) {
        u32 rem = s_rem, cum = 0; int sel = 0;
        for (int d = 255; d >= 0; --d) {
            u32 nc = cum + hist[d];
            if (nc >= rem) { sel = d; break; }
            cum = nc;
        }
        s_sel2 = (u32)sel; s_cnt = 0;
    }
    __syncthreads();
    const u32 thresh = (sel1 << 14) | (s_sel2 << 6);

    for (int a = tid; a < A; a += 256) {
        float s = cls[(size_t)a * C + c];
        if (s > CLS_T) {
            u32 bits = __float_as_uint(s);
            u32 k = bits - KEY_BASE;
            if (k >= thresh) {
                u32 pos = atomicAdd(&s_cnt, 1u);
                if (pos < FB_CAP) cand[pos] = ((u64)bits << 32) | (u32)(~(u32)a);
            }
        }
    }
    __syncthreads();
    const u32 total = s_cnt < FB_CAP ? s_cnt : FB_CAP;
    for (int i = tid; i < FB_CAP; i += 256)
        if (i >= (int)total) cand[i] = 0;
    __syncthreads();

    for (u32 kk = 2; kk <= FB_CAP; kk <<= 1) {
        for (u32 j = kk >> 1; j > 0; j >>= 1) {
            for (u32 i = tid; i < FB_CAP; i += 256) {
                u32 l = i ^ j;
                if (l > i) {
                    u64 av = cand[i], bv = cand[l];
                    bool up = ((i & kk) == 0);
                    if ((up && av < bv) || (!up && av > bv)) { cand[i] = bv; cand[l] = av; }
                }
            }
            __syncthreads();
        }
    }
    const int T = (int)(total < TOPK ? total : TOPK);

    for (int i = tid; i < T; i += 256) {
        u32 a = ~(u32)(cand[i] & 0xFFFFFFFFull);
        float x1 = boxes[(size_t)a*4+0], y1 = boxes[(size_t)a*4+1];
        float x2 = boxes[(size_t)a*4+2], y2 = boxes[(size_t)a*4+3];
        bx1[i] = x1; by1[i] = y1; bx2[i] = x2; by2[i] = y2;
        bar[i] = fmaxf(x2 - x1, 0.0f) * fmaxf(y2 - y1, 0.0f);
    }
    __syncthreads();

    for (int i = tid; i < T; i += 256) {
        u64 m[NWORDS] = {0,0,0,0,0};
        float x1 = bx1[i], y1 = by1[i], x2 = bx2[i], y2 = by2[i], ai = bar[i];
        for (int j = i + 1; j < T; ++j) {
            float iw = fmaxf(fminf(x2, bx2[j]) - fmaxf(x1, bx1[j]), 0.0f);
            float ih = fmaxf(fminf(y2, by2[j]) - fmaxf(y1, by1[j]), 0.0f);
            float inter = iw * ih;
            float uni = ((ai + bar[j]) - inter) + 1e-8f;
            if (inter / uni > 0.5f) m[j >> 6] |= 1ull << (j & 63);
        }
        for (int k2 = 0; k2 < NWORDS; ++k2) iomask[i][k2] = m[k2];
    }
    __syncthreads();

    if (tid == 0) {
        u64 sup[NWORDS] = {0,0,0,0,0};
        u64 kp [NWORDS] = {0,0,0,0,0};
        for (int i = 0; i < T; ++i) {
            if (!((sup[i >> 6] >> (i & 63)) & 1ull)) {
                kp[i >> 6] |= 1ull << (i & 63);
                for (int k2 = 0; k2 < NWORDS; ++k2) sup[k2] |= iomask[i][k2];
            }
        }
        for (int k2 = 0; k2 < NWORDS; ++k2) keepm[k2] = kp[k2];
    }
    __syncthreads();

    for (int i = tid; i < T; i += 256) {
        if ((keepm[i >> 6] >> (i & 63)) & 1ull) {
            u64 key = cand[i];
            u32 a = ~(u32)(key & 0xFFFFFFFFull);
            u32 sbits = (u32)(key >> 32);
            u64 outk = ((u64)sbits << 32) | (u32)(255 - c);
            atomicMax(&akey[a], outk);
        }
    }
}

extern "C" void kernel_launch(void* const* d_in, const int* in_sizes, int n_in,
                              void* d_out, int out_size, void* d_ws, size_t ws_size,
                              hipStream_t stream) {
    const float* cls = (const float*)d_in[0];
    const float* reg = (const float*)d_in[1];
    const float* anc = (const float*)d_in[2];
    const int*   ph  = (const int*)d_in[3];
    const int*   pw  = (const int*)d_in[4];

    int A = in_sizes[2] / 4;
    int C = in_sizes[0] / A;

    float* out       = (float*)d_out;
    float* out_boxes = out + (size_t)2 * A;

    // workspace: akey | segcnt | pref | totals | gbuf
    size_t akey_bytes = (size_t)A * sizeof(u64);
    size_t off_sc     = (akey_bytes + 255) & ~(size_t)255;
    size_t sc_bytes   = (size_t)80 * NBLK * sizeof(u32);
    size_t off_pf     = (off_sc + sc_bytes + 255) & ~(size_t)255;
    size_t off_tt     = (off_pf + sc_bytes + 255) & ~(size_t)255;
    size_t tt_bytes   = 80 * sizeof(u32);
    size_t off_gb     = (off_tt + tt_bytes + 255) & ~(size_t)255;
    size_t gb_bytes   = (size_t)80 * NBLK * SCAP * sizeof(u64);
    size_t need       = off_gb + gb_bytes;

    u64* akey = (u64*)d_ws;

    bool fastpath = (C == 80) && ((A & 3) == 0) && (A < (1 << 20)) && (ws_size >= need);

    if (fastpath) {
        u32* segcnt = (u32*)((char*)d_ws + off_sc);
        u32* pref   = (u32*)((char*)d_ws + off_pf);
        u32* totals = (u32*)((char*)d_ws + off_tt);
        u64* gbuf   = (u64*)((char*)d_ws + off_gb);

        fused_scan_kernel<<<NBLK, 256, 0, stream>>>(anc, reg, ph, pw, cls,
                                                    out_boxes, akey, gbuf, segcnt, A);
        prefix_kernel<<<80, 256, 0, stream>>>(segcnt, pref, totals);
        class_fused_kernel<<<C, 640, 0, stream>>>(totals, pref, gbuf, cls, out_boxes, akey, A, C);
    } else {
        decode_kernel<<<(A + 255) / 256, 256, 0, stream>>>(anc, reg, ph, pw, out_boxes, akey, A);
        fb_topk_nms_kernel<<<C, 256, 0, stream>>>(cls, out_boxes, akey, A, C);
    }

    finalize_kernel<<<(A + 255) / 256, 256, 0, stream>>>(akey, out, A);
}

// Round 16
// 57.275 us; speedup vs baseline: 2.9372x; 1.0392x over previous
//
#include <hip/hip_runtime.h>
#include <cstdint>

typedef unsigned long long u64;
typedef unsigned int u32;

#define CLS_T    0.05f
#define T1G      0.9965f    // single collect threshold (fast path)
#define TOPK     300
#define NWORDS   5          // ceil(300/64)
#define HBINS    2560
#define KEY_BASE 0x3D000000u
#define CCAP     1024
#define NBLK     2048       // scan blocks
#define SCAP     16         // slots per (class, scan-block): 128B segment
#define OVBIT    0x80000000u

__device__ inline u32 bin_of_bits(u32 bits) {
    u32 b = (bits - KEY_BASE) >> 14;
    if (b > (HBINS - 1)) b = HBINS - 1;
    return b;
}

// decode one anchor's box (identical arithmetic to reference)
__device__ inline float4 decode_box(const float* __restrict__ anc,
                                    const float* __restrict__ reg,
                                    u32 a, float W, float H)
{
    float x1 = anc[(size_t)a*4+0], y1 = anc[(size_t)a*4+1];
    float x2 = anc[(size_t)a*4+2], y2 = anc[(size_t)a*4+3];
    float w = x2 - x1, h = y2 - y1;
    float cx = x1 + 0.5f*w, cy = y1 + 0.5f*h;
    float r0 = reg[(size_t)a*4+0]*0.1f, r1 = reg[(size_t)a*4+1]*0.1f;
    float r2 = reg[(size_t)a*4+2]*0.2f, r3 = reg[(size_t)a*4+3]*0.2f;
    float pcx = cx + r0*w, pcy = cy + r1*h;
    float pw_ = expf(r2)*w, ph_ = expf(r3)*h;
    float4 b;
    b.x = fmaxf(pcx - 0.5f*pw_, 0.0f);
    b.y = fmaxf(pcy - 0.5f*ph_, 0.0f);
    b.z = fminf(pcx + 0.5f*pw_, W);
    b.w = fminf(pcy + 0.5f*ph_, H);
    return b;
}

// compare-exchange for register bitonic: keep max if (lo==up), else min
__device__ inline void cex(u64& v, u64 p, bool lo, bool up) {
    u64 mx = v > p ? v : p;
    u64 mn = v > p ? p : v;
    v = (lo == up) ? mx : mn;
}
__device__ inline void sstep(u64& a0, u64& a1, u32 tid, u32 kk, u32 j) {
    u64 p0 = __shfl_xor((unsigned long long)a0, (int)j, 64);
    u64 p1 = __shfl_xor((unsigned long long)a1, (int)j, 64);
    bool lo = ((tid & j) == 0);
    cex(a0, p0, lo, ((tid & kk) == 0));
    cex(a1, p1, lo, (((tid + 512u) & kk) == 0));
}
// 640-thread-safe LDS exchange step
__device__ inline void lstep640(u64* cand, u64& a0, u64& a1, u32 tid, u32 kk, u32 j) {
    __syncthreads();
    if (tid < 512) { cand[tid] = a0; cand[tid + 512] = a1; }
    __syncthreads();
    if (tid < 512) {
        u64 p0 = cand[tid ^ j], p1 = cand[(tid ^ j) + 512];
        bool lo = ((tid & j) == 0);
        cex(a0, p0, lo, ((tid & kk) == 0));
        cex(a1, p1, lo, (((tid + 512u) & kk) == 0));
    }
}

// ---------------- standalone decode (fallback path only) ----------------
__global__ void decode_kernel(const float* __restrict__ anc,
                              const float* __restrict__ reg,
                              const int* __restrict__ ph,
                              const int* __restrict__ pw,
                              float* __restrict__ boxes,
                              u64* __restrict__ akey, int A)
{
    int a = blockIdx.x * blockDim.x + threadIdx.x;
    if (a >= A) return;
    akey[a] = 0;
    float W = (float)(*pw), H = (float)(*ph);
    float4 b = decode_box(anc, reg, (u32)a, W, H);
    boxes[a*4+0] = b.x; boxes[a*4+1] = b.y;
    boxes[a*4+2] = b.z; boxes[a*4+3] = b.w;
}

// ---------------- fused: zero akey + one-pass collect at T1 (zero global atomics) ----------------
__global__ __launch_bounds__(256) void fused_scan_kernel(
    const float* __restrict__ cls,
    u64* __restrict__ akey,
    u64* __restrict__ gbuf, u32* __restrict__ segcnt, int A)
{
    const int tid = threadIdx.x;
    const int blk = blockIdx.x;

    for (int a = blk * 256 + tid; a < A; a += NBLK * 256) akey[a] = 0;

    __shared__ u32 cnt[80];
    __shared__ u64 buf[80][SCAP];
    __shared__ u32 s_over;
    for (int i = tid; i < 80; i += 256) cnt[i] = 0;
    if (tid == 0) s_over = 0;
    __syncthreads();

    size_t Nf4 = (size_t)A * 20;   // A*80/4
    const float4* p4 = (const float4*)cls;
    for (size_t i = (size_t)blk * 256 + tid; i < Nf4; i += (size_t)NBLK * 256) {
        float4 v = p4[i];
        float ss[4] = {v.x, v.y, v.z, v.w};
        #pragma unroll
        for (int q = 0; q < 4; ++q) {
            if (ss[q] > T1G) {
                u32 flat = (u32)(i * 4 + q);
                u32 a = flat / 80u;            // const-div -> magic mul
                u32 c = flat - a * 80u;
                u32 p = atomicAdd(&cnt[c], 1u);   // LDS atomic only
                if (p < SCAP) buf[c][p] = ((u64)__float_as_uint(ss[q]) << 32) | (u32)(~a);
                else s_over = 1;
            }
        }
    }
    __syncthreads();

    const u32 ob = s_over ? OVBIT : 0u;
    for (int m = tid; m < 80 * SCAP; m += 256) {
        int c = m / SCAP, e = m - c * SCAP;
        u32 cc = cnt[c]; if (cc > SCAP) cc = SCAP;
        if ((u32)e < cc)
            gbuf[((size_t)c * NBLK + blk) * SCAP + e] = buf[c][e];
    }
    for (int c = tid; c < 80; c += 256) {
        u32 cc = cnt[c]; if (cc > SCAP) cc = SCAP;
        segcnt[(size_t)c * NBLK + blk] = cc | ob;
    }
}

// ---------------- fused per-class: in-block prefix + gather + sort + decode + NMS ----------------
__global__ __launch_bounds__(640) void class_fused_kernel(
    const u32* __restrict__ segcnt, const u64* __restrict__ gbuf,
    const float* __restrict__ cls,     // [A][C] for slow path
    const float* __restrict__ anc, const float* __restrict__ reg,
    const int* __restrict__ ph, const int* __restrict__ pw,
    u64* __restrict__ akey, int A, int C)
{
    const int c = blockIdx.x;
    const u32 tid = threadIdx.x;
    const int lane = tid & 63;

    __shared__ u32 sh[HBINS];          // slow path histogram; fast path scan partials
    __shared__ u32 sp[NBLK];           // exclusive prefix of segment counts
    __shared__ u64 cand[CCAP];
    __shared__ u32 s_sel, s_cnt, s_rem, s_ob;
    __shared__ float4 sbox[TOPK];
    __shared__ float  sbar[TOPK];
    __shared__ u64 iomaskT[NWORDS][TOPK];
    __shared__ u64 s_keep[NWORDS];

    if (tid == 0) { s_sel = 0; s_cnt = 0; s_ob = 0; }
    __syncthreads();

    const float W = (float)(*pw), H = (float)(*ph);

    // ---- in-block prefix over this class's segcnt row (512 threads x 4) ----
    u32 v[4] = {0,0,0,0};
    u32 s = 0;
    if (tid < 512) {
        const u32* row = segcnt + (size_t)c * NBLK;
        u32 ob = 0;
        #pragma unroll
        for (int q = 0; q < 4; ++q) {
            u32 r = row[tid * 4 + q];
            ob |= r & OVBIT;
            v[q] = r & ~OVBIT;
            s += v[q];
        }
        if (ob) atomicOr(&s_ob, 1u);
        sh[tid] = s;
    }
    __syncthreads();
    for (int d = 1; d < 512; d <<= 1) {
        u32 t2 = (tid >= (u32)d && tid < 512) ? sh[tid - d] : 0;
        __syncthreads();
        if (tid < 512) sh[tid] += t2;
        __syncthreads();
    }
    if (tid < 512) {
        u32 run = sh[tid] - s;
        #pragma unroll
        for (int q = 0; q < 4; ++q) { sp[tid * 4 + q] = run; run += v[q]; }
    }
    __syncthreads();
    const u32 n = sh[511];
    const bool over = (s_ob != 0);
    __syncthreads();   // sh reuse barrier (slow path zeroes it)

    u32 cnt_f = 0;
    bool fast_ok = false;

    if (!over && n >= TOPK && n <= CCAP) {
        // direct gather: dense index i -> (segment b, slot e) via binary search over sp
        for (u32 i = tid; i < n; i += 640) {
            int lo = 0, hi = NBLK;
            while (hi - lo > 1) {
                int mid = (lo + hi) >> 1;
                if (sp[mid] <= i) lo = mid; else hi = mid;
            }
            u32 e = i - sp[lo];
            cand[i] = gbuf[((size_t)c * NBLK + lo) * SCAP + e];
        }
        __syncthreads();
        cnt_f = n;
        fast_ok = true;
    }

    if (!fast_ok) {
        // ---- slow exact path: 2-level select over the class column ----
        __syncthreads();
        for (int i = tid; i < HBINS; i += 640) sh[i] = 0;
        if (tid == 0) s_cnt = 0;
        __syncthreads();
        for (int a = tid; a < A; a += 640) {
            float sc = cls[(size_t)a * C + c];
            if (sc > CLS_T) atomicAdd(&sh[bin_of_bits(__float_as_uint(sc))], 1u);
        }
        __syncthreads();
        if (tid == 0) {
            u32 cum = 0; int sel = 0;
            for (int d = HBINS - 1; d >= 0; --d) {
                u32 nc = cum + sh[d];
                if (nc >= TOPK) { sel = d; break; }
                cum = nc;
            }
            s_sel = (u32)sel; s_rem = TOPK - cum;
        }
        __syncthreads();
        const u32 sel1 = s_sel;
        __syncthreads();
        for (int i = tid; i < 256; i += 640) sh[i] = 0;
        __syncthreads();
        for (int a = tid; a < A; a += 640) {
            float sc = cls[(size_t)a * C + c];
            if (sc > CLS_T) {
                u32 k = __float_as_uint(sc) - KEY_BASE;
                u32 b = k >> 14; if (b >= HBINS) b = HBINS - 1;
                if (b == sel1) atomicAdd(&sh[(k >> 6) & 0xFF], 1u);
            }
        }
        __syncthreads();
        if (tid == 0) {
            u32 rem = s_rem, cum = 0; int sel = 0;
            for (int d = 255; d >= 0; --d) {
                u32 nc = cum + sh[d];
                if (nc >= rem) { sel = d; break; }
                cum = nc;
            }
            s_sel = (sel1 << 14) | ((u32)sel << 6);
            s_cnt = 0;
        }
        __syncthreads();
        const u32 thresh = s_sel;
        for (int a = tid; a < A; a += 640) {
            float sc = cls[(size_t)a * C + c];
            if (sc > CLS_T) {
                u32 bits = __float_as_uint(sc);
                if (bits - KEY_BASE >= thresh) {
                    u32 p = atomicAdd(&s_cnt, 1u);
                    if (p < CCAP) cand[p] = ((u64)bits << 32) | (u32)(~(u32)a);
                }
            }
        }
        __syncthreads();
        cnt_f = s_cnt < CCAP ? s_cnt : CCAP;
    }

    // pad + zero iomaskT
    for (u32 i = cnt_f + tid; i < CCAP; i += 640) cand[i] = 0;
    for (int m = tid; m < NWORDS * TOPK; m += 640) ((u64*)iomaskT)[m] = 0;
    __syncthreads();

    // ---- register bitonic sort of 1024 (tid<512 active, barrier-safe) ----
    u64 a0 = 0, a1 = 0;
    if (tid < 512) { a0 = cand[tid]; a1 = cand[tid + 512]; }
    if (tid < 512)
        for (u32 kk = 2; kk <= 64; kk <<= 1)
            for (u32 j = kk >> 1; j >= 1; j >>= 1)
                sstep(a0, a1, tid, kk, j);
    lstep640(cand, a0, a1, tid, 128u, 64u);
    if (tid < 512) for (u32 j = 32; j >= 1; j >>= 1) sstep(a0, a1, tid, 128u, j);
    lstep640(cand, a0, a1, tid, 256u, 128u);
    lstep640(cand, a0, a1, tid, 256u, 64u);
    if (tid < 512) for (u32 j = 32; j >= 1; j >>= 1) sstep(a0, a1, tid, 256u, j);
    lstep640(cand, a0, a1, tid, 512u, 256u);
    lstep640(cand, a0, a1, tid, 512u, 128u);
    lstep640(cand, a0, a1, tid, 512u, 64u);
    if (tid < 512) for (u32 j = 32; j >= 1; j >>= 1) sstep(a0, a1, tid, 512u, j);
    if (tid < 512) {   // kk=1024, j=512: in-thread exchange
        u64 mx = a0 > a1 ? a0 : a1, mn = a0 > a1 ? a1 : a0;
        a0 = mx; a1 = mn;
    }
    lstep640(cand, a0, a1, tid, 1024u, 256u);
    lstep640(cand, a0, a1, tid, 1024u, 128u);
    lstep640(cand, a0, a1, tid, 1024u, 64u);
    if (tid < 512) for (u32 j = 32; j >= 1; j >>= 1) sstep(a0, a1, tid, 1024u, j);
    // thread tid<512 holds sorted element tid in a0

    const int T = (int)(cnt_f < TOPK ? cnt_f : TOPK);

    // ---- inline decode boxes for my candidate ----
    u64 key = a0; u32 aidx = 0;
    if ((int)tid < T) {
        aidx = ~(u32)(key & 0xFFFFFFFFull);
        float4 b4 = decode_box(anc, reg, aidx, W, H);
        sbox[tid] = b4;
        sbar[tid] = fmaxf(b4.z - b4.x, 0.0f) * fmaxf(b4.w - b4.y, 0.0f);
    }
    __syncthreads();

    // ---- colmask: row jj, parity p, branchless IoU ----
    {
        const int jj = (int)(tid < 320 ? tid : tid - 320);
        const int p  = (int)(tid < 320 ? 0 : 1);
        if (jj < T) {
            float4 b = sbox[jj];
            float ar = sbar[jj];
            u64 cm[NWORDS] = {0,0,0,0,0};
            for (int i = p; i < jj; i += 2) {
                float4 bi = sbox[i];
                float iw = fmaxf(fminf(b.z, bi.z) - fmaxf(b.x, bi.x), 0.0f);
                float ih = fmaxf(fminf(b.w, bi.w) - fmaxf(b.y, bi.y), 0.0f);
                float inter = iw * ih;
                float uni = ((ar + sbar[i]) - inter) + 1e-8f;
                if (inter / uni > 0.5f) cm[i >> 6] |= 1ull << (i & 63);
            }
            #pragma unroll
            for (int w = 0; w < NWORDS; ++w)
                if (cm[w]) atomicOr(&iomaskT[w][jj], cm[w]);
        }
    }
    __syncthreads();

    // ---- wave 0: word-serial, round-parallel ballot greedy ----
    if (tid < 64) {
        u64 K[NWORDS];
        #pragma unroll
        for (int w = 0; w < NWORDS; ++w) {
            int b = w * 64 + lane;
            bool valid = (b < T);
            u64 cmw = 0, se = 0;
            if (valid) {
                #pragma unroll
                for (int w2 = 0; w2 < NWORDS; ++w2)
                    if (w2 < w) se |= K[w2] & iomaskT[w2][b];
                cmw = iomaskT[w][b];
            }
            u64 U = __ballot(valid && se == 0);
            u64 Kw = 0;
            int guard = 0;
            while (U && guard++ < 64) {
                u64 newk = __ballot(((U >> lane) & 1ull) && ((cmw & U) == 0));
                Kw |= newk; U &= ~newk;
                u64 supp = __ballot((cmw & Kw) != 0);
                U &= ~supp;
            }
            K[w] = Kw;
        }
        if (lane == 0) {
            #pragma unroll
            for (int w = 0; w < NWORDS; ++w) s_keep[w] = K[w];
        }
    }
    __syncthreads();

    if ((int)tid < T) {
        if ((s_keep[tid >> 6] >> (tid & 63)) & 1ull) {
            u32 sbits = (u32)(key >> 32);
            u64 outk = ((u64)sbits << 32) | (u32)(255 - c);
            atomicMax(&akey[aidx], outk);
        }
    }
}

// ---------------- finalize: decode kept boxes inline ----------------
__global__ void finalize_kernel(const u64* __restrict__ akey,
                                const float* __restrict__ anc,
                                const float* __restrict__ reg,
                                const int* __restrict__ ph,
                                const int* __restrict__ pw,
                                float* __restrict__ out, int A)
{
    int a = blockIdx.x * blockDim.x + threadIdx.x;
    if (a >= A) return;
    float* scores = out;
    float* labels = out + A;
    float* boxes  = out + (size_t)2 * A;
    u64 k = akey[a];
    if (k) {
        scores[a] = __uint_as_float((u32)(k >> 32));
        labels[a] = (float)(int)(255u - (u32)(k & 0xFFFFFFFFull));
        float W = (float)(*pw), H = (float)(*ph);
        float4 b = decode_box(anc, reg, (u32)a, W, H);
        boxes[(size_t)a*4+0] = b.x; boxes[(size_t)a*4+1] = b.y;
        boxes[(size_t)a*4+2] = b.z; boxes[(size_t)a*4+3] = b.w;
    } else {
        scores[a] = 0.0f;
        labels[a] = -1.0f;
        boxes[(size_t)a*4+0] = 0.0f;
        boxes[(size_t)a*4+1] = 0.0f;
        boxes[(size_t)a*4+2] = 0.0f;
        boxes[(size_t)a*4+3] = 0.0f;
    }
}

// ---------------- fallback finalize (boxes precomputed in out) ----------------
__global__ void fb_finalize_kernel(const u64* __restrict__ akey,
                                   float* __restrict__ out, int A)
{
    int a = blockIdx.x * blockDim.x + threadIdx.x;
    if (a >= A) return;
    float* scores = out;
    float* labels = out + A;
    float* boxes  = out + (size_t)2 * A;
    u64 k = akey[a];
    if (k) {
        scores[a] = __uint_as_float((u32)(k >> 32));
        labels[a] = (float)(int)(255u - (u32)(k & 0xFFFFFFFFull));
    } else {
        scores[a] = 0.0f;
        labels[a] = -1.0f;
        boxes[(size_t)a*4+0] = 0.0f;
        boxes[(size_t)a*4+1] = 0.0f;
        boxes[(size_t)a*4+2] = 0.0f;
        boxes[(size_t)a*4+3] = 0.0f;
    }
}

// ---------------- fallback (generic C / small ws): round-1 proven kernel ----------------
#define FB_CAP 1024
__global__ __launch_bounds__(256) void fb_topk_nms_kernel(
    const float* __restrict__ cls,
    const float* __restrict__ boxes,
    u64* __restrict__ akey,
    int A, int C)
{
    const int c   = blockIdx.x;
    const int tid = threadIdx.x;

    __shared__ u32 hist[HBINS];
    __shared__ u64 cand[FB_CAP];
    __shared__ float bx1[TOPK], by1[TOPK], bx2[TOPK], by2[TOPK], bar[TOPK];
    __shared__ u64 iomask[TOPK][NWORDS];
    __shared__ u64 keepm[NWORDS];
    __shared__ u32 s_sel1, s_sel2, s_rem, s_cnt;

    for (int i = tid; i < HBINS; i += 256) hist[i] = 0;
    __syncthreads();
    for (int a = tid; a < A; a += 256) {
        float s = cls[(size_t)a * C + c];
        if (s > CLS_T) {
            u32 k = __float_as_uint(s) - KEY_BASE;
            u32 b = k >> 14; if (b >= HBINS) b = HBINS - 1;
            atomicAdd(&hist[b], 1u);
        }
    }
    __syncthreads();
    if (tid == 0) {
        u32 cum = 0; int sel = 0;
        for (int d = HBINS - 1; d >= 0; --d) {
            u32 nc = cum + hist[d];
            if (nc >= TOPK) { sel = d; break; }
            cum = nc;
        }
        s_sel1 = (u32)sel; s_rem = TOPK - cum;
    }
    __syncthreads();
    const u32 sel1 = s_sel1;

    for (int i = tid; i < 256; i += 256) hist[i] = 0;
    __syncthreads();
    for (int a = tid; a < A; a += 256) {
        float s = cls[(size_t)a * C + c];
        if (s > CLS_T) {
            u32 k = __float_as_uint(s) - KEY_BASE;
            u32 b = k >> 14; if (b >= HBINS) b = HBINS - 1;
            if (b == sel1) atomicAdd(&hist[(k >> 6) & 0xFF], 1u);
        }
    }
    __syncthreads();
    if (tid == 0) {
        u32 rem = s_rem, cum = 0; int sel = 0;
        for (int d = 255; d >= 0; --d) {
            u32 nc = cum + hist[d];
            if (nc >= rem) { sel = d; break; }
            cum = nc;
        }
        s_sel2 = (u32)sel; s_cnt = 0;
    }
    __syncthreads();
    const u32 thresh = (sel1 << 14) | (s_sel2 << 6);

    for (int a = tid; a < A; a += 256) {
        float s = cls[(size_t)a * C + c];
        if (s > CLS_T) {
            u32 bits = __float_as_uint(s);
            u32 k = bits - KEY_BASE;
            if (k >= thresh) {
                u32 pos = atomicAdd(&s_cnt, 1u);
                if (pos < FB_CAP) cand[pos] = ((u64)bits << 32) | (u32)(~(u32)a);
            }
        }
    }
    __syncthreads();
    const u32 total = s_cnt < FB_CAP ? s_cnt : FB_CAP;
    for (int i = tid; i < FB_CAP; i += 256)
        if (i >= (int)total) cand[i] = 0;
    __syncthreads();

    for (u32 kk = 2; kk <= FB_CAP; kk <<= 1) {
        for (u32 j = kk >> 1; j > 0; j >>= 1) {
            for (u32 i = tid; i < FB_CAP; i += 256) {
                u32 l = i ^ j;
                if (l > i) {
                    u64 av = cand[i], bv = cand[l];
                    bool up = ((i & kk) == 0);
                    if ((up && av < bv) || (!up && av > bv)) { cand[i] = bv; cand[l] = av; }
                }
            }
            __syncthreads();
        }
    }
    const int T = (int)(total < TOPK ? total : TOPK);

    for (int i = tid; i < T; i += 256) {
        u32 a = ~(u32)(cand[i] & 0xFFFFFFFFull);
        float x1 = boxes[(size_t)a*4+0], y1 = boxes[(size_t)a*4+1];
        float x2 = boxes[(size_t)a*4+2], y2 = boxes[(size_t)a*4+3];
        bx1[i] = x1; by1[i] = y1; bx2[i] = x2; by2[i] = y2;
        bar[i] = fmaxf(x2 - x1, 0.0f) * fmaxf(y2 - y1, 0.0f);
    }
    __syncthreads();

    for (int i = tid; i < T; i += 256) {
        u64 m[NWORDS] = {0,0,0,0,0};
        float x1 = bx1[i], y1 = by1[i], x2 = bx2[i], y2 = by2[i], ai = bar[i];
        for (int j = i + 1; j < T; ++j) {
            float iw = fmaxf(fminf(x2, bx2[j]) - fmaxf(x1, bx1[j]), 0.0f);
            float ih = fmaxf(fminf(y2, by2[j]) - fmaxf(y1, by1[j]), 0.0f);
            float inter = iw * ih;
            float uni = ((ai + bar[j]) - inter) + 1e-8f;
            if (inter / uni > 0.5f) m[j >> 6] |= 1ull << (j & 63);
        }
        for (int k2 = 0; k2 < NWORDS; ++k2) iomask[i][k2] = m[k2];
    }
    __syncthreads();

    if (tid == 0) {
        u64 sup[NWORDS] = {0,0,0,0,0};
        u64 kp [NWORDS] = {0,0,0,0,0};
        for (int i = 0; i < T; ++i) {
            if (!((sup[i >> 6] >> (i & 63)) & 1ull)) {
                kp[i >> 6] |= 1ull << (i & 63);
                for (int k2 = 0; k2 < NWORDS; ++k2) sup[k2] |= iomask[i][k2];
            }
        }
        for (int k2 = 0; k2 < NWORDS; ++k2) keepm[k2] = kp[k2];
    }
    __syncthreads();

    for (int i = tid; i < T; i += 256) {
        if ((keepm[i >> 6] >> (i & 63)) & 1ull) {
            u64 key = cand[i];
            u32 a = ~(u32)(key & 0xFFFFFFFFull);
            u32 sbits = (u32)(key >> 32);
            u64 outk = ((u64)sbits << 32) | (u32)(255 - c);
            atomicMax(&akey[a], outk);
        }
    }
}

extern "C" void kernel_launch(void* const* d_in, const int* in_sizes, int n_in,
                              void* d_out, int out_size, void* d_ws, size_t ws_size,
                              hipStream_t stream) {
    const float* cls = (const float*)d_in[0];
    const float* reg = (const float*)d_in[1];
    const float* anc = (const float*)d_in[2];
    const int*   ph  = (const int*)d_in[3];
    const int*   pw  = (const int*)d_in[4];

    int A = in_sizes[2] / 4;
    int C = in_sizes[0] / A;

    float* out       = (float*)d_out;
    float* out_boxes = out + (size_t)2 * A;

    // workspace: akey | segcnt | gbuf
    size_t akey_bytes = (size_t)A * sizeof(u64);
    size_t off_sc     = (akey_bytes + 255) & ~(size_t)255;
    size_t sc_bytes   = (size_t)80 * NBLK * sizeof(u32);
    size_t off_gb     = (off_sc + sc_bytes + 255) & ~(size_t)255;
    size_t gb_bytes   = (size_t)80 * NBLK * SCAP * sizeof(u64);
    size_t need       = off_gb + gb_bytes;

    u64* akey = (u64*)d_ws;

    bool fastpath = (C == 80) && ((A & 3) == 0) && (A < (1 << 20)) && (ws_size >= need);

    if (fastpath) {
        u32* segcnt = (u32*)((char*)d_ws + off_sc);
        u64* gbuf   = (u64*)((char*)d_ws + off_gb);

        fused_scan_kernel<<<NBLK, 256, 0, stream>>>(cls, akey, gbuf, segcnt, A);
        class_fused_kernel<<<C, 640, 0, stream>>>(segcnt, gbuf, cls, anc, reg, ph, pw, akey, A, C);
        finalize_kernel<<<(A + 255) / 256, 256, 0, stream>>>(akey, anc, reg, ph, pw, out, A);
    } else {
        decode_kernel<<<(A + 255) / 256, 256, 0, stream>>>(anc, reg, ph, pw, out_boxes, akey, A);
        fb_topk_nms_kernel<<<C, 256, 0, stream>>>(cls, out_boxes, akey, A, C);
        fb_finalize_kernel<<<(A + 255) / 256, 256, 0, stream>>>(akey, out, A);
    }
}

// Round 17
// 51.824 us; speedup vs baseline: 3.2461x; 1.1052x over previous
//
#include <hip/hip_runtime.h>
#include <cstdint>

typedef unsigned long long u64;
typedef unsigned int u32;

#define CLS_T    0.05f
#define T1G      0.997933f  // collect threshold: n ~ 406 +- 20 per class
#define TOPK     300
#define NWORDS   5          // ceil(300/64)
#define HBINS    2560
#define KEY_BASE 0x3D000000u
#define CCAP     512
#define NBLK     2048       // scan blocks
#define SCAP     16         // slots per (class, scan-block): 128B segment
#define OVBIT    0x80000000u

__device__ inline u32 bin_of_bits(u32 bits) {
    u32 b = (bits - KEY_BASE) >> 14;
    if (b > (HBINS - 1)) b = HBINS - 1;
    return b;
}

// decode one anchor's box (identical arithmetic to reference)
__device__ inline float4 decode_box(const float* __restrict__ anc,
                                    const float* __restrict__ reg,
                                    u32 a, float W, float H)
{
    float x1 = anc[(size_t)a*4+0], y1 = anc[(size_t)a*4+1];
    float x2 = anc[(size_t)a*4+2], y2 = anc[(size_t)a*4+3];
    float w = x2 - x1, h = y2 - y1;
    float cx = x1 + 0.5f*w, cy = y1 + 0.5f*h;
    float r0 = reg[(size_t)a*4+0]*0.1f, r1 = reg[(size_t)a*4+1]*0.1f;
    float r2 = reg[(size_t)a*4+2]*0.2f, r3 = reg[(size_t)a*4+3]*0.2f;
    float pcx = cx + r0*w, pcy = cy + r1*h;
    float pw_ = expf(r2)*w, ph_ = expf(r3)*h;
    float4 b;
    b.x = fmaxf(pcx - 0.5f*pw_, 0.0f);
    b.y = fmaxf(pcy - 0.5f*ph_, 0.0f);
    b.z = fminf(pcx + 0.5f*pw_, W);
    b.w = fminf(pcy + 0.5f*ph_, H);
    return b;
}

// compare-exchange: keep max if (lo==up), else min  (descending bitonic)
__device__ inline void cex(u64& v, u64 p, bool lo, bool up) {
    u64 mx = v > p ? v : p;
    u64 mn = v > p ? p : v;
    v = (lo == up) ? mx : mn;
}
// in-wave stage (j <= 32): shfl_xor, barrier-free
__device__ inline void s1(u64& v, u32 tid, u32 kk, u32 j) {
    u64 p = __shfl_xor((unsigned long long)v, (int)j, 64);
    cex(v, p, (tid & j) == 0, (tid & kk) == 0);
}
// cross-wave stage (j >= 64): LDS exchange, 640-thread barrier-safe
__device__ inline void l1(u64* sm, u64& v, u32 tid, u32 kk, u32 j) {
    __syncthreads();
    if (tid < 512) sm[tid] = v;
    __syncthreads();
    if (tid < 512) {
        u64 p = sm[tid ^ j];
        cex(v, p, (tid & j) == 0, (tid & kk) == 0);
    }
}

// ---------------- standalone decode (fallback path only) ----------------
__global__ void decode_kernel(const float* __restrict__ anc,
                              const float* __restrict__ reg,
                              const int* __restrict__ ph,
                              const int* __restrict__ pw,
                              float* __restrict__ boxes,
                              u64* __restrict__ akey, int A)
{
    int a = blockIdx.x * blockDim.x + threadIdx.x;
    if (a >= A) return;
    akey[a] = 0;
    float W = (float)(*pw), H = (float)(*ph);
    float4 b = decode_box(anc, reg, (u32)a, W, H);
    boxes[a*4+0] = b.x; boxes[a*4+1] = b.y;
    boxes[a*4+2] = b.z; boxes[a*4+3] = b.w;
}

// ---------------- fused: zero akey + one-pass collect at T1 (zero global atomics) ----------------
__global__ __launch_bounds__(256) void fused_scan_kernel(
    const float* __restrict__ cls,
    u64* __restrict__ akey,
    u64* __restrict__ gbuf, u32* __restrict__ segcnt, int A)
{
    const int tid = threadIdx.x;
    const int blk = blockIdx.x;

    for (int a = blk * 256 + tid; a < A; a += NBLK * 256) akey[a] = 0;

    __shared__ u32 cnt[80];
    __shared__ u64 buf[80][SCAP];
    __shared__ u32 s_over;
    for (int i = tid; i < 80; i += 256) cnt[i] = 0;
    if (tid == 0) s_over = 0;
    __syncthreads();

    size_t Nf4 = (size_t)A * 20;   // A*80/4
    const float4* p4 = (const float4*)cls;
    for (size_t i = (size_t)blk * 256 + tid; i < Nf4; i += (size_t)NBLK * 256) {
        float4 v = p4[i];
        float ss[4] = {v.x, v.y, v.z, v.w};
        #pragma unroll
        for (int q = 0; q < 4; ++q) {
            if (ss[q] > T1G) {
                u32 flat = (u32)(i * 4 + q);
                u32 a = flat / 80u;            // const-div -> magic mul
                u32 c = flat - a * 80u;
                u32 p = atomicAdd(&cnt[c], 1u);   // LDS atomic only
                if (p < SCAP) buf[c][p] = ((u64)__float_as_uint(ss[q]) << 32) | (u32)(~a);
                else s_over = 1;
            }
        }
    }
    __syncthreads();

    const u32 ob = s_over ? OVBIT : 0u;
    for (int m = tid; m < 80 * SCAP; m += 256) {
        int c = m / SCAP, e = m - c * SCAP;
        u32 cc = cnt[c]; if (cc > SCAP) cc = SCAP;
        if ((u32)e < cc)
            gbuf[((size_t)c * NBLK + blk) * SCAP + e] = buf[c][e];
    }
    for (int c = tid; c < 80; c += 256) {
        u32 cc = cnt[c]; if (cc > SCAP) cc = SCAP;
        segcnt[(size_t)c * NBLK + blk] = cc | ob;
    }
}

// ---------------- fused per-class: wave prefix + gather + 512-sort + decode + NMS ----------------
__global__ __launch_bounds__(640) void class_fused_kernel(
    const u32* __restrict__ segcnt, const u64* __restrict__ gbuf,
    const float* __restrict__ cls,     // [A][C] for slow path
    const float* __restrict__ anc, const float* __restrict__ reg,
    const int* __restrict__ ph, const int* __restrict__ pw,
    u64* __restrict__ akey, int A, int C)
{
    const int c = blockIdx.x;
    const u32 tid = threadIdx.x;
    const int lane = tid & 63;

    __shared__ u32 sh[HBINS];          // slow path histogram
    __shared__ u32 sp[NBLK];           // exclusive prefix of segment counts
    __shared__ u64 cand[CCAP];
    __shared__ u32 wtot[8], wob[8];
    __shared__ u32 s_sel, s_cnt, s_rem;
    __shared__ float4 sbox[TOPK];
    __shared__ float  sbar[TOPK];
    __shared__ u64 iomaskT[NWORDS][TOPK];
    __shared__ u64 s_keep[NWORDS];

    const float W = (float)(*pw), H = (float)(*ph);

    // ---- wave-structured prefix over this class's segcnt row (2 barriers) ----
    u32 v4[4] = {0,0,0,0};
    u32 s = 0, ob = 0;
    if (tid < 512) {
        const u32* row = segcnt + (size_t)c * NBLK;
        #pragma unroll
        for (int q = 0; q < 4; ++q) {
            u32 r = row[tid * 4 + q];
            ob |= r & OVBIT;
            v4[q] = r & ~OVBIT;
            s += v4[q];
        }
    }
    u32 incl = s;
    #pragma unroll
    for (int d = 1; d < 64; d <<= 1) {
        u32 t = __shfl_up(incl, d, 64);
        if ((tid & 63) >= (u32)d) incl += t;
    }
    u64 obm = __ballot(ob != 0);
    if (tid < 512 && (tid & 63) == 63) {
        wtot[tid >> 6] = incl;
        wob [tid >> 6] = (obm != 0) ? 1u : 0u;
    }
    __syncthreads();
    u32 woff = 0, ntot = 0, obt = 0;
    #pragma unroll
    for (int w2 = 0; w2 < 8; ++w2) {
        u32 t = wtot[w2];
        obt |= wob[w2];
        if (w2 < (int)(tid >> 6)) woff += t;
        ntot += t;
    }
    if (tid < 512) {
        u32 base = woff + incl - s;
        #pragma unroll
        for (int q = 0; q < 4; ++q) { sp[tid * 4 + q] = base; base += v4[q]; }
    }
    __syncthreads();
    const u32 n = ntot;
    const bool over = (obt != 0);

    u32 cnt_f = 0;
    bool fast_ok = false;

    if (!over && n >= TOPK && n <= CCAP) {
        // direct gather: dense index i -> (segment b, slot e) via binary search over sp
        for (u32 i = tid; i < n; i += 640) {
            int lo = 0, hi = NBLK;
            while (hi - lo > 1) {
                int mid = (lo + hi) >> 1;
                if (sp[mid] <= i) lo = mid; else hi = mid;
            }
            u32 e = i - sp[lo];
            cand[i] = gbuf[((size_t)c * NBLK + lo) * SCAP + e];
        }
        cnt_f = n;
        fast_ok = true;
    }

    if (!fast_ok) {
        // ---- slow exact path: 2-level select over the class column ----
        __syncthreads();
        for (int i = tid; i < HBINS; i += 640) sh[i] = 0;
        if (tid == 0) s_cnt = 0;
        __syncthreads();
        for (int a = tid; a < A; a += 640) {
            float sc = cls[(size_t)a * C + c];
            if (sc > CLS_T) atomicAdd(&sh[bin_of_bits(__float_as_uint(sc))], 1u);
        }
        __syncthreads();
        if (tid == 0) {
            u32 cum = 0; int sel = 0;
            for (int d = HBINS - 1; d >= 0; --d) {
                u32 nc = cum + sh[d];
                if (nc >= TOPK) { sel = d; break; }
                cum = nc;
            }
            s_sel = (u32)sel; s_rem = TOPK - cum;
        }
        __syncthreads();
        const u32 sel1 = s_sel;
        __syncthreads();
        for (int i = tid; i < 256; i += 640) sh[i] = 0;
        __syncthreads();
        for (int a = tid; a < A; a += 640) {
            float sc = cls[(size_t)a * C + c];
            if (sc > CLS_T) {
                u32 k = __float_as_uint(sc) - KEY_BASE;
                u32 b = k >> 14; if (b >= HBINS) b = HBINS - 1;
                if (b == sel1) atomicAdd(&sh[(k >> 6) & 0xFF], 1u);
            }
        }
        __syncthreads();
        if (tid == 0) {
            u32 rem = s_rem, cum = 0; int sel = 0;
            for (int d = 255; d >= 0; --d) {
                u32 nc = cum + sh[d];
                if (nc >= rem) { sel = d; break; }
                cum = nc;
            }
            s_sel = (sel1 << 14) | ((u32)sel << 6);
            s_cnt = 0;
        }
        __syncthreads();
        const u32 thresh = s_sel;
        for (int a = tid; a < A; a += 640) {
            float sc = cls[(size_t)a * C + c];
            if (sc > CLS_T) {
                u32 bits = __float_as_uint(sc);
                if (bits - KEY_BASE >= thresh) {
                    u32 p = atomicAdd(&s_cnt, 1u);
                    if (p < CCAP) cand[p] = ((u64)bits << 32) | (u32)(~(u32)a);
                }
            }
        }
        __syncthreads();
        cnt_f = s_cnt < CCAP ? s_cnt : CCAP;
    }

    // pad + zero iomaskT, one barrier
    for (u32 i = cnt_f + tid; i < CCAP; i += 640) cand[i] = 0;
    for (int m = tid; m < NWORDS * TOPK; m += 640) ((u64*)iomaskT)[m] = 0;
    __syncthreads();

    // ---- 512-element bitonic sort, 1 elem/thread, descending ----
    // shfl stages (j<=32) barrier-free; LDS stages only for j in {64,128,256}
    u64 v = 0;
    if (tid < 512) {
        v = cand[tid];
        for (u32 kk = 2; kk <= 64; kk <<= 1)
            for (u32 j = kk >> 1; j >= 1; j >>= 1)
                s1(v, tid, kk, j);
    }
    l1(cand, v, tid, 128u, 64u);
    if (tid < 512) for (u32 j = 32; j >= 1; j >>= 1) s1(v, tid, 128u, j);
    l1(cand, v, tid, 256u, 128u);
    l1(cand, v, tid, 256u, 64u);
    if (tid < 512) for (u32 j = 32; j >= 1; j >>= 1) s1(v, tid, 256u, j);
    l1(cand, v, tid, 512u, 256u);
    l1(cand, v, tid, 512u, 128u);
    l1(cand, v, tid, 512u, 64u);
    if (tid < 512) for (u32 j = 32; j >= 1; j >>= 1) s1(v, tid, 512u, j);
    // thread tid<512 holds sorted element tid in v

    const int T = (int)(cnt_f < TOPK ? cnt_f : TOPK);

    // ---- inline decode boxes for my candidate ----
    u64 key = v; u32 aidx = 0;
    if ((int)tid < T) {
        aidx = ~(u32)(key & 0xFFFFFFFFull);
        float4 b4 = decode_box(anc, reg, aidx, W, H);
        sbox[tid] = b4;
        sbar[tid] = fmaxf(b4.z - b4.x, 0.0f) * fmaxf(b4.w - b4.y, 0.0f);
    }
    __syncthreads();

    // ---- colmask: row jj, parity p, branchless IoU ----
    {
        const int jj = (int)(tid < 320 ? tid : tid - 320);
        const int p  = (int)(tid < 320 ? 0 : 1);
        if (jj < T) {
            float4 b = sbox[jj];
            float ar = sbar[jj];
            u64 cm[NWORDS] = {0,0,0,0,0};
            for (int i = p; i < jj; i += 2) {
                float4 bi = sbox[i];
                float iw = fmaxf(fminf(b.z, bi.z) - fmaxf(b.x, bi.x), 0.0f);
                float ih = fmaxf(fminf(b.w, bi.w) - fmaxf(b.y, bi.y), 0.0f);
                float inter = iw * ih;
                float uni = ((ar + sbar[i]) - inter) + 1e-8f;
                if (inter / uni > 0.5f) cm[i >> 6] |= 1ull << (i & 63);
            }
            #pragma unroll
            for (int w = 0; w < NWORDS; ++w)
                if (cm[w]) atomicOr(&iomaskT[w][jj], cm[w]);
        }
    }
    __syncthreads();

    // ---- wave 0: word-serial, round-parallel ballot greedy ----
    if (tid < 64) {
        u64 K[NWORDS];
        #pragma unroll
        for (int w = 0; w < NWORDS; ++w) {
            int b = w * 64 + lane;
            bool valid = (b < T);
            u64 cmw = 0, se = 0;
            if (valid) {
                #pragma unroll
                for (int w2 = 0; w2 < NWORDS; ++w2)
                    if (w2 < w) se |= K[w2] & iomaskT[w2][b];
                cmw = iomaskT[w][b];
            }
            u64 U = __ballot(valid && se == 0);
            u64 Kw = 0;
            int guard = 0;
            while (U && guard++ < 64) {
                u64 newk = __ballot(((U >> lane) & 1ull) && ((cmw & U) == 0));
                Kw |= newk; U &= ~newk;
                u64 supp = __ballot((cmw & Kw) != 0);
                U &= ~supp;
            }
            K[w] = Kw;
        }
        if (lane == 0) {
            #pragma unroll
            for (int w = 0; w < NWORDS; ++w) s_keep[w] = K[w];
        }
    }
    __syncthreads();

    if ((int)tid < T) {
        if ((s_keep[tid >> 6] >> (tid & 63)) & 1ull) {
            u32 sbits = (u32)(key >> 32);
            u64 outk = ((u64)sbits << 32) | (u32)(255 - c);
            atomicMax(&akey[aidx], outk);
        }
    }
}

// ---------------- finalize: decode kept boxes inline ----------------
__global__ void finalize_kernel(const u64* __restrict__ akey,
                                const float* __restrict__ anc,
                                const float* __restrict__ reg,
                                const int* __restrict__ ph,
                                const int* __restrict__ pw,
                                float* __restrict__ out, int A)
{
    int a = blockIdx.x * blockDim.x + threadIdx.x;
    if (a >= A) return;
    float* scores = out;
    float* labels = out + A;
    float* boxes  = out + (size_t)2 * A;
    u64 k = akey[a];
    if (k) {
        scores[a] = __uint_as_float((u32)(k >> 32));
        labels[a] = (float)(int)(255u - (u32)(k & 0xFFFFFFFFull));
        float W = (float)(*pw), H = (float)(*ph);
        float4 b = decode_box(anc, reg, (u32)a, W, H);
        boxes[(size_t)a*4+0] = b.x; boxes[(size_t)a*4+1] = b.y;
        boxes[(size_t)a*4+2] = b.z; boxes[(size_t)a*4+3] = b.w;
    } else {
        scores[a] = 0.0f;
        labels[a] = -1.0f;
        boxes[(size_t)a*4+0] = 0.0f;
        boxes[(size_t)a*4+1] = 0.0f;
        boxes[(size_t)a*4+2] = 0.0f;
        boxes[(size_t)a*4+3] = 0.0f;
    }
}

// ---------------- fallback finalize (boxes precomputed in out) ----------------
__global__ void fb_finalize_kernel(const u64* __restrict__ akey,
                                   float* __restrict__ out, int A)
{
    int a = blockIdx.x * blockDim.x + threadIdx.x;
    if (a >= A) return;
    float* scores = out;
    float* labels = out + A;
    float* boxes  = out + (size_t)2 * A;
    u64 k = akey[a];
    if (k) {
        scores[a] = __uint_as_float((u32)(k >> 32));
        labels[a] = (float)(int)(255u - (u32)(k & 0xFFFFFFFFull));
    } else {
        scores[a] = 0.0f;
        labels[a] = -1.0f;
        boxes[(size_t)a*4+0] = 0.0f;
        boxes[(size_t)a*4+1] = 0.0f;
        boxes[(size_t)a*4+2] = 0.0f;
        boxes[(size_t)a*4+3] = 0.0f;
    }
}

// ---------------- fallback (generic C / small ws): round-1 proven kernel ----------------
#define FB_CAP 1024
__global__ __launch_bounds__(256) void fb_topk_nms_kernel(
    const float* __restrict__ cls,
    const float* __restrict__ boxes,
    u64* __restrict__ akey,
    int A, int C)
{
    const int c   = blockIdx.x;
    const int tid = threadIdx.x;

    __shared__ u32 hist[HBINS];
    __shared__ u64 cand[FB_CAP];
    __shared__ float bx1[TOPK], by1[TOPK], bx2[TOPK], by2[TOPK], bar[TOPK];
    __shared__ u64 iomask[TOPK][NWORDS];
    __shared__ u64 keepm[NWORDS];
    __shared__ u32 s_sel1, s_sel2, s_rem, s_cnt;

    for (int i = tid; i < HBINS; i += 256) hist[i] = 0;
    __syncthreads();
    for (int a = tid; a < A; a += 256) {
        float s = cls[(size_t)a * C + c];
        if (s > CLS_T) {
            u32 k = __float_as_uint(s) - KEY_BASE;
            u32 b = k >> 14; if (b >= HBINS) b = HBINS - 1;
            atomicAdd(&hist[b], 1u);
        }
    }
    __syncthreads();
    if (tid == 0) {
        u32 cum = 0; int sel = 0;
        for (int d = HBINS - 1; d >= 0; --d) {
            u32 nc = cum + hist[d];
            if (nc >= TOPK) { sel = d; break; }
            cum = nc;
        }
        s_sel1 = (u32)sel; s_rem = TOPK - cum;
    }
    __syncthreads();
    const u32 sel1 = s_sel1;

    for (int i = tid; i < 256; i += 256) hist[i] = 0;
    __syncthreads();
    for (int a = tid; a < A; a += 256) {
        float s = cls[(size_t)a * C + c];
        if (s > CLS_T) {
            u32 k = __float_as_uint(s) - KEY_BASE;
            u32 b = k >> 14; if (b >= HBINS) b = HBINS - 1;
            if (b == sel1) atomicAdd(&hist[(k >> 6) & 0xFF], 1u);
        }
    }
    __syncthreads();
    if (tid == 0) {
        u32 rem = s_rem, cum = 0; int sel = 0;
        for (int d = 255; d >= 0; --d) {
            u32 nc = cum + hist[d];
            if (nc >= rem) { sel = d; break; }
            cum = nc;
        }
        s_sel2 = (u32)sel; s_cnt = 0;
    }
    __syncthreads();
    const u32 thresh = (sel1 << 14) | (s_sel2 << 6);

    for (int a = tid; a < A; a += 256) {
        float s = cls[(size_t)a * C + c];
        if (s > CLS_T) {
            u32 bits = __float_as_uint(s);
            u32 k = bits - KEY_BASE;
            if (k >= thresh) {
                u32 pos = atomicAdd(&s_cnt, 1u);
                if (pos < FB_CAP) cand[pos] = ((u64)bits << 32) | (u32)(~(u32)a);
            }
        }
    }
    __syncthreads();
    const u32 total = s_cnt < FB_CAP ? s_cnt : FB_CAP;
    for (int i = tid; i < FB_CAP; i += 256)
        if (i >= (int)total) cand[i] = 0;
    __syncthreads();

    for (u32 kk = 2; kk <= FB_CAP; kk <<= 1) {
        for (u32 j = kk >> 1; j > 0; j >>= 1) {
            for (u32 i = tid; i < FB_CAP; i += 256) {
                u32 l = i ^ j;
                if (l > i) {
                    u64 av = cand[i], bv = cand[l];
                    bool up = ((i & kk) == 0);
                    if ((up && av < bv) || (!up && av > bv)) { cand[i] = bv; cand[l] = av; }
                }
            }
            __syncthreads();
        }
    }
    const int T = (int)(total < TOPK ? total : TOPK);

    for (int i = tid; i < T; i += 256) {
        u32 a = ~(u32)(cand[i] & 0xFFFFFFFFull);
        float x1 = boxes[(size_t)a*4+0], y1 = boxes[(size_t)a*4+1];
        float x2 = boxes[(size_t)a*4+2], y2 = boxes[(size_t)a*4+3];
        bx1[i] = x1; by1[i] = y1; bx2[i] = x2; by2[i] = y2;
        bar[i] = fmaxf(x2 - x1, 0.0f) * fmaxf(y2 - y1, 0.0f);
    }
    __syncthreads();

    for (int i = tid; i < T; i += 256) {
        u64 m[NWORDS] = {0,0,0,0,0};
        float x1 = bx1[i], y1 = by1[i], x2 = bx2[i], y2 = by2[i], ai = bar[i];
        for (int j = i + 1; j < T; ++j) {
            float iw = fmaxf(fminf(x2, bx2[j]) - fmaxf(x1, bx1[j]), 0.0f);
            float ih = fmaxf(fminf(y2, by2[j]) - fmaxf(y1, by1[j]), 0.0f);
            float inter = iw * ih;
            float uni = ((ai + bar[j]) - inter) + 1e-8f;
            if (inter / uni > 0.5f) m[j >> 6] |= 1ull << (j & 63);
        }
        for (int k2 = 0; k2 < NWORDS; ++k2) iomask[i][k2] = m[k2];
    }
    __syncthreads();

    if (tid == 0) {
        u64 sup[NWORDS] = {0,0,0,0,0};
        u64 kp [NWORDS] = {0,0,0,0,0};
        for (int i = 0; i < T; ++i) {
            if (!((sup[i >> 6] >> (i & 63)) & 1ull)) {
                kp[i >> 6] |= 1ull << (i & 63);
                for (int k2 = 0; k2 < NWORDS; ++k2) sup[k2] |= iomask[i][k2];
            }
        }
        for (int k2 = 0; k2 < NWORDS; ++k2) keepm[k2] = kp[k2];
    }
    __syncthreads();

    for (int i = tid; i < T; i += 256) {
        if ((keepm[i >> 6] >> (i & 63)) & 1ull) {
            u64 key = cand[i];
            u32 a = ~(u32)(key & 0xFFFFFFFFull);
            u32 sbits = (u32)(key >> 32);
            u64 outk = ((u64)sbits << 32) | (u32)(255 - c);
            atomicMax(&akey[a], outk);
        }
    }
}

extern "C" void kernel_launch(void* const* d_in, const int* in_sizes, int n_in,
                              void* d_out, int out_size, void* d_ws, size_t ws_size,
                              hipStream_t stream) {
    const float* cls = (const float*)d_in[0];
    const float* reg = (const float*)d_in[1];
    const float* anc = (const float*)d_in[2];
    const int*   ph  = (const int*)d_in[3];
    const int*   pw  = (const int*)d_in[4];

    int A = in_sizes[2] / 4;
    int C = in_sizes[0] / A;

    float* out       = (float*)d_out;
    float* out_boxes = out + (size_t)2 * A;

    // workspace: akey | segcnt | gbuf
    size_t akey_bytes = (size_t)A * sizeof(u64);
    size_t off_sc     = (akey_bytes + 255) & ~(size_t)255;
    size_t sc_bytes   = (size_t)80 * NBLK * sizeof(u32);
    size_t off_gb     = (off_sc + sc_bytes + 255) & ~(size_t)255;
    size_t gb_bytes   = (size_t)80 * NBLK * SCAP * sizeof(u64);
    size_t need       = off_gb + gb_bytes;

    u64* akey = (u64*)d_ws;

    bool fastpath = (C == 80) && ((A & 3) == 0) && (A < (1 << 20)) && (ws_size >= need);

    if (fastpath) {
        u32* segcnt = (u32*)((char*)d_ws + off_sc);
        u64* gbuf   = (u64*)((char*)d_ws + off_gb);

        fused_scan_kernel<<<NBLK, 256, 0, stream>>>(cls, akey, gbuf, segcnt, A);
        class_fused_kernel<<<C, 640, 0, stream>>>(segcnt, gbuf, cls, anc, reg, ph, pw, akey, A, C);
        finalize_kernel<<<(A + 255) / 256, 256, 0, stream>>>(akey, anc, reg, ph, pw, out, A);
    } else {
        decode_kernel<<<(A + 255) / 256, 256, 0, stream>>>(anc, reg, ph, pw, out_boxes, akey, A);
        fb_topk_nms_kernel<<<C, 256, 0, stream>>>(cls, out_boxes, akey, A, C);
        fb_finalize_kernel<<<(A + 255) / 256, 256, 0, stream>>>(akey, out, A);
    }
}